// Round 14
// baseline (164.033 us; speedup 1.0000x reference)
//
#include <hip/hip_runtime.h>

typedef _Float16 half8 __attribute__((ext_vector_type(8)));
typedef _Float16 half4 __attribute__((ext_vector_type(4)));
typedef float f32x4 __attribute__((ext_vector_type(4)));
typedef float f32x16 __attribute__((ext_vector_type(16)));
typedef unsigned u32x4 __attribute__((ext_vector_type(4)));

#define N_B 2
#define S_LEN 2048
#define NH 16
#define HD 64
#define DM 1024
#define LOG2E 1.44269504088896f

// volatile asm load: cannot be sunk to use (defeats hipcc's pressure-min
// scheduling that serialized R13); counted vmcnt manages completion.
#define GLD(dst, ptr, OFF)                                                \
    asm volatile("global_load_dwordx4 %0, %1, off offset:" #OFF           \
                 : "=&v"(dst) : "v"(ptr))
#define WAITV(N)  asm volatile("s_waitcnt vmcnt(" #N ")" ::: "memory")
#define SB0()     __builtin_amdgcn_sched_barrier(0)

__device__ __forceinline__ void gload16(const void* g, void* l) {
    __builtin_amdgcn_global_load_lds(
        (const __attribute__((address_space(1))) unsigned int*)g,
        (__attribute__((address_space(3))) unsigned int*)l, 16, 0, 0);
}

__device__ __forceinline__ float fexp2(float x) {
    float r;
    asm("v_exp_f32 %0, %1" : "=v"(r) : "v"(x));
    return r;
}

// ---------------------------------------------------------------------------
// Fused prep (one launch): blocks [0,4096) regroup K -> f16 [n][h][s][d];
// [4096,5120) transpose V -> Vt f16 [n][h][d][s]; [5120,6144) cvt W -> f16.
// ---------------------------------------------------------------------------
__global__ __launch_bounds__(256) void k_prep(const float* __restrict__ K,
                                              const float* __restrict__ V,
                                              const float* __restrict__ Wo,
                                              _Float16* __restrict__ Kh,
                                              _Float16* __restrict__ Vt,
                                              _Float16* __restrict__ Wh) {
    __shared__ _Float16 tile[64][65];
    const int id = blockIdx.x;
    if (id < 4096) {                       // ---- K regroup
        int i = id * 256 + threadIdx.x;
        float4 v = ((const float4*)K)[i];
        int base = i * 4;
        int d = base & 63;
        int h = (base >> 6) & 15;
        int s = (base >> 10) & 2047;
        int n = base >> 21;
        size_t o = ((size_t)((n * NH + h) * S_LEN + s)) * HD + d;
        half4 hv = {(_Float16)v.x, (_Float16)v.y, (_Float16)v.z, (_Float16)v.w};
        *(half4*)(Kh + o) = hv;
    } else if (id < 5120) {                // ---- V transpose
        int b = id - 4096;
        int st = b & 31, h = (b >> 5) & 15, n = b >> 9;
        int c = threadIdx.x & 63, r0 = threadIdx.x >> 6;
#pragma unroll
        for (int i = 0; i < 16; ++i) {
            int r = i * 4 + r0;
            tile[r][c] = (_Float16)V[((size_t)(n * S_LEN) + st * 64 + r) * DM + h * HD + c];
        }
        __syncthreads();
#pragma unroll
        for (int i = 0; i < 16; ++i) {
            int d = i * 4 + r0;
            Vt[((size_t)((n * NH + h) * HD + d)) * S_LEN + st * 64 + c] = tile[c][d];
        }
    } else {                               // ---- W convert
        int i = (id - 5120) * 256 + threadIdx.x;
        float4 v = ((const float4*)Wo)[i];
        half4 hv = {(_Float16)v.x, (_Float16)v.y, (_Float16)v.z, (_Float16)v.w};
        *(half4*)(Wh + (size_t)i * 4) = hv;
    }
}

// ---------------------------------------------------------------------------
// Flash attention, barrier-free + HAND-PIPELINED register prefetch:
// K(t+1) issued (volatile asm) right after QK^T(t); V(t+1) right after
// PV(t); consumption gated by counted s_waitcnt vmcnt(8) + sched_barrier(0)
// (rule-18 fence). No LDS in the loop, no cross-wave hazards (plain reg
// loads only -> deterministic). Block = 4 waves (256 thr), QBLK=64:
// wave w: q-subtile (w&1), KV half (w>>1). K/V are L2-resident per XCD.
// LDS only for the final wave-pair merge.
// ---------------------------------------------------------------------------
__global__ __launch_bounds__(256, 2) void k_attn(const float* __restrict__ Q,
                                                 const _Float16* __restrict__ Kh,
                                                 const _Float16* __restrict__ Vth,
                                                 _Float16* __restrict__ Oatt) {
    __shared__ float MRG[2 * 2176];      // 17.4 KB, merge only

    // XCD swizzle (bijective on 1024 = 8 * 128): 4 nh per XCD, 32 qt each
    const int id = blockIdx.x;
    const int xcd = id & 7;
    const int sl = id >> 3;              // 0..127
    const int nh = xcd + 8 * (sl >> 5);
    const int qt = sl & 31;              // q tile of 64

    const int tid = threadIdx.x;
    const int w = tid >> 6;              // 0..3
    const int wq = w & 1;                // q-subtile
    const int hf = w >> 1;               // KV half
    const int lane = tid & 63;
    const int l31 = lane & 31;
    const int hi = lane >> 5;
    const int n = nh >> 4, h = nh & 15;

    const size_t head = (size_t)nh * S_LEN * HD;
    const char* Khead = (const char*)(Kh + head);
    const char* Vhead = (const char*)(Vth + head);

    // ---- Q fragments (B-frag: col q=l31, k=8hi+j per 16-d chunk), LOG2E-scaled
    const int qg = qt * 64 + wq * 32 + l31;
    const float* qbase = Q + ((size_t)(n * S_LEN) + qg) * DM + h * HD;
    auto mkqf = [&](int c) -> half8 {
        float4 a = *(const float4*)(qbase + 16 * c + 8 * hi);
        float4 b = *(const float4*)(qbase + 16 * c + 8 * hi + 4);
        half8 r = {(_Float16)(a.x * LOG2E), (_Float16)(a.y * LOG2E),
                   (_Float16)(a.z * LOG2E), (_Float16)(a.w * LOG2E),
                   (_Float16)(b.x * LOG2E), (_Float16)(b.y * LOG2E),
                   (_Float16)(b.z * LOG2E), (_Float16)(b.w * LOG2E)};
        return r;
    };
    half8 qf0 = mkqf(0), qf1 = mkqf(1), qf2 = mkqf(2), qf3 = mkqf(3);

    f32x16 oacc0 = {}, oacc1 = {};
    float m_q = -1e30f, l_q = 0.f;       // m uniform per q; l per-(q,hi) partial

    // per-lane fragment pointers (advance per round)
    const char* kp0 = Khead + ((size_t)(hf * 1024 + l31)) * 128 + 16 * hi;  // K blk0
    const char* kp1 = kp0 + 4096;                                           // K blk1
    const char* vp0 = Vhead + (size_t)l31 * 4096 + hf * 2048 + 16 * hi;     // V dblk0
    const char* vp1 = vp0 + 131072;                                         // V dblk1

    half8 kf0, kf1, kf2, kf3, kf4, kf5, kf6, kf7;
    half8 vf0, vf1, vf2, vf3, vf4, vf5, vf6, vf7;

    // ---- prologue: issue K(0), V(0) ----
    GLD(kf0, kp0, 0);  GLD(kf1, kp0, 32);  GLD(kf2, kp0, 64);  GLD(kf3, kp0, 96);
    GLD(kf4, kp1, 0);  GLD(kf5, kp1, 32);  GLD(kf6, kp1, 64);  GLD(kf7, kp1, 96);
    GLD(vf0, vp0, 0);  GLD(vf1, vp0, 32);  GLD(vf2, vp0, 64);  GLD(vf3, vp0, 96);
    GLD(vf4, vp1, 0);  GLD(vf5, vp1, 32);  GLD(vf6, vp1, 64);  GLD(vf7, vp1, 96);

    auto pk2 = [&](float a, float b) -> unsigned {
        unsigned short ua = __builtin_bit_cast(unsigned short, (_Float16)a);
        unsigned short ub = __builtin_bit_cast(unsigned short, (_Float16)b);
        return (unsigned)ua | ((unsigned)ub << 16);
    };
    // P C-layout -> A-frag (R9/R10/R13-validated shfl version)
    auto mkpa = [&](const f32x16& S, int rb) -> half8 {
        unsigned w0 = pk2(S[rb + 0], S[rb + 1]);
        unsigned w1 = pk2(S[rb + 2], S[rb + 3]);
        unsigned w2 = pk2(S[rb + 4], S[rb + 5]);
        unsigned w3 = pk2(S[rb + 6], S[rb + 7]);
        unsigned x0 = (unsigned)__shfl_xor((int)w0, 32);
        unsigned x1 = (unsigned)__shfl_xor((int)w1, 32);
        unsigned x2 = (unsigned)__shfl_xor((int)w2, 32);
        unsigned x3 = (unsigned)__shfl_xor((int)w3, 32);
        u32x4 t;
        t[0] = hi ? x2 : w0;
        t[1] = hi ? x3 : w1;
        t[2] = hi ? w2 : x0;
        t[3] = hi ? w3 : x1;
        return __builtin_bit_cast(half8, t);
    };

    for (int t = 0; t < 16; ++t) {
        // ---- gate: K(t) resident (8 V-loads still in flight) ----
        WAITV(8);
        SB0();
        f32x16 s0 = {}, s1 = {};
        __builtin_amdgcn_s_setprio(1);
        s0 = __builtin_amdgcn_mfma_f32_32x32x16_f16(kf0, qf0, s0, 0, 0, 0);
        s0 = __builtin_amdgcn_mfma_f32_32x32x16_f16(kf1, qf1, s0, 0, 0, 0);
        s0 = __builtin_amdgcn_mfma_f32_32x32x16_f16(kf2, qf2, s0, 0, 0, 0);
        s0 = __builtin_amdgcn_mfma_f32_32x32x16_f16(kf3, qf3, s0, 0, 0, 0);
        s1 = __builtin_amdgcn_mfma_f32_32x32x16_f16(kf4, qf0, s1, 0, 0, 0);
        s1 = __builtin_amdgcn_mfma_f32_32x32x16_f16(kf5, qf1, s1, 0, 0, 0);
        s1 = __builtin_amdgcn_mfma_f32_32x32x16_f16(kf6, qf2, s1, 0, 0, 0);
        s1 = __builtin_amdgcn_mfma_f32_32x32x16_f16(kf7, qf3, s1, 0, 0, 0);
        __builtin_amdgcn_s_setprio(0);
        // ---- issue K(t+1) (clamped at t=15: dummy reload, keeps counts uniform)
        if (t < 15) { kp0 += 8192; kp1 += 8192; }
        GLD(kf0, kp0, 0);  GLD(kf1, kp0, 32);  GLD(kf2, kp0, 64);  GLD(kf3, kp0, 96);
        GLD(kf4, kp1, 0);  GLD(kf5, kp1, 32);  GLD(kf6, kp1, 64);  GLD(kf7, kp1, 96);

        // ---- lane-local online softmax (exp2 domain), defer-max THR=14 ----
        float a0 = fmaxf(fmaxf(s0[0], s0[1]), fmaxf(s0[2], s0[3]));
        float a1 = fmaxf(fmaxf(s0[4], s0[5]), fmaxf(s0[6], s0[7]));
        float a2 = fmaxf(fmaxf(s0[8], s0[9]), fmaxf(s0[10], s0[11]));
        float a3 = fmaxf(fmaxf(s0[12], s0[13]), fmaxf(s0[14], s0[15]));
        float b0 = fmaxf(fmaxf(s1[0], s1[1]), fmaxf(s1[2], s1[3]));
        float b1 = fmaxf(fmaxf(s1[4], s1[5]), fmaxf(s1[6], s1[7]));
        float b2 = fmaxf(fmaxf(s1[8], s1[9]), fmaxf(s1[10], s1[11]));
        float b3 = fmaxf(fmaxf(s1[12], s1[13]), fmaxf(s1[14], s1[15]));
        float lmax = fmaxf(fmaxf(fmaxf(a0, a1), fmaxf(a2, a3)),
                           fmaxf(fmaxf(b0, b1), fmaxf(b2, b3)));
        if (!__all(lmax <= m_q + 14.f)) {
            float tm = fmaxf(lmax, __shfl_xor(lmax, 32));
            float mn = fmaxf(m_q, tm);
            float sc = fexp2(m_q - mn);
            m_q = mn;
            l_q *= sc;
            int scb = __builtin_bit_cast(int, sc);
#pragma unroll
            for (int r = 0; r < 16; ++r) {
                int qr = (r & 3) + 8 * (r >> 2) + 4 * hi;
                float s = __builtin_bit_cast(float, __builtin_amdgcn_ds_bpermute(4 * qr, scb));
                oacc0[r] *= s;
                oacc1[r] *= s;
            }
        }
        float r0 = 0.f, r1 = 0.f, r2 = 0.f, r3 = 0.f;
#pragma unroll
        for (int i = 0; i < 16; i += 4) {
            float p0 = fexp2(s0[i + 0] - m_q); s0[i + 0] = p0; r0 += p0;
            float p1 = fexp2(s0[i + 1] - m_q); s0[i + 1] = p1; r1 += p1;
            float p2 = fexp2(s0[i + 2] - m_q); s0[i + 2] = p2; r2 += p2;
            float p3 = fexp2(s0[i + 3] - m_q); s0[i + 3] = p3; r3 += p3;
        }
#pragma unroll
        for (int i = 0; i < 16; i += 4) {
            float p0 = fexp2(s1[i + 0] - m_q); s1[i + 0] = p0; r0 += p0;
            float p1 = fexp2(s1[i + 1] - m_q); s1[i + 1] = p1; r1 += p1;
            float p2 = fexp2(s1[i + 2] - m_q); s1[i + 2] = p2; r2 += p2;
            float p3 = fexp2(s1[i + 3] - m_q); s1[i + 3] = p3; r3 += p3;
        }
        l_q += (r0 + r1) + (r2 + r3);

        // ---- P -> A-fragments ----
        half8 pa0 = mkpa(s0, 0), pa1 = mkpa(s0, 8);
        half8 pa2 = mkpa(s1, 0), pa3 = mkpa(s1, 8);

        // ---- gate: V(t) resident (8 K(t+1)-loads in flight) ----
        WAITV(8);
        SB0();
        __builtin_amdgcn_s_setprio(1);
        oacc0 = __builtin_amdgcn_mfma_f32_32x32x16_f16(pa0, vf0, oacc0, 0, 0, 0);
        oacc0 = __builtin_amdgcn_mfma_f32_32x32x16_f16(pa1, vf1, oacc0, 0, 0, 0);
        oacc0 = __builtin_amdgcn_mfma_f32_32x32x16_f16(pa2, vf2, oacc0, 0, 0, 0);
        oacc0 = __builtin_amdgcn_mfma_f32_32x32x16_f16(pa3, vf3, oacc0, 0, 0, 0);
        oacc1 = __builtin_amdgcn_mfma_f32_32x32x16_f16(pa0, vf4, oacc1, 0, 0, 0);
        oacc1 = __builtin_amdgcn_mfma_f32_32x32x16_f16(pa1, vf5, oacc1, 0, 0, 0);
        oacc1 = __builtin_amdgcn_mfma_f32_32x32x16_f16(pa2, vf6, oacc1, 0, 0, 0);
        oacc1 = __builtin_amdgcn_mfma_f32_32x32x16_f16(pa3, vf7, oacc1, 0, 0, 0);
        __builtin_amdgcn_s_setprio(0);
        // ---- issue V(t+1) (clamped at t=15) ----
        if (t < 15) { vp0 += 128; vp1 += 128; }
        GLD(vf0, vp0, 0);  GLD(vf1, vp0, 32);  GLD(vf2, vp0, 64);  GLD(vf3, vp0, 96);
        GLD(vf4, vp1, 0);  GLD(vf5, vp1, 32);  GLD(vf6, vp1, 64);  GLD(vf7, vp1, 96);
    }
    WAITV(0);                            // drain dummy prefetches
    SB0();

    // ---- combine hi-half l partials (once) ----
    l_q += __shfl_xor(l_q, 32);

    // ---- merge wave pairs (w <-> w+2) via LDS, exp2 domain ----
    if (hf == 1) {
        float* B = MRG + wq * 2176;
        B[lane] = m_q;
        B[64 + lane] = l_q;
#pragma unroll
        for (int r = 0; r < 16; ++r) {
            B[128 + r * 64 + lane] = oacc0[r];
            B[1152 + r * 64 + lane] = oacc1[r];
        }
    }
    __syncthreads();
    if (hf == 0) {
        float* B = MRG + wq * 2176;
        float m1 = B[lane], l1 = B[64 + lane];
        float m = fmaxf(m_q, m1);
        float e0 = fexp2(m_q - m), e1 = fexp2(m1 - m);
        float linv = 1.f / (l_q * e0 + l1 * e1);
        int e0b = __builtin_bit_cast(int, e0);
        int e1b = __builtin_bit_cast(int, e1);
        int ivb = __builtin_bit_cast(int, linv);
#pragma unroll
        for (int r = 0; r < 16; ++r) {
            int qr = (r & 3) + 8 * (r >> 2) + 4 * hi;
            float s0f = __builtin_bit_cast(float, __builtin_amdgcn_ds_bpermute(4 * qr, e0b));
            float s1f = __builtin_bit_cast(float, __builtin_amdgcn_ds_bpermute(4 * qr, e1b));
            float iv = __builtin_bit_cast(float, __builtin_amdgcn_ds_bpermute(4 * qr, ivb));
            float o0 = (oacc0[r] * s0f + B[128 + r * 64 + lane] * s1f) * iv;
            float o1 = (oacc1[r] * s0f + B[1152 + r * 64 + lane] * s1f) * iv;
            int qglob = qt * 64 + wq * 32 + qr;
            size_t base = ((size_t)(n * S_LEN + qglob)) * DM + h * HD + l31;
            Oatt[base] = (_Float16)o0;
            Oatt[base + 32] = (_Float16)o1;
        }
    }
}

// ---------------------------------------------------------------------------
// Projection GEMM, m97-style: 128x128 tile, BK=64, LDS double-buffered via
// gload16 (inverse-swizzled source, linear dest), 4 waves a 64x64 output.
// Grid 256 = 8 ot-strips x 32 mt; ot pinned per XCD (W strip L2-resident).
// ---------------------------------------------------------------------------
__global__ __launch_bounds__(256) void k_proj(const _Float16* __restrict__ A,
                                              const _Float16* __restrict__ W,
                                              const float* __restrict__ bias,
                                              float* __restrict__ out) {
    __shared__ _Float16 As[2][128 * 64];   // 16 KB each
    __shared__ _Float16 Ws[2][128 * 64];

    const int id = blockIdx.x;
    const int ot = id & 7;     // O strip of 128
    const int mt = id >> 3;    // M strip of 128 (0..31)
    const int tid = threadIdx.x;
    const int w = tid >> 6;
    const int lane = tid & 63;
    const int lr = lane & 15, lg = lane >> 4;
    const int wm = (w >> 1) * 64, wn = (w & 1) * 64;

    const int rr = lane >> 3;
    const int cb = (lane & 7) * 16;
    const int gcb = cb ^ (rr << 4);

    const char* Abase = (const char*)(A + (size_t)(mt * 128) * DM);
    const char* Wbase = (const char*)(W + (size_t)(ot * 128) * DM);

    auto STAGE = [&](int kt, int b) {
#pragma unroll
        for (int r = 0; r < 4; ++r) {
            int row = r * 32 + w * 8 + rr;
            gload16(Abase + (size_t)row * 2048 + kt * 128 + gcb,
                    (char*)&As[b][0] + (r * 32 + w * 8) * 128);
            gload16(Wbase + (size_t)row * 2048 + kt * 128 + gcb,
                    (char*)&Ws[b][0] + (r * 32 + w * 8) * 128);
        }
    };

    f32x4 zero = {0.f, 0.f, 0.f, 0.f};
    f32x4 acc[4][4];
#pragma unroll
    for (int mi = 0; mi < 4; ++mi)
#pragma unroll
        for (int ni = 0; ni < 4; ++ni) acc[mi][ni] = zero;

    auto COMPUTE = [&](int b) {
        const char* ldsA = (const char*)&As[b][0];
        const char* ldsW = (const char*)&Ws[b][0];
        half8 af[4][2], wf[4][2];
#pragma unroll
        for (int mi = 0; mi < 4; ++mi) {
            int row = wm + mi * 16 + lr;
            int sw = (row & 7) << 4;
            const char* p = ldsA + row * 128;
            af[mi][0] = *(const half8*)(p + ((lg * 16) ^ sw));
            af[mi][1] = *(const half8*)(p + ((64 + lg * 16) ^ sw));
        }
#pragma unroll
        for (int ni = 0; ni < 4; ++ni) {
            int row = wn + ni * 16 + lr;
            int sw = (row & 7) << 4;
            const char* p = ldsW + row * 128;
            wf[ni][0] = *(const half8*)(p + ((lg * 16) ^ sw));
            wf[ni][1] = *(const half8*)(p + ((64 + lg * 16) ^ sw));
        }
#pragma unroll
        for (int mi = 0; mi < 4; ++mi)
#pragma unroll
            for (int ni = 0; ni < 4; ++ni) {
                acc[mi][ni] = __builtin_amdgcn_mfma_f32_16x16x32_f16(af[mi][0], wf[ni][0], acc[mi][ni], 0, 0, 0);
                acc[mi][ni] = __builtin_amdgcn_mfma_f32_16x16x32_f16(af[mi][1], wf[ni][1], acc[mi][ni], 0, 0, 0);
            }
    };

    STAGE(0, 0);
    __syncthreads();
    for (int kt = 0; kt < 15; ++kt) {
        STAGE(kt + 1, (kt & 1) ^ 1);
        COMPUTE(kt & 1);
        __syncthreads();
    }
    COMPUTE(1);   // kt=15, no stage -> no DMA outstanding at endpgm

    // epilogue: C row = m (A dim), col = o (W dim)
#pragma unroll
    for (int ni = 0; ni < 4; ++ni) {
        int o = ot * 128 + wn + ni * 16 + lr;
        float b = bias[o];
#pragma unroll
        for (int mi = 0; mi < 4; ++mi)
#pragma unroll
            for (int i = 0; i < 4; ++i) {
                int m = mt * 128 + wm + mi * 16 + lg * 4 + i;
                out[(size_t)m * DM + o] = acc[mi][ni][i] + b;
            }
    }
}

// ---------------------------------------------------------------------------
extern "C" void kernel_launch(void* const* d_in, const int* in_sizes, int n_in,
                              void* d_out, int out_size, void* d_ws, size_t ws_size,
                              hipStream_t stream) {
    const float* Q = (const float*)d_in[0];
    const float* K = (const float*)d_in[1];
    const float* V = (const float*)d_in[2];
    const float* Wo = (const float*)d_in[3];
    const float* bo = (const float*)d_in[4];
    float* out = (float*)d_out;
    char* ws = (char*)d_ws;

    _Float16* Kh = (_Float16*)(ws);                     // 8 MB
    _Float16* Vt = (_Float16*)(ws + (8u << 20));        // 8 MB
    _Float16* Oatt = (_Float16*)(ws + (16u << 20));     // 8 MB
    _Float16* Wh = (_Float16*)(ws + (24u << 20));       // 2 MB

    k_prep<<<6144, 256, 0, stream>>>(K, V, Wo, Kh, Vt, Wh);
    k_attn<<<1024, 256, 0, stream>>>(Q, Kh, Vt, Oatt);
    k_proj<<<256, 256, 0, stream>>>(Oatt, Wh, bo, out);
}

// Round 15
// 102.191 us; speedup vs baseline: 1.6052x; 1.6052x over previous
//
#include <hip/hip_runtime.h>

typedef _Float16 half8 __attribute__((ext_vector_type(8)));
typedef _Float16 half4 __attribute__((ext_vector_type(4)));
typedef float f32x4 __attribute__((ext_vector_type(4)));
typedef float f32x16 __attribute__((ext_vector_type(16)));
typedef unsigned u32x4 __attribute__((ext_vector_type(4)));

#define N_B 2
#define S_LEN 2048
#define NH 16
#define HD 64
#define DM 1024
#define LOG2E 1.44269504088896f

__device__ __forceinline__ void gload16(const void* g, void* l) {
    __builtin_amdgcn_global_load_lds(
        (const __attribute__((address_space(1))) unsigned int*)g,
        (__attribute__((address_space(3))) unsigned int*)l, 16, 0, 0);
}

__device__ __forceinline__ float fexp2(float x) {
    float r;
    asm("v_exp_f32 %0, %1" : "=v"(r) : "v"(x));
    return r;
}

// ---------------------------------------------------------------------------
// Fused prep (one launch): blocks [0,4096) regroup K -> f16 [n][h][s][d];
// [4096,5120) transpose V -> Vt f16 [n][h][d][s]; [5120,6144) cvt W -> f16.
// ---------------------------------------------------------------------------
__global__ __launch_bounds__(256) void k_prep(const float* __restrict__ K,
                                              const float* __restrict__ V,
                                              const float* __restrict__ Wo,
                                              _Float16* __restrict__ Kh,
                                              _Float16* __restrict__ Vt,
                                              _Float16* __restrict__ Wh) {
    __shared__ _Float16 tile[64][65];
    const int id = blockIdx.x;
    if (id < 4096) {                       // ---- K regroup
        int i = id * 256 + threadIdx.x;
        float4 v = ((const float4*)K)[i];
        int base = i * 4;
        int d = base & 63;
        int h = (base >> 6) & 15;
        int s = (base >> 10) & 2047;
        int n = base >> 21;
        size_t o = ((size_t)((n * NH + h) * S_LEN + s)) * HD + d;
        half4 hv = {(_Float16)v.x, (_Float16)v.y, (_Float16)v.z, (_Float16)v.w};
        *(half4*)(Kh + o) = hv;
    } else if (id < 5120) {                // ---- V transpose
        int b = id - 4096;
        int st = b & 31, h = (b >> 5) & 15, n = b >> 9;
        int c = threadIdx.x & 63, r0 = threadIdx.x >> 6;
#pragma unroll
        for (int i = 0; i < 16; ++i) {
            int r = i * 4 + r0;
            tile[r][c] = (_Float16)V[((size_t)(n * S_LEN) + st * 64 + r) * DM + h * HD + c];
        }
        __syncthreads();
#pragma unroll
        for (int i = 0; i < 16; ++i) {
            int d = i * 4 + r0;
            Vt[((size_t)((n * NH + h) * HD + d)) * S_LEN + st * 64 + c] = tile[c][d];
        }
    } else {                               // ---- W convert
        int i = (id - 5120) * 256 + threadIdx.x;
        float4 v = ((const float4*)Wo)[i];
        half4 hv = {(_Float16)v.x, (_Float16)v.y, (_Float16)v.z, (_Float16)v.w};
        *(half4*)(Wh + (size_t)i * 4) = hv;
    }
}

// ---------------------------------------------------------------------------
// Flash attention, SOFTWARE-PIPELINED rounds on the R10 skeleton:
// s(t) is carried across the loop; round t = {softmax(t)+pack(t)} ->
// barrier1 (drains V(t), K(t+1) DMA; softmax covered the latency) ->
// {QK(t+1) || PV(t)} (one independent 16-MFMA + 16-ds_read pool) ->
// STAGE_K(t+2) (its buffer has no readers this round) -> barrier2 ->
// STAGE_V(t+1) (after all PV(t) reads). Same barriers/staging/math as the
// 74.4us base; only the compute order across rounds changed.
// Block = 8 waves (512 thr), QBLK=128; wave w: q-subtile (w&3), KV half
// (w>>2). K double-buffered, V single-buffered. No DMA at endpgm.
// ---------------------------------------------------------------------------
__global__ __launch_bounds__(512, 4) void k_attn(const float* __restrict__ Q,
                                                 const _Float16* __restrict__ Kh,
                                                 const _Float16* __restrict__ Vth,
                                                 _Float16* __restrict__ Oatt) {
    __shared__ char SB[49152];
    // [0,32768): K dbuf (b,hf) 8KB each ; [32768,49152): V single (hf) 8KB

    // XCD swizzle (bijective on 512 = 8 * 64): 4 nh per XCD, 16 qt each
    const int id = blockIdx.x;
    const int xcd = id & 7;
    const int sl = id >> 3;              // 0..63
    const int nh = xcd + 8 * (sl >> 4);
    const int qt = sl & 15;              // q tile of 128

    const int tid = threadIdx.x;
    const int w = tid >> 6;              // 0..7
    const int wq = w & 3;                // q-subtile
    const int hf = w >> 2;               // KV half
    const int lane = tid & 63;
    const int l31 = lane & 31;
    const int hi = lane >> 5;
    const int n = nh >> 4, h = nh & 15;

    const size_t head = (size_t)nh * S_LEN * HD;
    const char* Khead = (const char*)(Kh + head);
    const char* Vhead = (const char*)(Vth + head);

    // ---- Q fragments (B-frag: col q=l31, k=8hi+j per 16-d chunk), LOG2E-scaled
    const int qg = qt * 128 + wq * 32 + l31;
    const float* qbase = Q + ((size_t)(n * S_LEN) + qg) * DM + h * HD;
    auto mkqf = [&](int c) -> half8 {
        float4 a = *(const float4*)(qbase + 16 * c + 8 * hi);
        float4 b = *(const float4*)(qbase + 16 * c + 8 * hi + 4);
        half8 r = {(_Float16)(a.x * LOG2E), (_Float16)(a.y * LOG2E),
                   (_Float16)(a.z * LOG2E), (_Float16)(a.w * LOG2E),
                   (_Float16)(b.x * LOG2E), (_Float16)(b.y * LOG2E),
                   (_Float16)(b.z * LOG2E), (_Float16)(b.w * LOG2E)};
        return r;
    };
    half8 qf0 = mkqf(0), qf1 = mkqf(1), qf2 = mkqf(2), qf3 = mkqf(3);

    f32x16 oacc0 = {}, oacc1 = {};
    float m_q = -1e30f, l_q = 0.f;       // per q=l31 (2x redundant over hi)

    // staging geometry: wave w stages slices wq*2+j of its half's tiles
    const int rr = lane >> 3;
    const int cb = (lane & 7) * 16;
    const int gcb = cb ^ (rr << 4);      // inverse-swizzled global column

    auto kbuf = [&](int b, int half) -> char* { return SB + (b * 2 + half) * 8192; };
    auto vbuf = [&](int half) -> char* { return SB + 32768 + half * 8192; };

    auto STAGE_K = [&](int t, int b) {
#pragma unroll
        for (int j = 0; j < 2; ++j) {
            int slice = wq * 2 + j;            // 0..7
            int row = slice * 8 + rr;          // 0..63
            int key = hf * 1024 + t * 64 + row;
            gload16(Khead + (size_t)key * 128 + gcb, kbuf(b, hf) + slice * 1024);
        }
    };
    auto STAGE_V = [&](int t) {
#pragma unroll
        for (int j = 0; j < 2; ++j) {
            int slice = wq * 2 + j;
            int row = slice * 8 + rr;
            gload16(Vhead + (size_t)row * 4096 + hf * 2048 + t * 128 + gcb,
                    vbuf(hf) + slice * 1024);
        }
    };

    const int rmask = (l31 & 7) << 4;
    auto ldF = [&](const char* lds, int blk, int c) -> half8 {
        int off = (32 * blk + l31) * 128 + ((32 * c + 16 * hi) ^ rmask);
        return *(const half8*)(lds + off);
    };

    auto pk2 = [&](float a, float b) -> unsigned {
        unsigned short ua = __builtin_bit_cast(unsigned short, (_Float16)a);
        unsigned short ub = __builtin_bit_cast(unsigned short, (_Float16)b);
        return (unsigned)ua | ((unsigned)ub << 16);
    };
    auto mkpa = [&](const f32x16& S, int rb) -> half8 {
        unsigned w0 = pk2(S[rb + 0], S[rb + 1]);
        unsigned w1 = pk2(S[rb + 2], S[rb + 3]);
        unsigned w2 = pk2(S[rb + 4], S[rb + 5]);
        unsigned w3 = pk2(S[rb + 6], S[rb + 7]);
        unsigned x0 = (unsigned)__shfl_xor((int)w0, 32);
        unsigned x1 = (unsigned)__shfl_xor((int)w1, 32);
        unsigned x2 = (unsigned)__shfl_xor((int)w2, 32);
        unsigned x3 = (unsigned)__shfl_xor((int)w3, 32);
        u32x4 t;
        t[0] = hi ? x2 : w0;
        t[1] = hi ? x3 : w1;
        t[2] = hi ? w2 : x0;
        t[3] = hi ? w3 : x1;
        return __builtin_bit_cast(half8, t);
    };

    // ---- prologue: K(0) resident, QK(0), then V(0)/K(1) in flight ----
    STAGE_K(0, 0);
    __syncthreads();                     // drains K(0)
    STAGE_V(0);
    STAGE_K(1, 1);
    f32x16 s0 = {}, s1 = {};
    {
        const char* ldsK = kbuf(0, hf);
        __builtin_amdgcn_s_setprio(1);
        s0 = __builtin_amdgcn_mfma_f32_32x32x16_f16(ldF(ldsK, 0, 0), qf0, s0, 0, 0, 0);
        s0 = __builtin_amdgcn_mfma_f32_32x32x16_f16(ldF(ldsK, 0, 1), qf1, s0, 0, 0, 0);
        s0 = __builtin_amdgcn_mfma_f32_32x32x16_f16(ldF(ldsK, 0, 2), qf2, s0, 0, 0, 0);
        s0 = __builtin_amdgcn_mfma_f32_32x32x16_f16(ldF(ldsK, 0, 3), qf3, s0, 0, 0, 0);
        s1 = __builtin_amdgcn_mfma_f32_32x32x16_f16(ldF(ldsK, 1, 0), qf0, s1, 0, 0, 0);
        s1 = __builtin_amdgcn_mfma_f32_32x32x16_f16(ldF(ldsK, 1, 1), qf1, s1, 0, 0, 0);
        s1 = __builtin_amdgcn_mfma_f32_32x32x16_f16(ldF(ldsK, 1, 2), qf2, s1, 0, 0, 0);
        s1 = __builtin_amdgcn_mfma_f32_32x32x16_f16(ldF(ldsK, 1, 3), qf3, s1, 0, 0, 0);
        __builtin_amdgcn_s_setprio(0);
    }

    for (int t = 0; t < 16; ++t) {
        // ---- softmax(t) + pack(t)  [VALU/TRANS only; covers DMA drain] ----
        float mx[16];
#pragma unroll
        for (int i = 0; i < 16; ++i) mx[i] = fmaxf(s0[i], s1[i]);
#pragma unroll
        for (int st = 8; st > 0; st >>= 1)
#pragma unroll
            for (int i = 0; i < 8; ++i)
                if (i < st) mx[i] = fmaxf(mx[i], mx[i + st]);
        float tm = fmaxf(mx[0], __shfl_xor(mx[0], 32));
        if (!__all(tm <= m_q + 8.f)) {
            float mn = fmaxf(m_q, tm);
            float sc = fexp2(m_q - mn);
            m_q = mn;
            l_q *= sc;
            int scb = __builtin_bit_cast(int, sc);
#pragma unroll
            for (int r = 0; r < 16; ++r) {
                int qr = (r & 3) + 8 * (r >> 2) + 4 * hi;
                float s = __builtin_bit_cast(float, __builtin_amdgcn_ds_bpermute(4 * qr, scb));
                oacc0[r] *= s;
                oacc1[r] *= s;
            }
        }
        float rs = 0.f;
#pragma unroll
        for (int i = 0; i < 16; ++i) { float p = fexp2(s0[i] - m_q); s0[i] = p; rs += p; }
#pragma unroll
        for (int i = 0; i < 16; ++i) { float p = fexp2(s1[i] - m_q); s1[i] = p; rs += p; }
        rs += __shfl_xor(rs, 32);
        l_q += rs;
        half8 pa0 = mkpa(s0, 0), pa1 = mkpa(s0, 8);
        half8 pa2 = mkpa(s1, 0), pa3 = mkpa(s1, 8);

        __syncthreads();                 // #1: V(t) and K(t+1) now resident

        // ---- QK(t+1) || PV(t): one independent MFMA+LDS pool ----
        f32x16 n0 = {}, n1 = {};
        __builtin_amdgcn_s_setprio(1);
        if (t < 15) {
            const char* ldsK = kbuf((t + 1) & 1, hf);
            n0 = __builtin_amdgcn_mfma_f32_32x32x16_f16(ldF(ldsK, 0, 0), qf0, n0, 0, 0, 0);
            n0 = __builtin_amdgcn_mfma_f32_32x32x16_f16(ldF(ldsK, 0, 1), qf1, n0, 0, 0, 0);
            n0 = __builtin_amdgcn_mfma_f32_32x32x16_f16(ldF(ldsK, 0, 2), qf2, n0, 0, 0, 0);
            n0 = __builtin_amdgcn_mfma_f32_32x32x16_f16(ldF(ldsK, 0, 3), qf3, n0, 0, 0, 0);
            n1 = __builtin_amdgcn_mfma_f32_32x32x16_f16(ldF(ldsK, 1, 0), qf0, n1, 0, 0, 0);
            n1 = __builtin_amdgcn_mfma_f32_32x32x16_f16(ldF(ldsK, 1, 1), qf1, n1, 0, 0, 0);
            n1 = __builtin_amdgcn_mfma_f32_32x32x16_f16(ldF(ldsK, 1, 2), qf2, n1, 0, 0, 0);
            n1 = __builtin_amdgcn_mfma_f32_32x32x16_f16(ldF(ldsK, 1, 3), qf3, n1, 0, 0, 0);
        }
        {
            const char* ldsV = vbuf(hf);
            oacc0 = __builtin_amdgcn_mfma_f32_32x32x16_f16(pa0, ldF(ldsV, 0, 0), oacc0, 0, 0, 0);
            oacc0 = __builtin_amdgcn_mfma_f32_32x32x16_f16(pa1, ldF(ldsV, 0, 1), oacc0, 0, 0, 0);
            oacc0 = __builtin_amdgcn_mfma_f32_32x32x16_f16(pa2, ldF(ldsV, 0, 2), oacc0, 0, 0, 0);
            oacc0 = __builtin_amdgcn_mfma_f32_32x32x16_f16(pa3, ldF(ldsV, 0, 3), oacc0, 0, 0, 0);
            oacc1 = __builtin_amdgcn_mfma_f32_32x32x16_f16(pa0, ldF(ldsV, 1, 0), oacc1, 0, 0, 0);
            oacc1 = __builtin_amdgcn_mfma_f32_32x32x16_f16(pa1, ldF(ldsV, 1, 1), oacc1, 0, 0, 0);
            oacc1 = __builtin_amdgcn_mfma_f32_32x32x16_f16(pa2, ldF(ldsV, 1, 2), oacc1, 0, 0, 0);
            oacc1 = __builtin_amdgcn_mfma_f32_32x32x16_f16(pa3, ldF(ldsV, 1, 3), oacc1, 0, 0, 0);
        }
        __builtin_amdgcn_s_setprio(0);

        if (t < 14) STAGE_K(t + 2, t & 1);  // buffer has no readers this round

        __syncthreads();                 // #2: all PV(t) reads of vbuf done

        if (t < 15) STAGE_V(t + 1);      // safe to overwrite vbuf now

        s0 = n0; s1 = n1;                // SSA rename, no copies expected
    }

    // ---- merge wave pairs (w <-> w+4) via LDS, exp2 domain ----
    // (loop ended with barrier #2 at t=15; no DMA outstanding)
    float* MRG = (float*)SB;             // 4 regions x 2176 f32 (34.8 KB)
    if (hf == 1) {
        float* B = MRG + wq * 2176;
        B[lane] = m_q;
        B[64 + lane] = l_q;
#pragma unroll
        for (int r = 0; r < 16; ++r) {
            B[128 + r * 64 + lane] = oacc0[r];
            B[1152 + r * 64 + lane] = oacc1[r];
        }
    }
    __syncthreads();
    if (hf == 0) {
        float* B = MRG + wq * 2176;
        float m1 = B[lane], l1 = B[64 + lane];
        float m = fmaxf(m_q, m1);
        float e0 = fexp2(m_q - m), e1 = fexp2(m1 - m);
        float linv = 1.f / (l_q * e0 + l1 * e1);
        int e0b = __builtin_bit_cast(int, e0);
        int e1b = __builtin_bit_cast(int, e1);
        int ivb = __builtin_bit_cast(int, linv);
#pragma unroll
        for (int r = 0; r < 16; ++r) {
            int qr = (r & 3) + 8 * (r >> 2) + 4 * hi;
            float s0f = __builtin_bit_cast(float, __builtin_amdgcn_ds_bpermute(4 * qr, e0b));
            float s1f = __builtin_bit_cast(float, __builtin_amdgcn_ds_bpermute(4 * qr, e1b));
            float iv = __builtin_bit_cast(float, __builtin_amdgcn_ds_bpermute(4 * qr, ivb));
            float o0 = (oacc0[r] * s0f + B[128 + r * 64 + lane] * s1f) * iv;
            float o1 = (oacc1[r] * s0f + B[1152 + r * 64 + lane] * s1f) * iv;
            int qglob = qt * 128 + wq * 32 + qr;
            size_t base = ((size_t)(n * S_LEN + qglob)) * DM + h * HD + l31;
            Oatt[base] = (_Float16)o0;
            Oatt[base + 32] = (_Float16)o1;
        }
    }
}

// ---------------------------------------------------------------------------
// Projection GEMM, m97-style: 128x128 tile, BK=64, LDS double-buffered via
// gload16 (inverse-swizzled source, linear dest), 4 waves a 64x64 output.
// Grid 256 = 8 ot-strips x 32 mt; ot pinned per XCD (W strip L2-resident).
// ---------------------------------------------------------------------------
__global__ __launch_bounds__(256) void k_proj(const _Float16* __restrict__ A,
                                              const _Float16* __restrict__ W,
                                              const float* __restrict__ bias,
                                              float* __restrict__ out) {
    __shared__ _Float16 As[2][128 * 64];   // 16 KB each
    __shared__ _Float16 Ws[2][128 * 64];

    const int id = blockIdx.x;
    const int ot = id & 7;     // O strip of 128
    const int mt = id >> 3;    // M strip of 128 (0..31)
    const int tid = threadIdx.x;
    const int w = tid >> 6;
    const int lane = tid & 63;
    const int lr = lane & 15, lg = lane >> 4;
    const int wm = (w >> 1) * 64, wn = (w & 1) * 64;

    const int rr = lane >> 3;
    const int cb = (lane & 7) * 16;
    const int gcb = cb ^ (rr << 4);

    const char* Abase = (const char*)(A + (size_t)(mt * 128) * DM);
    const char* Wbase = (const char*)(W + (size_t)(ot * 128) * DM);

    auto STAGE = [&](int kt, int b) {
#pragma unroll
        for (int r = 0; r < 4; ++r) {
            int row = r * 32 + w * 8 + rr;
            gload16(Abase + (size_t)row * 2048 + kt * 128 + gcb,
                    (char*)&As[b][0] + (r * 32 + w * 8) * 128);
            gload16(Wbase + (size_t)row * 2048 + kt * 128 + gcb,
                    (char*)&Ws[b][0] + (r * 32 + w * 8) * 128);
        }
    };

    f32x4 zero = {0.f, 0.f, 0.f, 0.f};
    f32x4 acc[4][4];
#pragma unroll
    for (int mi = 0; mi < 4; ++mi)
#pragma unroll
        for (int ni = 0; ni < 4; ++ni) acc[mi][ni] = zero;

    auto COMPUTE = [&](int b) {
        const char* ldsA = (const char*)&As[b][0];
        const char* ldsW = (const char*)&Ws[b][0];
        half8 af[4][2], wf[4][2];
#pragma unroll
        for (int mi = 0; mi < 4; ++mi) {
            int row = wm + mi * 16 + lr;
            int sw = (row & 7) << 4;
            const char* p = ldsA + row * 128;
            af[mi][0] = *(const half8*)(p + ((lg * 16) ^ sw));
            af[mi][1] = *(const half8*)(p + ((64 + lg * 16) ^ sw));
        }
#pragma unroll
        for (int ni = 0; ni < 4; ++ni) {
            int row = wn + ni * 16 + lr;
            int sw = (row & 7) << 4;
            const char* p = ldsW + row * 128;
            wf[ni][0] = *(const half8*)(p + ((lg * 16) ^ sw));
            wf[ni][1] = *(const half8*)(p + ((64 + lg * 16) ^ sw));
        }
#pragma unroll
        for (int mi = 0; mi < 4; ++mi)
#pragma unroll
            for (int ni = 0; ni < 4; ++ni) {
                acc[mi][ni] = __builtin_amdgcn_mfma_f32_16x16x32_f16(af[mi][0], wf[ni][0], acc[mi][ni], 0, 0, 0);
                acc[mi][ni] = __builtin_amdgcn_mfma_f32_16x16x32_f16(af[mi][1], wf[ni][1], acc[mi][ni], 0, 0, 0);
            }
    };

    STAGE(0, 0);
    __syncthreads();
    for (int kt = 0; kt < 15; ++kt) {
        STAGE(kt + 1, (kt & 1) ^ 1);
        COMPUTE(kt & 1);
        __syncthreads();
    }
    COMPUTE(1);   // kt=15, no stage -> no DMA outstanding at endpgm

    // epilogue: C row = m (A dim), col = o (W dim)
#pragma unroll
    for (int ni = 0; ni < 4; ++ni) {
        int o = ot * 128 + wn + ni * 16 + lr;
        float b = bias[o];
#pragma unroll
        for (int mi = 0; mi < 4; ++mi)
#pragma unroll
            for (int i = 0; i < 4; ++i) {
                int m = mt * 128 + wm + mi * 16 + lg * 4 + i;
                out[(size_t)m * DM + o] = acc[mi][ni][i] + b;
            }
    }
}

// ---------------------------------------------------------------------------
extern "C" void kernel_launch(void* const* d_in, const int* in_sizes, int n_in,
                              void* d_out, int out_size, void* d_ws, size_t ws_size,
                              hipStream_t stream) {
    const float* Q = (const float*)d_in[0];
    const float* K = (const float*)d_in[1];
    const float* V = (const float*)d_in[2];
    const float* Wo = (const float*)d_in[3];
    const float* bo = (const float*)d_in[4];
    float* out = (float*)d_out;
    char* ws = (char*)d_ws;

    _Float16* Kh = (_Float16*)(ws);                     // 8 MB
    _Float16* Vt = (_Float16*)(ws + (8u << 20));        // 8 MB
    _Float16* Oatt = (_Float16*)(ws + (16u << 20));     // 8 MB
    _Float16* Wh = (_Float16*)(ws + (24u << 20));       // 2 MB

    k_prep<<<6144, 256, 0, stream>>>(K, V, Wo, Kh, Vt, Wh);
    k_attn<<<512, 512, 0, stream>>>(Q, Kh, Vt, Oatt);
    k_proj<<<256, 256, 0, stream>>>(Oatt, Wh, bo, out);
}

// Round 16
// 93.289 us; speedup vs baseline: 1.7583x; 1.0954x over previous
//
#include <hip/hip_runtime.h>

typedef _Float16 half8 __attribute__((ext_vector_type(8)));
typedef _Float16 half4 __attribute__((ext_vector_type(4)));
typedef float f32x4 __attribute__((ext_vector_type(4)));
typedef float f32x16 __attribute__((ext_vector_type(16)));
typedef unsigned u32x4 __attribute__((ext_vector_type(4)));

#define N_B 2
#define S_LEN 2048
#define NH 16
#define HD 64
#define DM 1024
#define LOG2E 1.44269504088896f

__device__ __forceinline__ void gload16(const void* g, void* l) {
    __builtin_amdgcn_global_load_lds(
        (const __attribute__((address_space(1))) unsigned int*)g,
        (__attribute__((address_space(3))) unsigned int*)l, 16, 0, 0);
}

__device__ __forceinline__ float fexp2(float x) {
    float r;
    asm("v_exp_f32 %0, %1" : "=v"(r) : "v"(x));
    return r;
}

// ---------------------------------------------------------------------------
// Fused prep (one launch): blocks [0,4096) regroup K -> f16 [n][h][s][d];
// [4096,5120) transpose V -> Vt f16 [n][h][d][s]; [5120,6144) cvt W -> f16.
// ---------------------------------------------------------------------------
__global__ __launch_bounds__(256) void k_prep(const float* __restrict__ K,
                                              const float* __restrict__ V,
                                              const float* __restrict__ Wo,
                                              _Float16* __restrict__ Kh,
                                              _Float16* __restrict__ Vt,
                                              _Float16* __restrict__ Wh) {
    __shared__ _Float16 tile[64][65];
    const int id = blockIdx.x;
    if (id < 4096) {                       // ---- K regroup
        int i = id * 256 + threadIdx.x;
        float4 v = ((const float4*)K)[i];
        int base = i * 4;
        int d = base & 63;
        int h = (base >> 6) & 15;
        int s = (base >> 10) & 2047;
        int n = base >> 21;
        size_t o = ((size_t)((n * NH + h) * S_LEN + s)) * HD + d;
        half4 hv = {(_Float16)v.x, (_Float16)v.y, (_Float16)v.z, (_Float16)v.w};
        *(half4*)(Kh + o) = hv;
    } else if (id < 5120) {                // ---- V transpose
        int b = id - 4096;
        int st = b & 31, h = (b >> 5) & 15, n = b >> 9;
        int c = threadIdx.x & 63, r0 = threadIdx.x >> 6;
#pragma unroll
        for (int i = 0; i < 16; ++i) {
            int r = i * 4 + r0;
            tile[r][c] = (_Float16)V[((size_t)(n * S_LEN) + st * 64 + r) * DM + h * HD + c];
        }
        __syncthreads();
#pragma unroll
        for (int i = 0; i < 16; ++i) {
            int d = i * 4 + r0;
            Vt[((size_t)((n * NH + h) * HD + d)) * S_LEN + st * 64 + c] = tile[c][d];
        }
    } else {                               // ---- W convert
        int i = (id - 5120) * 256 + threadIdx.x;
        float4 v = ((const float4*)Wo)[i];
        half4 hv = {(_Float16)v.x, (_Float16)v.y, (_Float16)v.z, (_Float16)v.w};
        *(half4*)(Wh + (size_t)i * 4) = hv;
    }
}

// ---------------------------------------------------------------------------
// Flash attention (best-measured R10 configuration, 74.4us): 32x32 MFMA,
// in-register P (shfl-mkpa), wave-level KV split. Block = 8 waves (512 thr),
// QBLK=128; wave w: q-subtile (w&3), KV half (w>>2). K double-buffered;
// V single-buffered, drained by the mid-round __syncthreads. defer-max
// THR=8. Only change vs benched version: P f32->f16 packing uses
// v_cvt_pkrtz_f16_f32 (1 instr per pair instead of 3).
// ---------------------------------------------------------------------------
__global__ __launch_bounds__(512, 4) void k_attn(const float* __restrict__ Q,
                                                 const _Float16* __restrict__ Kh,
                                                 const _Float16* __restrict__ Vth,
                                                 _Float16* __restrict__ Oatt) {
    __shared__ char SB[49152];
    // [0,32768): K dbuf (b,hf) 8KB each ; [32768,49152): V single (hf) 8KB

    // XCD swizzle (bijective on 512 = 8 * 64): 4 nh per XCD, 16 qt each
    const int id = blockIdx.x;
    const int xcd = id & 7;
    const int sl = id >> 3;              // 0..63
    const int nh = xcd + 8 * (sl >> 4);
    const int qt = sl & 15;              // q tile of 128

    const int tid = threadIdx.x;
    const int w = tid >> 6;              // 0..7
    const int wq = w & 3;                // q-subtile
    const int hf = w >> 2;               // KV half
    const int lane = tid & 63;
    const int l31 = lane & 31;
    const int hi = lane >> 5;
    const int n = nh >> 4, h = nh & 15;

    const size_t head = (size_t)nh * S_LEN * HD;
    const char* Khead = (const char*)(Kh + head);
    const char* Vhead = (const char*)(Vth + head);

    // ---- Q fragments (B-frag: col q=l31, k=8hi+j per 16-d chunk), LOG2E-scaled
    const int qg = qt * 128 + wq * 32 + l31;
    const float* qbase = Q + ((size_t)(n * S_LEN) + qg) * DM + h * HD;
    auto mkqf = [&](int c) -> half8 {
        float4 a = *(const float4*)(qbase + 16 * c + 8 * hi);
        float4 b = *(const float4*)(qbase + 16 * c + 8 * hi + 4);
        half8 r = {(_Float16)(a.x * LOG2E), (_Float16)(a.y * LOG2E),
                   (_Float16)(a.z * LOG2E), (_Float16)(a.w * LOG2E),
                   (_Float16)(b.x * LOG2E), (_Float16)(b.y * LOG2E),
                   (_Float16)(b.z * LOG2E), (_Float16)(b.w * LOG2E)};
        return r;
    };
    half8 qf0 = mkqf(0), qf1 = mkqf(1), qf2 = mkqf(2), qf3 = mkqf(3);

    f32x16 oacc0 = {}, oacc1 = {};
    float m_q = -1e30f, l_q = 0.f;       // per q=l31 (2x redundant over hi)

    // staging geometry: wave w stages slices wq*2+j of its half's tiles
    const int rr = lane >> 3;
    const int cb = (lane & 7) * 16;
    const int gcb = cb ^ (rr << 4);      // inverse-swizzled global column

    auto kbuf = [&](int b, int half) -> char* { return SB + (b * 2 + half) * 8192; };
    auto vbuf = [&](int half) -> char* { return SB + 32768 + half * 8192; };

    auto STAGE_K = [&](int t, int b) {
#pragma unroll
        for (int j = 0; j < 2; ++j) {
            int slice = wq * 2 + j;            // 0..7
            int row = slice * 8 + rr;          // 0..63
            int key = hf * 1024 + t * 64 + row;
            gload16(Khead + (size_t)key * 128 + gcb, kbuf(b, hf) + slice * 1024);
        }
    };
    auto STAGE_V = [&](int t) {
#pragma unroll
        for (int j = 0; j < 2; ++j) {
            int slice = wq * 2 + j;
            int row = slice * 8 + rr;
            gload16(Vhead + (size_t)row * 4096 + hf * 2048 + t * 128 + gcb,
                    vbuf(hf) + slice * 1024);
        }
    };

    const int rmask = (l31 & 7) << 4;
    auto ldF = [&](const char* lds, int blk, int c) -> half8 {
        int off = (32 * blk + l31) * 128 + ((32 * c + 16 * hi) ^ rmask);
        return *(const half8*)(lds + off);
    };

    auto pkrtz = [&](float a, float b) -> unsigned {
        return __builtin_bit_cast(unsigned, __builtin_amdgcn_cvt_pkrtz(a, b));
    };
    auto mkpa = [&](const f32x16& S, int rb) -> half8 {
        unsigned w0 = pkrtz(S[rb + 0], S[rb + 1]);
        unsigned w1 = pkrtz(S[rb + 2], S[rb + 3]);
        unsigned w2 = pkrtz(S[rb + 4], S[rb + 5]);
        unsigned w3 = pkrtz(S[rb + 6], S[rb + 7]);
        unsigned x0 = (unsigned)__shfl_xor((int)w0, 32);
        unsigned x1 = (unsigned)__shfl_xor((int)w1, 32);
        unsigned x2 = (unsigned)__shfl_xor((int)w2, 32);
        unsigned x3 = (unsigned)__shfl_xor((int)w3, 32);
        u32x4 t;
        t[0] = hi ? x2 : w0;
        t[1] = hi ? x3 : w1;
        t[2] = hi ? w2 : x0;
        t[3] = hi ? w3 : x1;
        return __builtin_bit_cast(half8, t);
    };

    STAGE_K(0, 0);
    __syncthreads();                       // K(0) resident

    for (int t = 0; t < 16; ++t) {
        const int buf = t & 1;
        STAGE_V(t);                        // V for THIS round (drained mid-round)
        if (t < 15) STAGE_K(t + 1, buf ^ 1);
        const char* ldsK = kbuf(buf, hf);

        // ---- S^T = K Q^T : two 32-key blocks, d chained over 4 chunks
        f32x16 s0 = {}, s1 = {};
        __builtin_amdgcn_s_setprio(1);
        s0 = __builtin_amdgcn_mfma_f32_32x32x16_f16(ldF(ldsK, 0, 0), qf0, s0, 0, 0, 0);
        s0 = __builtin_amdgcn_mfma_f32_32x32x16_f16(ldF(ldsK, 0, 1), qf1, s0, 0, 0, 0);
        s0 = __builtin_amdgcn_mfma_f32_32x32x16_f16(ldF(ldsK, 0, 2), qf2, s0, 0, 0, 0);
        s0 = __builtin_amdgcn_mfma_f32_32x32x16_f16(ldF(ldsK, 0, 3), qf3, s0, 0, 0, 0);
        s1 = __builtin_amdgcn_mfma_f32_32x32x16_f16(ldF(ldsK, 1, 0), qf0, s1, 0, 0, 0);
        s1 = __builtin_amdgcn_mfma_f32_32x32x16_f16(ldF(ldsK, 1, 1), qf1, s1, 0, 0, 0);
        s1 = __builtin_amdgcn_mfma_f32_32x32x16_f16(ldF(ldsK, 1, 2), qf2, s1, 0, 0, 0);
        s1 = __builtin_amdgcn_mfma_f32_32x32x16_f16(ldF(ldsK, 1, 3), qf3, s1, 0, 0, 0);
        __builtin_amdgcn_s_setprio(0);

        // ---- lane-local online softmax (exp2 domain), defer-max THR=8
        float mx[16];
#pragma unroll
        for (int i = 0; i < 16; ++i) mx[i] = fmaxf(s0[i], s1[i]);
#pragma unroll
        for (int st = 8; st > 0; st >>= 1)
#pragma unroll
            for (int i = 0; i < 8; ++i)
                if (i < st) mx[i] = fmaxf(mx[i], mx[i + st]);
        float tm = fmaxf(mx[0], __shfl_xor(mx[0], 32));
        if (!__all(tm <= m_q + 8.f)) {
            float mn = fmaxf(m_q, tm);
            float sc = fexp2(m_q - mn);
            m_q = mn;
            l_q *= sc;
            int scb = __builtin_bit_cast(int, sc);
#pragma unroll
            for (int r = 0; r < 16; ++r) {
                int qr = (r & 3) + 8 * (r >> 2) + 4 * hi;
                float s = __builtin_bit_cast(float, __builtin_amdgcn_ds_bpermute(4 * qr, scb));
                oacc0[r] *= s;
                oacc1[r] *= s;
            }
        }
        float rs = 0.f;
#pragma unroll
        for (int i = 0; i < 16; ++i) { float p = fexp2(s0[i] - m_q); s0[i] = p; rs += p; }
#pragma unroll
        for (int i = 0; i < 16; ++i) { float p = fexp2(s1[i] - m_q); s1[i] = p; rs += p; }
        rs += __shfl_xor(rs, 32);
        l_q += rs;

        // ---- P -> A-fragments (in-register)
        half8 pa0 = mkpa(s0, 0), pa1 = mkpa(s0, 8);
        half8 pa2 = mkpa(s1, 0), pa3 = mkpa(s1, 8);

        __syncthreads();                   // drain V(t) DMA (K(t+1) drains early too)

        // ---- O += P V
        const char* ldsV = vbuf(hf);
        __builtin_amdgcn_s_setprio(1);
        oacc0 = __builtin_amdgcn_mfma_f32_32x32x16_f16(pa0, ldF(ldsV, 0, 0), oacc0, 0, 0, 0);
        oacc0 = __builtin_amdgcn_mfma_f32_32x32x16_f16(pa1, ldF(ldsV, 0, 1), oacc0, 0, 0, 0);
        oacc0 = __builtin_amdgcn_mfma_f32_32x32x16_f16(pa2, ldF(ldsV, 0, 2), oacc0, 0, 0, 0);
        oacc0 = __builtin_amdgcn_mfma_f32_32x32x16_f16(pa3, ldF(ldsV, 0, 3), oacc0, 0, 0, 0);
        oacc1 = __builtin_amdgcn_mfma_f32_32x32x16_f16(pa0, ldF(ldsV, 1, 0), oacc1, 0, 0, 0);
        oacc1 = __builtin_amdgcn_mfma_f32_32x32x16_f16(pa1, ldF(ldsV, 1, 1), oacc1, 0, 0, 0);
        oacc1 = __builtin_amdgcn_mfma_f32_32x32x16_f16(pa2, ldF(ldsV, 1, 2), oacc1, 0, 0, 0);
        oacc1 = __builtin_amdgcn_mfma_f32_32x32x16_f16(pa3, ldF(ldsV, 1, 3), oacc1, 0, 0, 0);
        __builtin_amdgcn_s_setprio(0);

        __syncthreads();                   // all waves done with V(t) before next stage
    }

    // ---- merge wave pairs (w <-> w+4) via LDS, exp2 domain ----
    float* MRG = (float*)SB;               // 4 regions x 2176 f32 (34.8 KB)
    if (hf == 1) {
        float* B = MRG + wq * 2176;
        B[lane] = m_q;
        B[64 + lane] = l_q;
#pragma unroll
        for (int r = 0; r < 16; ++r) {
            B[128 + r * 64 + lane] = oacc0[r];
            B[1152 + r * 64 + lane] = oacc1[r];
        }
    }
    __syncthreads();
    if (hf == 0) {
        float* B = MRG + wq * 2176;
        float m1 = B[lane], l1 = B[64 + lane];
        float m = fmaxf(m_q, m1);
        float e0 = fexp2(m_q - m), e1 = fexp2(m1 - m);
        float linv = 1.f / (l_q * e0 + l1 * e1);
        int e0b = __builtin_bit_cast(int, e0);
        int e1b = __builtin_bit_cast(int, e1);
        int ivb = __builtin_bit_cast(int, linv);
#pragma unroll
        for (int r = 0; r < 16; ++r) {
            int qr = (r & 3) + 8 * (r >> 2) + 4 * hi;
            float s0f = __builtin_bit_cast(float, __builtin_amdgcn_ds_bpermute(4 * qr, e0b));
            float s1f = __builtin_bit_cast(float, __builtin_amdgcn_ds_bpermute(4 * qr, e1b));
            float iv = __builtin_bit_cast(float, __builtin_amdgcn_ds_bpermute(4 * qr, ivb));
            float o0 = (oacc0[r] * s0f + B[128 + r * 64 + lane] * s1f) * iv;
            float o1 = (oacc1[r] * s0f + B[1152 + r * 64 + lane] * s1f) * iv;
            int qglob = qt * 128 + wq * 32 + qr;
            size_t base = ((size_t)(n * S_LEN + qglob)) * DM + h * HD + l31;
            Oatt[base] = (_Float16)o0;
            Oatt[base + 32] = (_Float16)o1;
        }
    }
}

// ---------------------------------------------------------------------------
// Projection GEMM: 128x64 tile, BK=64, grid 512 (2 blocks/CU), LDS 48 KB
// double-buffered via gload16 (inverse-swizzled source, linear dest).
// 4 waves; wave w owns M rows [w*32, w*32+32) x all 64 N cols.
// XCD: ot = (id&7) + 8*((id>>3)&1) pins W strips per XCD.
// ---------------------------------------------------------------------------
__global__ __launch_bounds__(256) void k_proj(const _Float16* __restrict__ A,
                                              const _Float16* __restrict__ W,
                                              const float* __restrict__ bias,
                                              float* __restrict__ out) {
    __shared__ _Float16 As[2][128 * 64];   // 16 KB each
    __shared__ _Float16 Ws[2][64 * 64];    // 8 KB each

    const int id = blockIdx.x;
    const int ot = (id & 7) + 8 * ((id >> 3) & 1);   // 0..15, O strip of 64
    const int mt = id >> 4;                          // 0..31, M strip of 128
    const int tid = threadIdx.x;
    const int w = tid >> 6;
    const int lane = tid & 63;
    const int lr = lane & 15, lg = lane >> 4;
    const int wm = w * 32;

    const int rr = lane >> 3;
    const int cb = (lane & 7) * 16;
    const int gcb = cb ^ (rr << 4);

    const char* Abase = (const char*)(A + (size_t)(mt * 128) * DM);
    const char* Wbase = (const char*)(W + (size_t)(ot * 64) * DM);

    auto STAGE = [&](int kt, int b) {
#pragma unroll
        for (int r = 0; r < 4; ++r) {
            int row = r * 32 + w * 8 + rr;
            gload16(Abase + (size_t)row * 2048 + kt * 128 + gcb,
                    (char*)&As[b][0] + (r * 32 + w * 8) * 128);
        }
#pragma unroll
        for (int r = 0; r < 2; ++r) {
            int row = r * 32 + w * 8 + rr;
            gload16(Wbase + (size_t)row * 2048 + kt * 128 + gcb,
                    (char*)&Ws[b][0] + (r * 32 + w * 8) * 128);
        }
    };

    f32x4 zero = {0.f, 0.f, 0.f, 0.f};
    f32x4 acc[2][4];
#pragma unroll
    for (int mi = 0; mi < 2; ++mi)
#pragma unroll
        for (int ni = 0; ni < 4; ++ni) acc[mi][ni] = zero;

    auto COMPUTE = [&](int b) {
        const char* ldsA = (const char*)&As[b][0];
        const char* ldsW = (const char*)&Ws[b][0];
        half8 af[2][2], wf[4][2];
#pragma unroll
        for (int mi = 0; mi < 2; ++mi) {
            int row = wm + mi * 16 + lr;
            int sw = (row & 7) << 4;
            const char* p = ldsA + row * 128;
            af[mi][0] = *(const half8*)(p + ((lg * 16) ^ sw));
            af[mi][1] = *(const half8*)(p + ((64 + lg * 16) ^ sw));
        }
#pragma unroll
        for (int ni = 0; ni < 4; ++ni) {
            int row = ni * 16 + lr;
            int sw = (row & 7) << 4;
            const char* p = ldsW + row * 128;
            wf[ni][0] = *(const half8*)(p + ((lg * 16) ^ sw));
            wf[ni][1] = *(const half8*)(p + ((64 + lg * 16) ^ sw));
        }
#pragma unroll
        for (int mi = 0; mi < 2; ++mi)
#pragma unroll
            for (int ni = 0; ni < 4; ++ni) {
                acc[mi][ni] = __builtin_amdgcn_mfma_f32_16x16x32_f16(af[mi][0], wf[ni][0], acc[mi][ni], 0, 0, 0);
                acc[mi][ni] = __builtin_amdgcn_mfma_f32_16x16x32_f16(af[mi][1], wf[ni][1], acc[mi][ni], 0, 0, 0);
            }
    };

    STAGE(0, 0);
    __syncthreads();
    for (int kt = 0; kt < 15; ++kt) {
        STAGE(kt + 1, (kt & 1) ^ 1);
        COMPUTE(kt & 1);
        __syncthreads();
    }
    COMPUTE(1);   // kt=15, no stage -> no DMA outstanding at endpgm

    // epilogue: C row = m (A dim), col = o (W dim)
#pragma unroll
    for (int ni = 0; ni < 4; ++ni) {
        int o = ot * 64 + ni * 16 + lr;
        float b = bias[o];
#pragma unroll
        for (int mi = 0; mi < 2; ++mi)
#pragma unroll
            for (int i = 0; i < 4; ++i) {
                int m = mt * 128 + wm + mi * 16 + lg * 4 + i;
                out[(size_t)m * DM + o] = acc[mi][ni][i] + b;
            }
    }
}

// ---------------------------------------------------------------------------
extern "C" void kernel_launch(void* const* d_in, const int* in_sizes, int n_in,
                              void* d_out, int out_size, void* d_ws, size_t ws_size,
                              hipStream_t stream) {
    const float* Q = (const float*)d_in[0];
    const float* K = (const float*)d_in[1];
    const float* V = (const float*)d_in[2];
    const float* Wo = (const float*)d_in[3];
    const float* bo = (const float*)d_in[4];
    float* out = (float*)d_out;
    char* ws = (char*)d_ws;

    _Float16* Kh = (_Float16*)(ws);                     // 8 MB
    _Float16* Vt = (_Float16*)(ws + (8u << 20));        // 8 MB
    _Float16* Oatt = (_Float16*)(ws + (16u << 20));     // 8 MB
    _Float16* Wh = (_Float16*)(ws + (24u << 20));       // 2 MB

    k_prep<<<6144, 256, 0, stream>>>(K, V, Wo, Kh, Vt, Wh);
    k_attn<<<512, 512, 0, stream>>>(Q, Kh, Vt, Oatt);
    k_proj<<<512, 256, 0, stream>>>(Oatt, Wh, bo, out);
}

// Round 17
// 92.784 us; speedup vs baseline: 1.7679x; 1.0054x over previous
//
#include <hip/hip_runtime.h>

typedef _Float16 half8 __attribute__((ext_vector_type(8)));
typedef _Float16 half4 __attribute__((ext_vector_type(4)));
typedef float f32x4 __attribute__((ext_vector_type(4)));
typedef float f32x16 __attribute__((ext_vector_type(16)));
typedef unsigned u32x4 __attribute__((ext_vector_type(4)));

#define N_B 2
#define S_LEN 2048
#define NH 16
#define HD 64
#define DM 1024
#define LOG2E 1.44269504088896f

__device__ __forceinline__ void gload16(const void* g, void* l) {
    __builtin_amdgcn_global_load_lds(
        (const __attribute__((address_space(1))) unsigned int*)g,
        (__attribute__((address_space(3))) unsigned int*)l, 16, 0, 0);
}

__device__ __forceinline__ float fexp2(float x) {
    float r;
    asm("v_exp_f32 %0, %1" : "=v"(r) : "v"(x));
    return r;
}

// ---------------------------------------------------------------------------
// Fused prep (one launch): blocks [0,4096) convert K -> f16 [n][h][s][d];
// [4096,5120) transpose V -> Vt f16 [n][h][d][s] (float4 reads, half4
// writes -- was scalar both sides); [5120,6144) cvt W -> f16.
// ---------------------------------------------------------------------------
__global__ __launch_bounds__(256) void k_prep(const float* __restrict__ K,
                                              const float* __restrict__ V,
                                              const float* __restrict__ Wo,
                                              _Float16* __restrict__ Kh,
                                              _Float16* __restrict__ Vt,
                                              _Float16* __restrict__ Wh) {
    __shared__ _Float16 tile[64][65];
    const int id = blockIdx.x;
    if (id < 4096) {                       // ---- K regroup
        int i = id * 256 + threadIdx.x;
        float4 v = ((const float4*)K)[i];
        int base = i * 4;
        int d = base & 63;
        int h = (base >> 6) & 15;
        int s = (base >> 10) & 2047;
        int n = base >> 21;
        size_t o = ((size_t)((n * NH + h) * S_LEN + s)) * HD + d;
        half4 hv = {(_Float16)v.x, (_Float16)v.y, (_Float16)v.z, (_Float16)v.w};
        *(half4*)(Kh + o) = hv;
    } else if (id < 5120) {                // ---- V transpose (vectorized)
        int b = id - 4096;
        int st = b & 31, h = (b >> 5) & 15, n = b >> 9;
        int r0 = threadIdx.x >> 4;         // 0..15
        int c4 = (threadIdx.x & 15) * 4;   // 0,4,..,60
#pragma unroll
        for (int i = 0; i < 4; ++i) {
            int row = i * 16 + r0;
            float4 v = *(const float4*)(V + ((size_t)(n * S_LEN) + st * 64 + row) * DM + h * HD + c4);
            tile[row][c4 + 0] = (_Float16)v.x;
            tile[row][c4 + 1] = (_Float16)v.y;
            tile[row][c4 + 2] = (_Float16)v.z;
            tile[row][c4 + 3] = (_Float16)v.w;
        }
        __syncthreads();
#pragma unroll
        for (int i = 0; i < 4; ++i) {
            int d = i * 16 + r0;
            half4 hv = {tile[c4 + 0][d], tile[c4 + 1][d], tile[c4 + 2][d], tile[c4 + 3][d]};
            *(half4*)(Vt + ((size_t)((n * NH + h) * HD + d)) * S_LEN + st * 64 + c4) = hv;
        }
    } else {                               // ---- W convert
        int i = (id - 5120) * 256 + threadIdx.x;
        float4 v = ((const float4*)Wo)[i];
        half4 hv = {(_Float16)v.x, (_Float16)v.y, (_Float16)v.z, (_Float16)v.w};
        *(half4*)(Wh + (size_t)i * 4) = hv;
    }
}

// ---------------------------------------------------------------------------
// Flash attention (best-measured configuration, 71.0us): 32x32 MFMA,
// in-register P (cvt_pkrtz + shfl mkpa), wave-level KV split. Block = 8
// waves (512 thr), QBLK=128; wave w: q-subtile (w&3), KV half (w>>2).
// K double-buffered; V single-buffered, drained by the mid-round
// __syncthreads. defer-max THR=14 (P <= 2^14, f16-safe; R10-validated).
// ---------------------------------------------------------------------------
__global__ __launch_bounds__(512, 4) void k_attn(const float* __restrict__ Q,
                                                 const _Float16* __restrict__ Kh,
                                                 const _Float16* __restrict__ Vth,
                                                 _Float16* __restrict__ Oatt) {
    __shared__ char SB[49152];
    // [0,32768): K dbuf (b,hf) 8KB each ; [32768,49152): V single (hf) 8KB

    // XCD swizzle (bijective on 512 = 8 * 64): 4 nh per XCD, 16 qt each
    const int id = blockIdx.x;
    const int xcd = id & 7;
    const int sl = id >> 3;              // 0..63
    const int nh = xcd + 8 * (sl >> 4);
    const int qt = sl & 15;              // q tile of 128

    const int tid = threadIdx.x;
    const int w = tid >> 6;              // 0..7
    const int wq = w & 3;                // q-subtile
    const int hf = w >> 2;               // KV half
    const int lane = tid & 63;
    const int l31 = lane & 31;
    const int hi = lane >> 5;
    const int n = nh >> 4, h = nh & 15;

    const size_t head = (size_t)nh * S_LEN * HD;
    const char* Khead = (const char*)(Kh + head);
    const char* Vhead = (const char*)(Vth + head);

    // ---- Q fragments (B-frag: col q=l31, k=8hi+j per 16-d chunk), LOG2E-scaled
    const int qg = qt * 128 + wq * 32 + l31;
    const float* qbase = Q + ((size_t)(n * S_LEN) + qg) * DM + h * HD;
    auto mkqf = [&](int c) -> half8 {
        float4 a = *(const float4*)(qbase + 16 * c + 8 * hi);
        float4 b = *(const float4*)(qbase + 16 * c + 8 * hi + 4);
        half8 r = {(_Float16)(a.x * LOG2E), (_Float16)(a.y * LOG2E),
                   (_Float16)(a.z * LOG2E), (_Float16)(a.w * LOG2E),
                   (_Float16)(b.x * LOG2E), (_Float16)(b.y * LOG2E),
                   (_Float16)(b.z * LOG2E), (_Float16)(b.w * LOG2E)};
        return r;
    };
    half8 qf0 = mkqf(0), qf1 = mkqf(1), qf2 = mkqf(2), qf3 = mkqf(3);

    f32x16 oacc0 = {}, oacc1 = {};
    float m_q = -1e30f, l_q = 0.f;       // per q=l31 (2x redundant over hi)

    // staging geometry: wave w stages slices wq*2+j of its half's tiles
    const int rr = lane >> 3;
    const int cb = (lane & 7) * 16;
    const int gcb = cb ^ (rr << 4);      // inverse-swizzled global column

    auto kbuf = [&](int b, int half) -> char* { return SB + (b * 2 + half) * 8192; };
    auto vbuf = [&](int half) -> char* { return SB + 32768 + half * 8192; };

    auto STAGE_K = [&](int t, int b) {
#pragma unroll
        for (int j = 0; j < 2; ++j) {
            int slice = wq * 2 + j;            // 0..7
            int row = slice * 8 + rr;          // 0..63
            int key = hf * 1024 + t * 64 + row;
            gload16(Khead + (size_t)key * 128 + gcb, kbuf(b, hf) + slice * 1024);
        }
    };
    auto STAGE_V = [&](int t) {
#pragma unroll
        for (int j = 0; j < 2; ++j) {
            int slice = wq * 2 + j;
            int row = slice * 8 + rr;
            gload16(Vhead + (size_t)row * 4096 + hf * 2048 + t * 128 + gcb,
                    vbuf(hf) + slice * 1024);
        }
    };

    const int rmask = (l31 & 7) << 4;
    auto ldF = [&](const char* lds, int blk, int c) -> half8 {
        int off = (32 * blk + l31) * 128 + ((32 * c + 16 * hi) ^ rmask);
        return *(const half8*)(lds + off);
    };

    auto pkrtz = [&](float a, float b) -> unsigned {
        return __builtin_bit_cast(unsigned, __builtin_amdgcn_cvt_pkrtz(a, b));
    };
    auto mkpa = [&](const f32x16& S, int rb) -> half8 {
        unsigned w0 = pkrtz(S[rb + 0], S[rb + 1]);
        unsigned w1 = pkrtz(S[rb + 2], S[rb + 3]);
        unsigned w2 = pkrtz(S[rb + 4], S[rb + 5]);
        unsigned w3 = pkrtz(S[rb + 6], S[rb + 7]);
        unsigned x0 = (unsigned)__shfl_xor((int)w0, 32);
        unsigned x1 = (unsigned)__shfl_xor((int)w1, 32);
        unsigned x2 = (unsigned)__shfl_xor((int)w2, 32);
        unsigned x3 = (unsigned)__shfl_xor((int)w3, 32);
        u32x4 t;
        t[0] = hi ? x2 : w0;
        t[1] = hi ? x3 : w1;
        t[2] = hi ? w2 : x0;
        t[3] = hi ? w3 : x1;
        return __builtin_bit_cast(half8, t);
    };

    STAGE_K(0, 0);
    __syncthreads();                       // K(0) resident

    for (int t = 0; t < 16; ++t) {
        const int buf = t & 1;
        STAGE_V(t);                        // V for THIS round (drained mid-round)
        if (t < 15) STAGE_K(t + 1, buf ^ 1);
        const char* ldsK = kbuf(buf, hf);

        // ---- S^T = K Q^T : two 32-key blocks, d chained over 4 chunks
        f32x16 s0 = {}, s1 = {};
        __builtin_amdgcn_s_setprio(1);
        s0 = __builtin_amdgcn_mfma_f32_32x32x16_f16(ldF(ldsK, 0, 0), qf0, s0, 0, 0, 0);
        s0 = __builtin_amdgcn_mfma_f32_32x32x16_f16(ldF(ldsK, 0, 1), qf1, s0, 0, 0, 0);
        s0 = __builtin_amdgcn_mfma_f32_32x32x16_f16(ldF(ldsK, 0, 2), qf2, s0, 0, 0, 0);
        s0 = __builtin_amdgcn_mfma_f32_32x32x16_f16(ldF(ldsK, 0, 3), qf3, s0, 0, 0, 0);
        s1 = __builtin_amdgcn_mfma_f32_32x32x16_f16(ldF(ldsK, 1, 0), qf0, s1, 0, 0, 0);
        s1 = __builtin_amdgcn_mfma_f32_32x32x16_f16(ldF(ldsK, 1, 1), qf1, s1, 0, 0, 0);
        s1 = __builtin_amdgcn_mfma_f32_32x32x16_f16(ldF(ldsK, 1, 2), qf2, s1, 0, 0, 0);
        s1 = __builtin_amdgcn_mfma_f32_32x32x16_f16(ldF(ldsK, 1, 3), qf3, s1, 0, 0, 0);
        __builtin_amdgcn_s_setprio(0);

        // ---- lane-local online softmax (exp2 domain), defer-max THR=14
        float mx[16];
#pragma unroll
        for (int i = 0; i < 16; ++i) mx[i] = fmaxf(s0[i], s1[i]);
#pragma unroll
        for (int st = 8; st > 0; st >>= 1)
#pragma unroll
            for (int i = 0; i < 8; ++i)
                if (i < st) mx[i] = fmaxf(mx[i], mx[i + st]);
        float tm = fmaxf(mx[0], __shfl_xor(mx[0], 32));
        if (!__all(tm <= m_q + 14.f)) {
            float mn = fmaxf(m_q, tm);
            float sc = fexp2(m_q - mn);
            m_q = mn;
            l_q *= sc;
            int scb = __builtin_bit_cast(int, sc);
#pragma unroll
            for (int r = 0; r < 16; ++r) {
                int qr = (r & 3) + 8 * (r >> 2) + 4 * hi;
                float s = __builtin_bit_cast(float, __builtin_amdgcn_ds_bpermute(4 * qr, scb));
                oacc0[r] *= s;
                oacc1[r] *= s;
            }
        }
        float rs = 0.f;
#pragma unroll
        for (int i = 0; i < 16; ++i) { float p = fexp2(s0[i] - m_q); s0[i] = p; rs += p; }
#pragma unroll
        for (int i = 0; i < 16; ++i) { float p = fexp2(s1[i] - m_q); s1[i] = p; rs += p; }
        rs += __shfl_xor(rs, 32);
        l_q += rs;

        // ---- P -> A-fragments (in-register)
        half8 pa0 = mkpa(s0, 0), pa1 = mkpa(s0, 8);
        half8 pa2 = mkpa(s1, 0), pa3 = mkpa(s1, 8);

        __syncthreads();                   // drain V(t) DMA (K(t+1) drains early too)

        // ---- O += P V
        const char* ldsV = vbuf(hf);
        __builtin_amdgcn_s_setprio(1);
        oacc0 = __builtin_amdgcn_mfma_f32_32x32x16_f16(pa0, ldF(ldsV, 0, 0), oacc0, 0, 0, 0);
        oacc0 = __builtin_amdgcn_mfma_f32_32x32x16_f16(pa1, ldF(ldsV, 0, 1), oacc0, 0, 0, 0);
        oacc0 = __builtin_amdgcn_mfma_f32_32x32x16_f16(pa2, ldF(ldsV, 0, 2), oacc0, 0, 0, 0);
        oacc0 = __builtin_amdgcn_mfma_f32_32x32x16_f16(pa3, ldF(ldsV, 0, 3), oacc0, 0, 0, 0);
        oacc1 = __builtin_amdgcn_mfma_f32_32x32x16_f16(pa0, ldF(ldsV, 1, 0), oacc1, 0, 0, 0);
        oacc1 = __builtin_amdgcn_mfma_f32_32x32x16_f16(pa1, ldF(ldsV, 1, 1), oacc1, 0, 0, 0);
        oacc1 = __builtin_amdgcn_mfma_f32_32x32x16_f16(pa2, ldF(ldsV, 1, 2), oacc1, 0, 0, 0);
        oacc1 = __builtin_amdgcn_mfma_f32_32x32x16_f16(pa3, ldF(ldsV, 1, 3), oacc1, 0, 0, 0);
        __builtin_amdgcn_s_setprio(0);

        __syncthreads();                   // all waves done with V(t) before next stage
    }

    // ---- merge wave pairs (w <-> w+4) via LDS, exp2 domain ----
    float* MRG = (float*)SB;               // 4 regions x 2176 f32 (34.8 KB)
    if (hf == 1) {
        float* B = MRG + wq * 2176;
        B[lane] = m_q;
        B[64 + lane] = l_q;
#pragma unroll
        for (int r = 0; r < 16; ++r) {
            B[128 + r * 64 + lane] = oacc0[r];
            B[1152 + r * 64 + lane] = oacc1[r];
        }
    }
    __syncthreads();
    if (hf == 0) {
        float* B = MRG + wq * 2176;
        float m1 = B[lane], l1 = B[64 + lane];
        float m = fmaxf(m_q, m1);
        float e0 = fexp2(m_q - m), e1 = fexp2(m1 - m);
        float linv = 1.f / (l_q * e0 + l1 * e1);
        int e0b = __builtin_bit_cast(int, e0);
        int e1b = __builtin_bit_cast(int, e1);
        int ivb = __builtin_bit_cast(int, linv);
#pragma unroll
        for (int r = 0; r < 16; ++r) {
            int qr = (r & 3) + 8 * (r >> 2) + 4 * hi;
            float s0f = __builtin_bit_cast(float, __builtin_amdgcn_ds_bpermute(4 * qr, e0b));
            float s1f = __builtin_bit_cast(float, __builtin_amdgcn_ds_bpermute(4 * qr, e1b));
            float iv = __builtin_bit_cast(float, __builtin_amdgcn_ds_bpermute(4 * qr, ivb));
            float o0 = (oacc0[r] * s0f + B[128 + r * 64 + lane] * s1f) * iv;
            float o1 = (oacc1[r] * s0f + B[1152 + r * 64 + lane] * s1f) * iv;
            int qglob = qt * 128 + wq * 32 + qr;
            size_t base = ((size_t)(n * S_LEN + qglob)) * DM + h * HD + l31;
            Oatt[base] = (_Float16)o0;
            Oatt[base + 32] = (_Float16)o1;
        }
    }
}

// ---------------------------------------------------------------------------
// Projection GEMM: 128x64 tile, BK=64, grid 512 (2 blocks/CU), LDS 48 KB
// double-buffered via gload16 (inverse-swizzled source, linear dest).
// 4 waves; wave w owns M rows [w*32, w*32+32) x all 64 N cols.
// XCD: ot = (id&7) + 8*((id>>3)&1) pins W strips per XCD.
// ---------------------------------------------------------------------------
__global__ __launch_bounds__(256) void k_proj(const _Float16* __restrict__ A,
                                              const _Float16* __restrict__ W,
                                              const float* __restrict__ bias,
                                              float* __restrict__ out) {
    __shared__ _Float16 As[2][128 * 64];   // 16 KB each
    __shared__ _Float16 Ws[2][64 * 64];    // 8 KB each

    const int id = blockIdx.x;
    const int ot = (id & 7) + 8 * ((id >> 3) & 1);   // 0..15, O strip of 64
    const int mt = id >> 4;                          // 0..31, M strip of 128
    const int tid = threadIdx.x;
    const int w = tid >> 6;
    const int lane = tid & 63;
    const int lr = lane & 15, lg = lane >> 4;
    const int wm = w * 32;

    const int rr = lane >> 3;
    const int cb = (lane & 7) * 16;
    const int gcb = cb ^ (rr << 4);

    const char* Abase = (const char*)(A + (size_t)(mt * 128) * DM);
    const char* Wbase = (const char*)(W + (size_t)(ot * 64) * DM);

    auto STAGE = [&](int kt, int b) {
#pragma unroll
        for (int r = 0; r < 4; ++r) {
            int row = r * 32 + w * 8 + rr;
            gload16(Abase + (size_t)row * 2048 + kt * 128 + gcb,
                    (char*)&As[b][0] + (r * 32 + w * 8) * 128);
        }
#pragma unroll
        for (int r = 0; r < 2; ++r) {
            int row = r * 32 + w * 8 + rr;
            gload16(Wbase + (size_t)row * 2048 + kt * 128 + gcb,
                    (char*)&Ws[b][0] + (r * 32 + w * 8) * 128);
        }
    };

    f32x4 zero = {0.f, 0.f, 0.f, 0.f};
    f32x4 acc[2][4];
#pragma unroll
    for (int mi = 0; mi < 2; ++mi)
#pragma unroll
        for (int ni = 0; ni < 4; ++ni) acc[mi][ni] = zero;

    auto COMPUTE = [&](int b) {
        const char* ldsA = (const char*)&As[b][0];
        const char* ldsW = (const char*)&Ws[b][0];
        half8 af[2][2], wf[4][2];
#pragma unroll
        for (int mi = 0; mi < 2; ++mi) {
            int row = wm + mi * 16 + lr;
            int sw = (row & 7) << 4;
            const char* p = ldsA + row * 128;
            af[mi][0] = *(const half8*)(p + ((lg * 16) ^ sw));
            af[mi][1] = *(const half8*)(p + ((64 + lg * 16) ^ sw));
        }
#pragma unroll
        for (int ni = 0; ni < 4; ++ni) {
            int row = ni * 16 + lr;
            int sw = (row & 7) << 4;
            const char* p = ldsW + row * 128;
            wf[ni][0] = *(const half8*)(p + ((lg * 16) ^ sw));
            wf[ni][1] = *(const half8*)(p + ((64 + lg * 16) ^ sw));
        }
#pragma unroll
        for (int mi = 0; mi < 2; ++mi)
#pragma unroll
            for (int ni = 0; ni < 4; ++ni) {
                acc[mi][ni] = __builtin_amdgcn_mfma_f32_16x16x32_f16(af[mi][0], wf[ni][0], acc[mi][ni], 0, 0, 0);
                acc[mi][ni] = __builtin_amdgcn_mfma_f32_16x16x32_f16(af[mi][1], wf[ni][1], acc[mi][ni], 0, 0, 0);
            }
    };

    STAGE(0, 0);
    __syncthreads();
    for (int kt = 0; kt < 15; ++kt) {
        STAGE(kt + 1, (kt & 1) ^ 1);
        COMPUTE(kt & 1);
        __syncthreads();
    }
    COMPUTE(1);   // kt=15, no stage -> no DMA outstanding at endpgm

    // epilogue: C row = m (A dim), col = o (W dim)
#pragma unroll
    for (int ni = 0; ni < 4; ++ni) {
        int o = ot * 64 + ni * 16 + lr;
        float b = bias[o];
#pragma unroll
        for (int mi = 0; mi < 2; ++mi)
#pragma unroll
            for (int i = 0; i < 4; ++i) {
                int m = mt * 128 + wm + mi * 16 + lg * 4 + i;
                out[(size_t)m * DM + o] = acc[mi][ni][i] + b;
            }
    }
}

// ---------------------------------------------------------------------------
extern "C" void kernel_launch(void* const* d_in, const int* in_sizes, int n_in,
                              void* d_out, int out_size, void* d_ws, size_t ws_size,
                              hipStream_t stream) {
    const float* Q = (const float*)d_in[0];
    const float* K = (const float*)d_in[1];
    const float* V = (const float*)d_in[2];
    const float* Wo = (const float*)d_in[3];
    const float* bo = (const float*)d_in[4];
    float* out = (float*)d_out;
    char* ws = (char*)d_ws;

    _Float16* Kh = (_Float16*)(ws);                     // 8 MB
    _Float16* Vt = (_Float16*)(ws + (8u << 20));        // 8 MB
    _Float16* Oatt = (_Float16*)(ws + (16u << 20));     // 8 MB
    _Float16* Wh = (_Float16*)(ws + (24u << 20));       // 2 MB

    k_prep<<<6144, 256, 0, stream>>>(K, V, Wo, Kh, Vt, Wh);
    k_attn<<<512, 512, 0, stream>>>(Q, Kh, Vt, Oatt);
    k_proj<<<512, 256, 0, stream>>>(Oatt, Wh, bo, out);
}

// Round 18
// 91.839 us; speedup vs baseline: 1.7861x; 1.0103x over previous
//
#include <hip/hip_runtime.h>

typedef _Float16 half8 __attribute__((ext_vector_type(8)));
typedef _Float16 half4 __attribute__((ext_vector_type(4)));
typedef float f32x4 __attribute__((ext_vector_type(4)));
typedef float f32x16 __attribute__((ext_vector_type(16)));
typedef unsigned u32x4 __attribute__((ext_vector_type(4)));

#define N_B 2
#define S_LEN 2048
#define NH 16
#define HD 64
#define DM 1024
#define LOG2E 1.44269504088896f

__device__ __forceinline__ void gload16(const void* g, void* l) {
    __builtin_amdgcn_global_load_lds(
        (const __attribute__((address_space(1))) unsigned int*)g,
        (__attribute__((address_space(3))) unsigned int*)l, 16, 0, 0);
}

__device__ __forceinline__ float fexp2(float x) {
    float r;
    asm("v_exp_f32 %0, %1" : "=v"(r) : "v"(x));
    return r;
}

// ---------------------------------------------------------------------------
// Fused prep (one launch): blocks [0,4096) convert K -> f16 [n][h][s][d];
// [4096,5120) transpose V -> Vt f16 [n][h][d][s] (float4 reads, half4
// writes); [5120,6144) cvt W -> f16.
// ---------------------------------------------------------------------------
__global__ __launch_bounds__(256) void k_prep(const float* __restrict__ K,
                                              const float* __restrict__ V,
                                              const float* __restrict__ Wo,
                                              _Float16* __restrict__ Kh,
                                              _Float16* __restrict__ Vt,
                                              _Float16* __restrict__ Wh) {
    __shared__ _Float16 tile[64][65];
    const int id = blockIdx.x;
    if (id < 4096) {                       // ---- K regroup
        int i = id * 256 + threadIdx.x;
        float4 v = ((const float4*)K)[i];
        int base = i * 4;
        int d = base & 63;
        int h = (base >> 6) & 15;
        int s = (base >> 10) & 2047;
        int n = base >> 21;
        size_t o = ((size_t)((n * NH + h) * S_LEN + s)) * HD + d;
        half4 hv = {(_Float16)v.x, (_Float16)v.y, (_Float16)v.z, (_Float16)v.w};
        *(half4*)(Kh + o) = hv;
    } else if (id < 5120) {                // ---- V transpose (vectorized)
        int b = id - 4096;
        int st = b & 31, h = (b >> 5) & 15, n = b >> 9;
        int r0 = threadIdx.x >> 4;         // 0..15
        int c4 = (threadIdx.x & 15) * 4;   // 0,4,..,60
#pragma unroll
        for (int i = 0; i < 4; ++i) {
            int row = i * 16 + r0;
            float4 v = *(const float4*)(V + ((size_t)(n * S_LEN) + st * 64 + row) * DM + h * HD + c4);
            tile[row][c4 + 0] = (_Float16)v.x;
            tile[row][c4 + 1] = (_Float16)v.y;
            tile[row][c4 + 2] = (_Float16)v.z;
            tile[row][c4 + 3] = (_Float16)v.w;
        }
        __syncthreads();
#pragma unroll
        for (int i = 0; i < 4; ++i) {
            int d = i * 16 + r0;
            half4 hv = {tile[c4 + 0][d], tile[c4 + 1][d], tile[c4 + 2][d], tile[c4 + 3][d]};
            *(half4*)(Vt + ((size_t)((n * NH + h) * HD + d)) * S_LEN + st * 64 + c4) = hv;
        }
    } else {                               // ---- W convert
        int i = (id - 5120) * 256 + threadIdx.x;
        float4 v = ((const float4*)Wo)[i];
        half4 hv = {(_Float16)v.x, (_Float16)v.y, (_Float16)v.z, (_Float16)v.w};
        *(half4*)(Wh + (size_t)i * 4) = hv;
    }
}

// ---------------------------------------------------------------------------
// Flash attention: 32x32 MFMA, in-register P (cvt_pkrtz + shfl mkpa),
// wave-level KV split, FRAGMENT-ORDER LDS layout: K/V tiles are stored in
// LDS in exactly the order the wave reads MFMA fragments
// (index = ((blk*4+c)*32 + l31)*2 + hi), so every fragment read is a
// contiguous 1KB wave read -- bank-conflict-free by construction. The
// permutation is applied on the per-lane GLOBAL source address of
// global_load_lds (linear LDS dest, per-lane source: m173 pattern).
// Block = 8 waves (512 thr), QBLK=128; wave w: q-subtile (w&3), KV half
// (w>>2). K double-buffered; V single-buffered (mid-round drain).
// defer-max THR=14. No DMA outstanding at endpgm.
// ---------------------------------------------------------------------------
__global__ __launch_bounds__(512, 4) void k_attn(const float* __restrict__ Q,
                                                 const _Float16* __restrict__ Kh,
                                                 const _Float16* __restrict__ Vth,
                                                 _Float16* __restrict__ Oatt) {
    __shared__ char SB[49152];
    // [0,32768): K dbuf (b,hf) 8KB each ; [32768,49152): V single (hf) 8KB

    // XCD swizzle (bijective on 512 = 8 * 64): 4 nh per XCD, 16 qt each
    const int id = blockIdx.x;
    const int xcd = id & 7;
    const int sl = id >> 3;              // 0..63
    const int nh = xcd + 8 * (sl >> 4);
    const int qt = sl & 15;              // q tile of 128

    const int tid = threadIdx.x;
    const int w = tid >> 6;              // 0..7
    const int wq = w & 3;                // q-subtile
    const int hf = w >> 2;               // KV half
    const int lane = tid & 63;
    const int l31 = lane & 31;
    const int hi = lane >> 5;
    const int n = nh >> 4, h = nh & 15;

    const size_t head = (size_t)nh * S_LEN * HD;
    const char* Khead = (const char*)(Kh + head);
    const char* Vhead = (const char*)(Vth + head);

    // ---- Q fragments (B-frag: col q=l31, k=8hi+j per 16-d chunk), LOG2E-scaled
    const int qg = qt * 128 + wq * 32 + l31;
    const float* qbase = Q + ((size_t)(n * S_LEN) + qg) * DM + h * HD;
    auto mkqf = [&](int c) -> half8 {
        float4 a = *(const float4*)(qbase + 16 * c + 8 * hi);
        float4 b = *(const float4*)(qbase + 16 * c + 8 * hi + 4);
        half8 r = {(_Float16)(a.x * LOG2E), (_Float16)(a.y * LOG2E),
                   (_Float16)(a.z * LOG2E), (_Float16)(a.w * LOG2E),
                   (_Float16)(b.x * LOG2E), (_Float16)(b.y * LOG2E),
                   (_Float16)(b.z * LOG2E), (_Float16)(b.w * LOG2E)};
        return r;
    };
    half8 qf0 = mkqf(0), qf1 = mkqf(1), qf2 = mkqf(2), qf3 = mkqf(3);

    f32x16 oacc0 = {}, oacc1 = {};
    float m_q = -1e30f, l_q = 0.f;       // per q=l31 (2x redundant over hi)

    auto kbuf = [&](int b, int half) -> char* { return SB + (b * 2 + half) * 8192; };
    auto vbuf = [&](int half) -> char* { return SB + 32768 + half * 8192; };

    // staging: wave stages slices wq*2+j; per lane, decode the fragment-order
    // index and fetch the matching element from global.
    auto STAGE_K = [&](int t, int b) {
#pragma unroll
        for (int j = 0; j < 2; ++j) {
            int slice = wq * 2 + j;            // 0..7
            int idx = slice * 64 + lane;       // 0..511
            int bhi = idx & 1;
            int bl31 = (idx >> 1) & 31;
            int bc = (idx >> 6) & 3;
            int bblk = idx >> 8;
            int key = hf * 1024 + t * 64 + bblk * 32 + bl31;
            gload16(Khead + (size_t)key * 128 + bc * 32 + bhi * 16,
                    kbuf(b, hf) + slice * 1024);
        }
    };
    auto STAGE_V = [&](int t) {
#pragma unroll
        for (int j = 0; j < 2; ++j) {
            int slice = wq * 2 + j;
            int idx = slice * 64 + lane;
            int bhi = idx & 1;
            int bl31 = (idx >> 1) & 31;
            int bc = (idx >> 6) & 3;
            int bblk = idx >> 8;
            int drow = bblk * 32 + bl31;
            gload16(Vhead + (size_t)drow * 4096 + hf * 2048 + t * 128 + bc * 32 + bhi * 16,
                    vbuf(hf) + slice * 1024);
        }
    };

    // fragment read: contiguous 1KB per (blk,c) -- conflict-free
    auto ldF = [&](const char* lds, int blk, int c) -> half8 {
        int off = (((blk * 4 + c) * 32 + l31) * 2 + hi) * 16;
        return *(const half8*)(lds + off);
    };

    auto pkrtz = [&](float a, float b) -> unsigned {
        return __builtin_bit_cast(unsigned, __builtin_amdgcn_cvt_pkrtz(a, b));
    };
    auto mkpa = [&](const f32x16& S, int rb) -> half8 {
        unsigned w0 = pkrtz(S[rb + 0], S[rb + 1]);
        unsigned w1 = pkrtz(S[rb + 2], S[rb + 3]);
        unsigned w2 = pkrtz(S[rb + 4], S[rb + 5]);
        unsigned w3 = pkrtz(S[rb + 6], S[rb + 7]);
        unsigned x0 = (unsigned)__shfl_xor((int)w0, 32);
        unsigned x1 = (unsigned)__shfl_xor((int)w1, 32);
        unsigned x2 = (unsigned)__shfl_xor((int)w2, 32);
        unsigned x3 = (unsigned)__shfl_xor((int)w3, 32);
        u32x4 t;
        t[0] = hi ? x2 : w0;
        t[1] = hi ? x3 : w1;
        t[2] = hi ? w2 : x0;
        t[3] = hi ? w3 : x1;
        return __builtin_bit_cast(half8, t);
    };

    STAGE_K(0, 0);
    __syncthreads();                       // K(0) resident

    for (int t = 0; t < 16; ++t) {
        const int buf = t & 1;
        STAGE_V(t);                        // V for THIS round (drained mid-round)
        if (t < 15) STAGE_K(t + 1, buf ^ 1);
        const char* ldsK = kbuf(buf, hf);

        // ---- S^T = K Q^T : two 32-key blocks, d chained over 4 chunks
        f32x16 s0 = {}, s1 = {};
        __builtin_amdgcn_s_setprio(1);
        s0 = __builtin_amdgcn_mfma_f32_32x32x16_f16(ldF(ldsK, 0, 0), qf0, s0, 0, 0, 0);
        s0 = __builtin_amdgcn_mfma_f32_32x32x16_f16(ldF(ldsK, 0, 1), qf1, s0, 0, 0, 0);
        s0 = __builtin_amdgcn_mfma_f32_32x32x16_f16(ldF(ldsK, 0, 2), qf2, s0, 0, 0, 0);
        s0 = __builtin_amdgcn_mfma_f32_32x32x16_f16(ldF(ldsK, 0, 3), qf3, s0, 0, 0, 0);
        s1 = __builtin_amdgcn_mfma_f32_32x32x16_f16(ldF(ldsK, 1, 0), qf0, s1, 0, 0, 0);
        s1 = __builtin_amdgcn_mfma_f32_32x32x16_f16(ldF(ldsK, 1, 1), qf1, s1, 0, 0, 0);
        s1 = __builtin_amdgcn_mfma_f32_32x32x16_f16(ldF(ldsK, 1, 2), qf2, s1, 0, 0, 0);
        s1 = __builtin_amdgcn_mfma_f32_32x32x16_f16(ldF(ldsK, 1, 3), qf3, s1, 0, 0, 0);
        __builtin_amdgcn_s_setprio(0);

        // ---- lane-local online softmax (exp2 domain), defer-max THR=14
        float mx[16];
#pragma unroll
        for (int i = 0; i < 16; ++i) mx[i] = fmaxf(s0[i], s1[i]);
#pragma unroll
        for (int st = 8; st > 0; st >>= 1)
#pragma unroll
            for (int i = 0; i < 8; ++i)
                if (i < st) mx[i] = fmaxf(mx[i], mx[i + st]);
        float tm = fmaxf(mx[0], __shfl_xor(mx[0], 32));
        if (!__all(tm <= m_q + 14.f)) {
            float mn = fmaxf(m_q, tm);
            float sc = fexp2(m_q - mn);
            m_q = mn;
            l_q *= sc;
            int scb = __builtin_bit_cast(int, sc);
#pragma unroll
            for (int r = 0; r < 16; ++r) {
                int qr = (r & 3) + 8 * (r >> 2) + 4 * hi;
                float s = __builtin_bit_cast(float, __builtin_amdgcn_ds_bpermute(4 * qr, scb));
                oacc0[r] *= s;
                oacc1[r] *= s;
            }
        }
        float rs = 0.f;
#pragma unroll
        for (int i = 0; i < 16; ++i) { float p = fexp2(s0[i] - m_q); s0[i] = p; rs += p; }
#pragma unroll
        for (int i = 0; i < 16; ++i) { float p = fexp2(s1[i] - m_q); s1[i] = p; rs += p; }
        rs += __shfl_xor(rs, 32);
        l_q += rs;

        // ---- P -> A-fragments (in-register)
        half8 pa0 = mkpa(s0, 0), pa1 = mkpa(s0, 8);
        half8 pa2 = mkpa(s1, 0), pa3 = mkpa(s1, 8);

        __syncthreads();                   // drain V(t) DMA (K(t+1) drains early too)

        // ---- O += P V
        const char* ldsV = vbuf(hf);
        __builtin_amdgcn_s_setprio(1);
        oacc0 = __builtin_amdgcn_mfma_f32_32x32x16_f16(pa0, ldF(ldsV, 0, 0), oacc0, 0, 0, 0);
        oacc0 = __builtin_amdgcn_mfma_f32_32x32x16_f16(pa1, ldF(ldsV, 0, 1), oacc0, 0, 0, 0);
        oacc0 = __builtin_amdgcn_mfma_f32_32x32x16_f16(pa2, ldF(ldsV, 0, 2), oacc0, 0, 0, 0);
        oacc0 = __builtin_amdgcn_mfma_f32_32x32x16_f16(pa3, ldF(ldsV, 0, 3), oacc0, 0, 0, 0);
        oacc1 = __builtin_amdgcn_mfma_f32_32x32x16_f16(pa0, ldF(ldsV, 1, 0), oacc1, 0, 0, 0);
        oacc1 = __builtin_amdgcn_mfma_f32_32x32x16_f16(pa1, ldF(ldsV, 1, 1), oacc1, 0, 0, 0);
        oacc1 = __builtin_amdgcn_mfma_f32_32x32x16_f16(pa2, ldF(ldsV, 1, 2), oacc1, 0, 0, 0);
        oacc1 = __builtin_amdgcn_mfma_f32_32x32x16_f16(pa3, ldF(ldsV, 1, 3), oacc1, 0, 0, 0);
        __builtin_amdgcn_s_setprio(0);

        __syncthreads();                   // all waves done with V(t) before next stage
    }

    // ---- merge wave pairs (w <-> w+4) via LDS, exp2 domain ----
    float* MRG = (float*)SB;               // 4 regions x 2176 f32 (34.8 KB)
    if (hf == 1) {
        float* B = MRG + wq * 2176;
        B[lane] = m_q;
        B[64 + lane] = l_q;
#pragma unroll
        for (int r = 0; r < 16; ++r) {
            B[128 + r * 64 + lane] = oacc0[r];
            B[1152 + r * 64 + lane] = oacc1[r];
        }
    }
    __syncthreads();
    if (hf == 0) {
        float* B = MRG + wq * 2176;
        float m1 = B[lane], l1 = B[64 + lane];
        float m = fmaxf(m_q, m1);
        float e0 = fexp2(m_q - m), e1 = fexp2(m1 - m);
        float linv = 1.f / (l_q * e0 + l1 * e1);
        int e0b = __builtin_bit_cast(int, e0);
        int e1b = __builtin_bit_cast(int, e1);
        int ivb = __builtin_bit_cast(int, linv);
#pragma unroll
        for (int r = 0; r < 16; ++r) {
            int qr = (r & 3) + 8 * (r >> 2) + 4 * hi;
            float s0f = __builtin_bit_cast(float, __builtin_amdgcn_ds_bpermute(4 * qr, e0b));
            float s1f = __builtin_bit_cast(float, __builtin_amdgcn_ds_bpermute(4 * qr, e1b));
            float iv = __builtin_bit_cast(float, __builtin_amdgcn_ds_bpermute(4 * qr, ivb));
            float o0 = (oacc0[r] * s0f + B[128 + r * 64 + lane] * s1f) * iv;
            float o1 = (oacc1[r] * s0f + B[1152 + r * 64 + lane] * s1f) * iv;
            int qglob = qt * 128 + wq * 32 + qr;
            size_t base = ((size_t)(n * S_LEN + qglob)) * DM + h * HD + l31;
            Oatt[base] = (_Float16)o0;
            Oatt[base + 32] = (_Float16)o1;
        }
    }
}

// ---------------------------------------------------------------------------
// Projection GEMM: 128x64 tile, BK=64, grid 512 (2 blocks/CU), LDS 48 KB
// double-buffered via gload16 (inverse-swizzled source, linear dest).
// 4 waves; wave w owns M rows [w*32, w*32+32) x all 64 N cols.
// XCD: ot = (id&7) + 8*((id>>3)&1) pins W strips per XCD.
// ---------------------------------------------------------------------------
__global__ __launch_bounds__(256) void k_proj(const _Float16* __restrict__ A,
                                              const _Float16* __restrict__ W,
                                              const float* __restrict__ bias,
                                              float* __restrict__ out) {
    __shared__ _Float16 As[2][128 * 64];   // 16 KB each
    __shared__ _Float16 Ws[2][64 * 64];    // 8 KB each

    const int id = blockIdx.x;
    const int ot = (id & 7) + 8 * ((id >> 3) & 1);   // 0..15, O strip of 64
    const int mt = id >> 4;                          // 0..31, M strip of 128
    const int tid = threadIdx.x;
    const int w = tid >> 6;
    const int lane = tid & 63;
    const int lr = lane & 15, lg = lane >> 4;
    const int wm = w * 32;

    const int rr = lane >> 3;
    const int cb = (lane & 7) * 16;
    const int gcb = cb ^ (rr << 4);

    const char* Abase = (const char*)(A + (size_t)(mt * 128) * DM);
    const char* Wbase = (const char*)(W + (size_t)(ot * 64) * DM);

    auto STAGE = [&](int kt, int b) {
#pragma unroll
        for (int r = 0; r < 4; ++r) {
            int row = r * 32 + w * 8 + rr;
            gload16(Abase + (size_t)row * 2048 + kt * 128 + gcb,
                    (char*)&As[b][0] + (r * 32 + w * 8) * 128);
        }
#pragma unroll
        for (int r = 0; r < 2; ++r) {
            int row = r * 32 + w * 8 + rr;
            gload16(Wbase + (size_t)row * 2048 + kt * 128 + gcb,
                    (char*)&Ws[b][0] + (r * 32 + w * 8) * 128);
        }
    };

    f32x4 zero = {0.f, 0.f, 0.f, 0.f};
    f32x4 acc[2][4];
#pragma unroll
    for (int mi = 0; mi < 2; ++mi)
#pragma unroll
        for (int ni = 0; ni < 4; ++ni) acc[mi][ni] = zero;

    auto COMPUTE = [&](int b) {
        const char* ldsA = (const char*)&As[b][0];
        const char* ldsW = (const char*)&Ws[b][0];
        half8 af[2][2], wf[4][2];
#pragma unroll
        for (int mi = 0; mi < 2; ++mi) {
            int row = wm + mi * 16 + lr;
            int sw = (row & 7) << 4;
            const char* p = ldsA + row * 128;
            af[mi][0] = *(const half8*)(p + ((lg * 16) ^ sw));
            af[mi][1] = *(const half8*)(p + ((64 + lg * 16) ^ sw));
        }
#pragma unroll
        for (int ni = 0; ni < 4; ++ni) {
            int row = ni * 16 + lr;
            int sw = (row & 7) << 4;
            const char* p = ldsW + row * 128;
            wf[ni][0] = *(const half8*)(p + ((lg * 16) ^ sw));
            wf[ni][1] = *(const half8*)(p + ((64 + lg * 16) ^ sw));
        }
#pragma unroll
        for (int mi = 0; mi < 2; ++mi)
#pragma unroll
            for (int ni = 0; ni < 4; ++ni) {
                acc[mi][ni] = __builtin_amdgcn_mfma_f32_16x16x32_f16(af[mi][0], wf[ni][0], acc[mi][ni], 0, 0, 0);
                acc[mi][ni] = __builtin_amdgcn_mfma_f32_16x16x32_f16(af[mi][1], wf[ni][1], acc[mi][ni], 0, 0, 0);
            }
    };

    STAGE(0, 0);
    __syncthreads();
    for (int kt = 0; kt < 15; ++kt) {
        STAGE(kt + 1, (kt & 1) ^ 1);
        COMPUTE(kt & 1);
        __syncthreads();
    }
    COMPUTE(1);   // kt=15, no stage -> no DMA outstanding at endpgm

    // epilogue: C row = m (A dim), col = o (W dim)
#pragma unroll
    for (int ni = 0; ni < 4; ++ni) {
        int o = ot * 64 + ni * 16 + lr;
        float b = bias[o];
#pragma unroll
        for (int mi = 0; mi < 2; ++mi)
#pragma unroll
            for (int i = 0; i < 4; ++i) {
                int m = mt * 128 + wm + mi * 16 + lg * 4 + i;
                out[(size_t)m * DM + o] = acc[mi][ni][i] + b;
            }
    }
}

// ---------------------------------------------------------------------------
extern "C" void kernel_launch(void* const* d_in, const int* in_sizes, int n_in,
                              void* d_out, int out_size, void* d_ws, size_t ws_size,
                              hipStream_t stream) {
    const float* Q = (const float*)d_in[0];
    const float* K = (const float*)d_in[1];
    const float* V = (const float*)d_in[2];
    const float* Wo = (const float*)d_in[3];
    const float* bo = (const float*)d_in[4];
    float* out = (float*)d_out;
    char* ws = (char*)d_ws;

    _Float16* Kh = (_Float16*)(ws);                     // 8 MB
    _Float16* Vt = (_Float16*)(ws + (8u << 20));        // 8 MB
    _Float16* Oatt = (_Float16*)(ws + (16u << 20));     // 8 MB
    _Float16* Wh = (_Float16*)(ws + (24u << 20));       // 2 MB

    k_prep<<<6144, 256, 0, stream>>>(K, V, Wo, Kh, Vt, Wh);
    k_attn<<<512, 512, 0, stream>>>(Q, Kh, Vt, Oatt);
    k_proj<<<512, 256, 0, stream>>>(Oatt, Wh, bo, out);
}

// Round 19
// 91.398 us; speedup vs baseline: 1.7947x; 1.0048x over previous
//
#include <hip/hip_runtime.h>

typedef _Float16 half8 __attribute__((ext_vector_type(8)));
typedef _Float16 half4 __attribute__((ext_vector_type(4)));
typedef float f32x4 __attribute__((ext_vector_type(4)));
typedef float f32x16 __attribute__((ext_vector_type(16)));
typedef unsigned u32x4 __attribute__((ext_vector_type(4)));

#define N_B 2
#define S_LEN 2048
#define NH 16
#define HD 64
#define DM 1024
#define LOG2E 1.44269504088896f

__device__ __forceinline__ void gload16(const void* g, void* l) {
    __builtin_amdgcn_global_load_lds(
        (const __attribute__((address_space(1))) unsigned int*)g,
        (__attribute__((address_space(3))) unsigned int*)l, 16, 0, 0);
}

__device__ __forceinline__ float fexp2(float x) {
    float r;
    asm("v_exp_f32 %0, %1" : "=v"(r) : "v"(x));
    return r;
}

// ---------------------------------------------------------------------------
// Fused prep (one launch, grid 3584): blocks [0,2048) convert K (2 float4
// per thread) -> f16 [n][h][s][d]; [2048,2560) cvt W (2 float4 per thread);
// [2560,3584) transpose V -> Vt f16 [n][h][d][s].
// ---------------------------------------------------------------------------
__global__ __launch_bounds__(256) void k_prep(const float* __restrict__ K,
                                              const float* __restrict__ V,
                                              const float* __restrict__ Wo,
                                              _Float16* __restrict__ Kh,
                                              _Float16* __restrict__ Vt,
                                              _Float16* __restrict__ Wh) {
    __shared__ _Float16 tile[64][65];
    const int id = blockIdx.x;
    if (id < 2048) {                       // ---- K regroup, 2 float4/thread
#pragma unroll
        for (int u = 0; u < 2; ++u) {
            int i = id * 512 + u * 256 + threadIdx.x;
            float4 v = ((const float4*)K)[i];
            int base = i * 4;
            int d = base & 63;
            int h = (base >> 6) & 15;
            int s = (base >> 10) & 2047;
            int n = base >> 21;
            size_t o = ((size_t)((n * NH + h) * S_LEN + s)) * HD + d;
            half4 hv = {(_Float16)v.x, (_Float16)v.y, (_Float16)v.z, (_Float16)v.w};
            *(half4*)(Kh + o) = hv;
        }
    } else if (id < 2560) {                // ---- W convert, 2 float4/thread
#pragma unroll
        for (int u = 0; u < 2; ++u) {
            int i = (id - 2048) * 512 + u * 256 + threadIdx.x;
            float4 v = ((const float4*)Wo)[i];
            half4 hv = {(_Float16)v.x, (_Float16)v.y, (_Float16)v.z, (_Float16)v.w};
            *(half4*)(Wh + (size_t)i * 4) = hv;
        }
    } else {                               // ---- V transpose (vectorized)
        int b = id - 2560;
        int st = b & 31, h = (b >> 5) & 15, n = b >> 9;
        int r0 = threadIdx.x >> 4;         // 0..15
        int c4 = (threadIdx.x & 15) * 4;   // 0,4,..,60
#pragma unroll
        for (int i = 0; i < 4; ++i) {
            int row = i * 16 + r0;
            float4 v = *(const float4*)(V + ((size_t)(n * S_LEN) + st * 64 + row) * DM + h * HD + c4);
            tile[row][c4 + 0] = (_Float16)v.x;
            tile[row][c4 + 1] = (_Float16)v.y;
            tile[row][c4 + 2] = (_Float16)v.z;
            tile[row][c4 + 3] = (_Float16)v.w;
        }
        __syncthreads();
#pragma unroll
        for (int i = 0; i < 4; ++i) {
            int d = i * 16 + r0;
            half4 hv = {tile[c4 + 0][d], tile[c4 + 1][d], tile[c4 + 2][d], tile[c4 + 3][d]};
            *(half4*)(Vt + ((size_t)((n * NH + h) * HD + d)) * S_LEN + st * 64 + c4) = hv;
        }
    }
}

// ---------------------------------------------------------------------------
// Flash attention (best-measured, 67-68us): 32x32 MFMA, in-register P
// (cvt_pkrtz + shfl mkpa), wave-level KV split, fragment-order LDS layout
// (conflict-free reads; permutation on per-lane global source, linear LDS
// dest). Block = 8 waves (512 thr), QBLK=128; wave w: q-subtile (w&3), KV
// half (w>>2). K dbuf; V single (mid-round drain). defer-max THR=14.
// ---------------------------------------------------------------------------
__global__ __launch_bounds__(512, 4) void k_attn(const float* __restrict__ Q,
                                                 const _Float16* __restrict__ Kh,
                                                 const _Float16* __restrict__ Vth,
                                                 _Float16* __restrict__ Oatt) {
    __shared__ char SB[49152];
    // [0,32768): K dbuf (b,hf) 8KB each ; [32768,49152): V single (hf) 8KB

    // XCD swizzle (bijective on 512 = 8 * 64): 4 nh per XCD, 16 qt each
    const int id = blockIdx.x;
    const int xcd = id & 7;
    const int sl = id >> 3;              // 0..63
    const int nh = xcd + 8 * (sl >> 4);
    const int qt = sl & 15;              // q tile of 128

    const int tid = threadIdx.x;
    const int w = tid >> 6;              // 0..7
    const int wq = w & 3;                // q-subtile
    const int hf = w >> 2;               // KV half
    const int lane = tid & 63;
    const int l31 = lane & 31;
    const int hi = lane >> 5;
    const int n = nh >> 4, h = nh & 15;

    const size_t head = (size_t)nh * S_LEN * HD;
    const char* Khead = (const char*)(Kh + head);
    const char* Vhead = (const char*)(Vth + head);

    // ---- Q fragments (B-frag: col q=l31, k=8hi+j per 16-d chunk), LOG2E-scaled
    const int qg = qt * 128 + wq * 32 + l31;
    const float* qbase = Q + ((size_t)(n * S_LEN) + qg) * DM + h * HD;
    auto mkqf = [&](int c) -> half8 {
        float4 a = *(const float4*)(qbase + 16 * c + 8 * hi);
        float4 b = *(const float4*)(qbase + 16 * c + 8 * hi + 4);
        half8 r = {(_Float16)(a.x * LOG2E), (_Float16)(a.y * LOG2E),
                   (_Float16)(a.z * LOG2E), (_Float16)(a.w * LOG2E),
                   (_Float16)(b.x * LOG2E), (_Float16)(b.y * LOG2E),
                   (_Float16)(b.z * LOG2E), (_Float16)(b.w * LOG2E)};
        return r;
    };
    half8 qf0 = mkqf(0), qf1 = mkqf(1), qf2 = mkqf(2), qf3 = mkqf(3);

    f32x16 oacc0 = {}, oacc1 = {};
    float m_q = -1e30f, l_q = 0.f;       // per q=l31 (2x redundant over hi)

    auto kbuf = [&](int b, int half) -> char* { return SB + (b * 2 + half) * 8192; };
    auto vbuf = [&](int half) -> char* { return SB + 32768 + half * 8192; };

    // staging: wave stages slices wq*2+j; per lane, decode the fragment-order
    // index and fetch the matching element from global.
    auto STAGE_K = [&](int t, int b) {
#pragma unroll
        for (int j = 0; j < 2; ++j) {
            int slice = wq * 2 + j;            // 0..7
            int idx = slice * 64 + lane;       // 0..511
            int bhi = idx & 1;
            int bl31 = (idx >> 1) & 31;
            int bc = (idx >> 6) & 3;
            int bblk = idx >> 8;
            int key = hf * 1024 + t * 64 + bblk * 32 + bl31;
            gload16(Khead + (size_t)key * 128 + bc * 32 + bhi * 16,
                    kbuf(b, hf) + slice * 1024);
        }
    };
    auto STAGE_V = [&](int t) {
#pragma unroll
        for (int j = 0; j < 2; ++j) {
            int slice = wq * 2 + j;
            int idx = slice * 64 + lane;
            int bhi = idx & 1;
            int bl31 = (idx >> 1) & 31;
            int bc = (idx >> 6) & 3;
            int bblk = idx >> 8;
            int drow = bblk * 32 + bl31;
            gload16(Vhead + (size_t)drow * 4096 + hf * 2048 + t * 128 + bc * 32 + bhi * 16,
                    vbuf(hf) + slice * 1024);
        }
    };

    // fragment read: contiguous 1KB per (blk,c) -- conflict-free
    auto ldF = [&](const char* lds, int blk, int c) -> half8 {
        int off = (((blk * 4 + c) * 32 + l31) * 2 + hi) * 16;
        return *(const half8*)(lds + off);
    };

    auto pkrtz = [&](float a, float b) -> unsigned {
        return __builtin_bit_cast(unsigned, __builtin_amdgcn_cvt_pkrtz(a, b));
    };
    auto mkpa = [&](const f32x16& S, int rb) -> half8 {
        unsigned w0 = pkrtz(S[rb + 0], S[rb + 1]);
        unsigned w1 = pkrtz(S[rb + 2], S[rb + 3]);
        unsigned w2 = pkrtz(S[rb + 4], S[rb + 5]);
        unsigned w3 = pkrtz(S[rb + 6], S[rb + 7]);
        unsigned x0 = (unsigned)__shfl_xor((int)w0, 32);
        unsigned x1 = (unsigned)__shfl_xor((int)w1, 32);
        unsigned x2 = (unsigned)__shfl_xor((int)w2, 32);
        unsigned x3 = (unsigned)__shfl_xor((int)w3, 32);
        u32x4 t;
        t[0] = hi ? x2 : w0;
        t[1] = hi ? x3 : w1;
        t[2] = hi ? w2 : x0;
        t[3] = hi ? w3 : x1;
        return __builtin_bit_cast(half8, t);
    };

    STAGE_K(0, 0);
    __syncthreads();                       // K(0) resident

    for (int t = 0; t < 16; ++t) {
        const int buf = t & 1;
        STAGE_V(t);                        // V for THIS round (drained mid-round)
        if (t < 15) STAGE_K(t + 1, buf ^ 1);
        const char* ldsK = kbuf(buf, hf);

        // ---- S^T = K Q^T : two 32-key blocks, d chained over 4 chunks
        f32x16 s0 = {}, s1 = {};
        __builtin_amdgcn_s_setprio(1);
        s0 = __builtin_amdgcn_mfma_f32_32x32x16_f16(ldF(ldsK, 0, 0), qf0, s0, 0, 0, 0);
        s0 = __builtin_amdgcn_mfma_f32_32x32x16_f16(ldF(ldsK, 0, 1), qf1, s0, 0, 0, 0);
        s0 = __builtin_amdgcn_mfma_f32_32x32x16_f16(ldF(ldsK, 0, 2), qf2, s0, 0, 0, 0);
        s0 = __builtin_amdgcn_mfma_f32_32x32x16_f16(ldF(ldsK, 0, 3), qf3, s0, 0, 0, 0);
        s1 = __builtin_amdgcn_mfma_f32_32x32x16_f16(ldF(ldsK, 1, 0), qf0, s1, 0, 0, 0);
        s1 = __builtin_amdgcn_mfma_f32_32x32x16_f16(ldF(ldsK, 1, 1), qf1, s1, 0, 0, 0);
        s1 = __builtin_amdgcn_mfma_f32_32x32x16_f16(ldF(ldsK, 1, 2), qf2, s1, 0, 0, 0);
        s1 = __builtin_amdgcn_mfma_f32_32x32x16_f16(ldF(ldsK, 1, 3), qf3, s1, 0, 0, 0);
        __builtin_amdgcn_s_setprio(0);

        // ---- lane-local online softmax (exp2 domain), defer-max THR=14
        float mx[16];
#pragma unroll
        for (int i = 0; i < 16; ++i) mx[i] = fmaxf(s0[i], s1[i]);
#pragma unroll
        for (int st = 8; st > 0; st >>= 1)
#pragma unroll
            for (int i = 0; i < 8; ++i)
                if (i < st) mx[i] = fmaxf(mx[i], mx[i + st]);
        float tm = fmaxf(mx[0], __shfl_xor(mx[0], 32));
        if (!__all(tm <= m_q + 14.f)) {
            float mn = fmaxf(m_q, tm);
            float sc = fexp2(m_q - mn);
            m_q = mn;
            l_q *= sc;
            int scb = __builtin_bit_cast(int, sc);
#pragma unroll
            for (int r = 0; r < 16; ++r) {
                int qr = (r & 3) + 8 * (r >> 2) + 4 * hi;
                float s = __builtin_bit_cast(float, __builtin_amdgcn_ds_bpermute(4 * qr, scb));
                oacc0[r] *= s;
                oacc1[r] *= s;
            }
        }
        float rs = 0.f;
#pragma unroll
        for (int i = 0; i < 16; ++i) { float p = fexp2(s0[i] - m_q); s0[i] = p; rs += p; }
#pragma unroll
        for (int i = 0; i < 16; ++i) { float p = fexp2(s1[i] - m_q); s1[i] = p; rs += p; }
        rs += __shfl_xor(rs, 32);
        l_q += rs;

        // ---- P -> A-fragments (in-register)
        half8 pa0 = mkpa(s0, 0), pa1 = mkpa(s0, 8);
        half8 pa2 = mkpa(s1, 0), pa3 = mkpa(s1, 8);

        __syncthreads();                   // drain V(t) DMA (K(t+1) drains early too)

        // ---- O += P V
        const char* ldsV = vbuf(hf);
        __builtin_amdgcn_s_setprio(1);
        oacc0 = __builtin_amdgcn_mfma_f32_32x32x16_f16(pa0, ldF(ldsV, 0, 0), oacc0, 0, 0, 0);
        oacc0 = __builtin_amdgcn_mfma_f32_32x32x16_f16(pa1, ldF(ldsV, 0, 1), oacc0, 0, 0, 0);
        oacc0 = __builtin_amdgcn_mfma_f32_32x32x16_f16(pa2, ldF(ldsV, 0, 2), oacc0, 0, 0, 0);
        oacc0 = __builtin_amdgcn_mfma_f32_32x32x16_f16(pa3, ldF(ldsV, 0, 3), oacc0, 0, 0, 0);
        oacc1 = __builtin_amdgcn_mfma_f32_32x32x16_f16(pa0, ldF(ldsV, 1, 0), oacc1, 0, 0, 0);
        oacc1 = __builtin_amdgcn_mfma_f32_32x32x16_f16(pa1, ldF(ldsV, 1, 1), oacc1, 0, 0, 0);
        oacc1 = __builtin_amdgcn_mfma_f32_32x32x16_f16(pa2, ldF(ldsV, 1, 2), oacc1, 0, 0, 0);
        oacc1 = __builtin_amdgcn_mfma_f32_32x32x16_f16(pa3, ldF(ldsV, 1, 3), oacc1, 0, 0, 0);
        __builtin_amdgcn_s_setprio(0);

        __syncthreads();                   // all waves done with V(t) before next stage
    }

    // ---- merge wave pairs (w <-> w+4) via LDS, exp2 domain ----
    float* MRG = (float*)SB;               // 4 regions x 2176 f32 (34.8 KB)
    if (hf == 1) {
        float* B = MRG + wq * 2176;
        B[lane] = m_q;
        B[64 + lane] = l_q;
#pragma unroll
        for (int r = 0; r < 16; ++r) {
            B[128 + r * 64 + lane] = oacc0[r];
            B[1152 + r * 64 + lane] = oacc1[r];
        }
    }
    __syncthreads();
    if (hf == 0) {
        float* B = MRG + wq * 2176;
        float m1 = B[lane], l1 = B[64 + lane];
        float m = fmaxf(m_q, m1);
        float e0 = fexp2(m_q - m), e1 = fexp2(m1 - m);
        float linv = 1.f / (l_q * e0 + l1 * e1);
        int e0b = __builtin_bit_cast(int, e0);
        int e1b = __builtin_bit_cast(int, e1);
        int ivb = __builtin_bit_cast(int, linv);
#pragma unroll
        for (int r = 0; r < 16; ++r) {
            int qr = (r & 3) + 8 * (r >> 2) + 4 * hi;
            float s0f = __builtin_bit_cast(float, __builtin_amdgcn_ds_bpermute(4 * qr, e0b));
            float s1f = __builtin_bit_cast(float, __builtin_amdgcn_ds_bpermute(4 * qr, e1b));
            float iv = __builtin_bit_cast(float, __builtin_amdgcn_ds_bpermute(4 * qr, ivb));
            float o0 = (oacc0[r] * s0f + B[128 + r * 64 + lane] * s1f) * iv;
            float o1 = (oacc1[r] * s0f + B[1152 + r * 64 + lane] * s1f) * iv;
            int qglob = qt * 128 + wq * 32 + qr;
            size_t base = ((size_t)(n * S_LEN + qglob)) * DM + h * HD + l31;
            Oatt[base] = (_Float16)o0;
            Oatt[base + 32] = (_Float16)o1;
        }
    }
}

// ---------------------------------------------------------------------------
// Projection GEMM: 128x64 tile, BK=64, grid 512 (2 blocks/CU), LDS 48 KB
// double-buffered via gload16 (inverse-swizzled source, linear dest).
// 4 waves; wave w owns M rows [w*32, w*32+32) x all 64 N cols.
// XCD: ot = (id&7) + 8*((id>>3)&1) pins W strips per XCD.
// ---------------------------------------------------------------------------
__global__ __launch_bounds__(256) void k_proj(const _Float16* __restrict__ A,
                                              const _Float16* __restrict__ W,
                                              const float* __restrict__ bias,
                                              float* __restrict__ out) {
    __shared__ _Float16 As[2][128 * 64];   // 16 KB each
    __shared__ _Float16 Ws[2][64 * 64];    // 8 KB each

    const int id = blockIdx.x;
    const int ot = (id & 7) + 8 * ((id >> 3) & 1);   // 0..15, O strip of 64
    const int mt = id >> 4;                          // 0..31, M strip of 128
    const int tid = threadIdx.x;
    const int w = tid >> 6;
    const int lane = tid & 63;
    const int lr = lane & 15, lg = lane >> 4;
    const int wm = w * 32;

    const int rr = lane >> 3;
    const int cb = (lane & 7) * 16;
    const int gcb = cb ^ (rr << 4);

    const char* Abase = (const char*)(A + (size_t)(mt * 128) * DM);
    const char* Wbase = (const char*)(W + (size_t)(ot * 64) * DM);

    auto STAGE = [&](int kt, int b) {
#pragma unroll
        for (int r = 0; r < 4; ++r) {
            int row = r * 32 + w * 8 + rr;
            gload16(Abase + (size_t)row * 2048 + kt * 128 + gcb,
                    (char*)&As[b][0] + (r * 32 + w * 8) * 128);
        }
#pragma unroll
        for (int r = 0; r < 2; ++r) {
            int row = r * 32 + w * 8 + rr;
            gload16(Wbase + (size_t)row * 2048 + kt * 128 + gcb,
                    (char*)&Ws[b][0] + (r * 32 + w * 8) * 128);
        }
    };

    f32x4 zero = {0.f, 0.f, 0.f, 0.f};
    f32x4 acc[2][4];
#pragma unroll
    for (int mi = 0; mi < 2; ++mi)
#pragma unroll
        for (int ni = 0; ni < 4; ++ni) acc[mi][ni] = zero;

    auto COMPUTE = [&](int b) {
        const char* ldsA = (const char*)&As[b][0];
        const char* ldsW = (const char*)&Ws[b][0];
        half8 af[2][2], wf[4][2];
#pragma unroll
        for (int mi = 0; mi < 2; ++mi) {
            int row = wm + mi * 16 + lr;
            int sw = (row & 7) << 4;
            const char* p = ldsA + row * 128;
            af[mi][0] = *(const half8*)(p + ((lg * 16) ^ sw));
            af[mi][1] = *(const half8*)(p + ((64 + lg * 16) ^ sw));
        }
#pragma unroll
        for (int ni = 0; ni < 4; ++ni) {
            int row = ni * 16 + lr;
            int sw = (row & 7) << 4;
            const char* p = ldsW + row * 128;
            wf[ni][0] = *(const half8*)(p + ((lg * 16) ^ sw));
            wf[ni][1] = *(const half8*)(p + ((64 + lg * 16) ^ sw));
        }
#pragma unroll
        for (int mi = 0; mi < 2; ++mi)
#pragma unroll
            for (int ni = 0; ni < 4; ++ni) {
                acc[mi][ni] = __builtin_amdgcn_mfma_f32_16x16x32_f16(af[mi][0], wf[ni][0], acc[mi][ni], 0, 0, 0);
                acc[mi][ni] = __builtin_amdgcn_mfma_f32_16x16x32_f16(af[mi][1], wf[ni][1], acc[mi][ni], 0, 0, 0);
            }
    };

    STAGE(0, 0);
    __syncthreads();
    for (int kt = 0; kt < 15; ++kt) {
        STAGE(kt + 1, (kt & 1) ^ 1);
        COMPUTE(kt & 1);
        __syncthreads();
    }
    COMPUTE(1);   // kt=15, no stage -> no DMA outstanding at endpgm

    // epilogue: C row = m (A dim), col = o (W dim)
#pragma unroll
    for (int ni = 0; ni < 4; ++ni) {
        int o = ot * 64 + ni * 16 + lr;
        float b = bias[o];
#pragma unroll
        for (int mi = 0; mi < 2; ++mi)
#pragma unroll
            for (int i = 0; i < 4; ++i) {
                int m = mt * 128 + wm + mi * 16 + lg * 4 + i;
                out[(size_t)m * DM + o] = acc[mi][ni][i] + b;
            }
    }
}

// ---------------------------------------------------------------------------
extern "C" void kernel_launch(void* const* d_in, const int* in_sizes, int n_in,
                              void* d_out, int out_size, void* d_ws, size_t ws_size,
                              hipStream_t stream) {
    const float* Q = (const float*)d_in[0];
    const float* K = (const float*)d_in[1];
    const float* V = (const float*)d_in[2];
    const float* Wo = (const float*)d_in[3];
    const float* bo = (const float*)d_in[4];
    float* out = (float*)d_out;
    char* ws = (char*)d_ws;

    _Float16* Kh = (_Float16*)(ws);                     // 8 MB
    _Float16* Vt = (_Float16*)(ws + (8u << 20));        // 8 MB
    _Float16* Oatt = (_Float16*)(ws + (16u << 20));     // 8 MB
    _Float16* Wh = (_Float16*)(ws + (24u << 20));       // 2 MB

    k_prep<<<3584, 256, 0, stream>>>(K, V, Wo, Kh, Vt, Wh);
    k_attn<<<512, 512, 0, stream>>>(Q, Kh, Vt, Oatt);
    k_proj<<<512, 256, 0, stream>>>(Oatt, Wh, bo, out);
}

// Round 20
// 89.322 us; speedup vs baseline: 1.8364x; 1.0232x over previous
//
#include <hip/hip_runtime.h>

typedef _Float16 half8 __attribute__((ext_vector_type(8)));
typedef _Float16 half4 __attribute__((ext_vector_type(4)));
typedef float f32x4 __attribute__((ext_vector_type(4)));
typedef float f32x16 __attribute__((ext_vector_type(16)));
typedef unsigned u32x4 __attribute__((ext_vector_type(4)));

#define N_B 2
#define S_LEN 2048
#define NH 16
#define HD 64
#define DM 1024
#define LOG2E 1.44269504088896f

__device__ __forceinline__ void gload16(const void* g, void* l) {
    __builtin_amdgcn_global_load_lds(
        (const __attribute__((address_space(1))) unsigned int*)g,
        (__attribute__((address_space(3))) unsigned int*)l, 16, 0, 0);
}

__device__ __forceinline__ float fexp2(float x) {
    float r;
    asm("v_exp_f32 %0, %1" : "=v"(r) : "v"(x));
    return r;
}

// ---------------------------------------------------------------------------
// Fused prep (one launch, grid 3584): blocks [0,2048) convert K (2 float4
// per thread) -> f16 [n][h][s][d]; [2048,2560) cvt W (2 float4 per thread);
// [2560,3584) transpose V -> Vt f16 [n][h][d][s].
// ---------------------------------------------------------------------------
__global__ __launch_bounds__(256) void k_prep(const float* __restrict__ K,
                                              const float* __restrict__ V,
                                              const float* __restrict__ Wo,
                                              _Float16* __restrict__ Kh,
                                              _Float16* __restrict__ Vt,
                                              _Float16* __restrict__ Wh) {
    __shared__ _Float16 tile[64][65];
    const int id = blockIdx.x;
    if (id < 2048) {                       // ---- K regroup, 2 float4/thread
#pragma unroll
        for (int u = 0; u < 2; ++u) {
            int i = id * 512 + u * 256 + threadIdx.x;
            float4 v = ((const float4*)K)[i];
            int base = i * 4;
            int d = base & 63;
            int h = (base >> 6) & 15;
            int s = (base >> 10) & 2047;
            int n = base >> 21;
            size_t o = ((size_t)((n * NH + h) * S_LEN + s)) * HD + d;
            half4 hv = {(_Float16)v.x, (_Float16)v.y, (_Float16)v.z, (_Float16)v.w};
            *(half4*)(Kh + o) = hv;
        }
    } else if (id < 2560) {                // ---- W convert, 2 float4/thread
#pragma unroll
        for (int u = 0; u < 2; ++u) {
            int i = (id - 2048) * 512 + u * 256 + threadIdx.x;
            float4 v = ((const float4*)Wo)[i];
            half4 hv = {(_Float16)v.x, (_Float16)v.y, (_Float16)v.z, (_Float16)v.w};
            *(half4*)(Wh + (size_t)i * 4) = hv;
        }
    } else {                               // ---- V transpose (vectorized)
        int b = id - 2560;
        int st = b & 31, h = (b >> 5) & 15, n = b >> 9;
        int r0 = threadIdx.x >> 4;         // 0..15
        int c4 = (threadIdx.x & 15) * 4;   // 0,4,..,60
#pragma unroll
        for (int i = 0; i < 4; ++i) {
            int row = i * 16 + r0;
            float4 v = *(const float4*)(V + ((size_t)(n * S_LEN) + st * 64 + row) * DM + h * HD + c4);
            tile[row][c4 + 0] = (_Float16)v.x;
            tile[row][c4 + 1] = (_Float16)v.y;
            tile[row][c4 + 2] = (_Float16)v.z;
            tile[row][c4 + 3] = (_Float16)v.w;
        }
        __syncthreads();
#pragma unroll
        for (int i = 0; i < 4; ++i) {
            int d = i * 16 + r0;
            half4 hv = {tile[c4 + 0][d], tile[c4 + 1][d], tile[c4 + 2][d], tile[c4 + 3][d]};
            *(half4*)(Vt + ((size_t)((n * NH + h) * HD + d)) * S_LEN + st * 64 + c4) = hv;
        }
    }
}

// ---------------------------------------------------------------------------
// Flash attention, ONE barrier per round (minimal T3 recipe): K AND V both
// double-buffered (64 KB LDS); round t = { STAGE K/V(t+1) -> buf^1;
// QK(t) ; softmax ; PV(t) from buf ; __syncthreads() }. The single
// end-of-round barrier (full vmcnt+lgkm drain) orders staged-DMA completion
// and buffer reuse. 32x32 MFMA, in-register P (cvt_pkrtz + shfl mkpa),
// wave-level KV split, fragment-order LDS layout (conflict-free reads;
// permutation on per-lane global source, linear LDS dest). Block = 8 waves
// (512 thr), QBLK=128; wave w: q-subtile (w&3), KV half (w>>2).
// defer-max THR=14. No DMA outstanding at endpgm.
// ---------------------------------------------------------------------------
__global__ __launch_bounds__(512, 4) void k_attn(const float* __restrict__ Q,
                                                 const _Float16* __restrict__ Kh,
                                                 const _Float16* __restrict__ Vth,
                                                 _Float16* __restrict__ Oatt) {
    __shared__ char SB[65536];
    // [0,32768): K dbuf (b,hf) 8KB each ; [32768,65536): V dbuf (b,hf) 8KB each

    // XCD swizzle (bijective on 512 = 8 * 64): 4 nh per XCD, 16 qt each
    const int id = blockIdx.x;
    const int xcd = id & 7;
    const int sl = id >> 3;              // 0..63
    const int nh = xcd + 8 * (sl >> 4);
    const int qt = sl & 15;              // q tile of 128

    const int tid = threadIdx.x;
    const int w = tid >> 6;              // 0..7
    const int wq = w & 3;                // q-subtile
    const int hf = w >> 2;               // KV half
    const int lane = tid & 63;
    const int l31 = lane & 31;
    const int hi = lane >> 5;
    const int n = nh >> 4, h = nh & 15;

    const size_t head = (size_t)nh * S_LEN * HD;
    const char* Khead = (const char*)(Kh + head);
    const char* Vhead = (const char*)(Vth + head);

    // ---- Q fragments (B-frag: col q=l31, k=8hi+j per 16-d chunk), LOG2E-scaled
    const int qg = qt * 128 + wq * 32 + l31;
    const float* qbase = Q + ((size_t)(n * S_LEN) + qg) * DM + h * HD;
    auto mkqf = [&](int c) -> half8 {
        float4 a = *(const float4*)(qbase + 16 * c + 8 * hi);
        float4 b = *(const float4*)(qbase + 16 * c + 8 * hi + 4);
        half8 r = {(_Float16)(a.x * LOG2E), (_Float16)(a.y * LOG2E),
                   (_Float16)(a.z * LOG2E), (_Float16)(a.w * LOG2E),
                   (_Float16)(b.x * LOG2E), (_Float16)(b.y * LOG2E),
                   (_Float16)(b.z * LOG2E), (_Float16)(b.w * LOG2E)};
        return r;
    };
    half8 qf0 = mkqf(0), qf1 = mkqf(1), qf2 = mkqf(2), qf3 = mkqf(3);

    f32x16 oacc0 = {}, oacc1 = {};
    float m_q = -1e30f, l_q = 0.f;       // per q=l31 (2x redundant over hi)

    auto kbuf = [&](int b, int half) -> char* { return SB + (b * 2 + half) * 8192; };
    auto vbuf = [&](int b, int half) -> char* { return SB + 32768 + (b * 2 + half) * 8192; };

    // staging: wave stages slices wq*2+j; per lane, decode the fragment-order
    // index and fetch the matching element from global.
    auto STAGE_K = [&](int t, int b) {
#pragma unroll
        for (int j = 0; j < 2; ++j) {
            int slice = wq * 2 + j;            // 0..7
            int idx = slice * 64 + lane;       // 0..511
            int bhi = idx & 1;
            int bl31 = (idx >> 1) & 31;
            int bc = (idx >> 6) & 3;
            int bblk = idx >> 8;
            int key = hf * 1024 + t * 64 + bblk * 32 + bl31;
            gload16(Khead + (size_t)key * 128 + bc * 32 + bhi * 16,
                    kbuf(b, hf) + slice * 1024);
        }
    };
    auto STAGE_V = [&](int t, int b) {
#pragma unroll
        for (int j = 0; j < 2; ++j) {
            int slice = wq * 2 + j;
            int idx = slice * 64 + lane;
            int bhi = idx & 1;
            int bl31 = (idx >> 1) & 31;
            int bc = (idx >> 6) & 3;
            int bblk = idx >> 8;
            int drow = bblk * 32 + bl31;
            gload16(Vhead + (size_t)drow * 4096 + hf * 2048 + t * 128 + bc * 32 + bhi * 16,
                    vbuf(b, hf) + slice * 1024);
        }
    };

    // fragment read: contiguous 1KB per (blk,c) -- conflict-free
    auto ldF = [&](const char* lds, int blk, int c) -> half8 {
        int off = (((blk * 4 + c) * 32 + l31) * 2 + hi) * 16;
        return *(const half8*)(lds + off);
    };

    auto pkrtz = [&](float a, float b) -> unsigned {
        return __builtin_bit_cast(unsigned, __builtin_amdgcn_cvt_pkrtz(a, b));
    };
    auto mkpa = [&](const f32x16& S, int rb) -> half8 {
        unsigned w0 = pkrtz(S[rb + 0], S[rb + 1]);
        unsigned w1 = pkrtz(S[rb + 2], S[rb + 3]);
        unsigned w2 = pkrtz(S[rb + 4], S[rb + 5]);
        unsigned w3 = pkrtz(S[rb + 6], S[rb + 7]);
        unsigned x0 = (unsigned)__shfl_xor((int)w0, 32);
        unsigned x1 = (unsigned)__shfl_xor((int)w1, 32);
        unsigned x2 = (unsigned)__shfl_xor((int)w2, 32);
        unsigned x3 = (unsigned)__shfl_xor((int)w3, 32);
        u32x4 t;
        t[0] = hi ? x2 : w0;
        t[1] = hi ? x3 : w1;
        t[2] = hi ? w2 : x0;
        t[3] = hi ? w3 : x1;
        return __builtin_bit_cast(half8, t);
    };

    STAGE_K(0, 0);
    STAGE_V(0, 0);
    __syncthreads();                       // K(0), V(0) resident

    for (int t = 0; t < 16; ++t) {
        const int buf = t & 1;
        if (t < 15) {                      // prefetch next round into buf^1
            STAGE_K(t + 1, buf ^ 1);
            STAGE_V(t + 1, buf ^ 1);
        }
        const char* ldsK = kbuf(buf, hf);
        const char* ldsV = vbuf(buf, hf);

        // ---- S^T = K Q^T : two 32-key blocks, d chained over 4 chunks
        f32x16 s0 = {}, s1 = {};
        __builtin_amdgcn_s_setprio(1);
        s0 = __builtin_amdgcn_mfma_f32_32x32x16_f16(ldF(ldsK, 0, 0), qf0, s0, 0, 0, 0);
        s0 = __builtin_amdgcn_mfma_f32_32x32x16_f16(ldF(ldsK, 0, 1), qf1, s0, 0, 0, 0);
        s0 = __builtin_amdgcn_mfma_f32_32x32x16_f16(ldF(ldsK, 0, 2), qf2, s0, 0, 0, 0);
        s0 = __builtin_amdgcn_mfma_f32_32x32x16_f16(ldF(ldsK, 0, 3), qf3, s0, 0, 0, 0);
        s1 = __builtin_amdgcn_mfma_f32_32x32x16_f16(ldF(ldsK, 1, 0), qf0, s1, 0, 0, 0);
        s1 = __builtin_amdgcn_mfma_f32_32x32x16_f16(ldF(ldsK, 1, 1), qf1, s1, 0, 0, 0);
        s1 = __builtin_amdgcn_mfma_f32_32x32x16_f16(ldF(ldsK, 1, 2), qf2, s1, 0, 0, 0);
        s1 = __builtin_amdgcn_mfma_f32_32x32x16_f16(ldF(ldsK, 1, 3), qf3, s1, 0, 0, 0);
        __builtin_amdgcn_s_setprio(0);

        // ---- lane-local online softmax (exp2 domain), defer-max THR=14
        float mx[16];
#pragma unroll
        for (int i = 0; i < 16; ++i) mx[i] = fmaxf(s0[i], s1[i]);
#pragma unroll
        for (int st = 8; st > 0; st >>= 1)
#pragma unroll
            for (int i = 0; i < 8; ++i)
                if (i < st) mx[i] = fmaxf(mx[i], mx[i + st]);
        float tm = fmaxf(mx[0], __shfl_xor(mx[0], 32));
        if (!__all(tm <= m_q + 14.f)) {
            float mn = fmaxf(m_q, tm);
            float sc = fexp2(m_q - mn);
            m_q = mn;
            l_q *= sc;
            int scb = __builtin_bit_cast(int, sc);
#pragma unroll
            for (int r = 0; r < 16; ++r) {
                int qr = (r & 3) + 8 * (r >> 2) + 4 * hi;
                float s = __builtin_bit_cast(float, __builtin_amdgcn_ds_bpermute(4 * qr, scb));
                oacc0[r] *= s;
                oacc1[r] *= s;
            }
        }
        float rs = 0.f;
#pragma unroll
        for (int i = 0; i < 16; ++i) { float p = fexp2(s0[i] - m_q); s0[i] = p; rs += p; }
#pragma unroll
        for (int i = 0; i < 16; ++i) { float p = fexp2(s1[i] - m_q); s1[i] = p; rs += p; }
        rs += __shfl_xor(rs, 32);
        l_q += rs;

        // ---- P -> A-fragments (in-register)
        half8 pa0 = mkpa(s0, 0), pa1 = mkpa(s0, 8);
        half8 pa2 = mkpa(s1, 0), pa3 = mkpa(s1, 8);

        // ---- O += P V  (V(t) resident since last round's barrier)
        __builtin_amdgcn_s_setprio(1);
        oacc0 = __builtin_amdgcn_mfma_f32_32x32x16_f16(pa0, ldF(ldsV, 0, 0), oacc0, 0, 0, 0);
        oacc0 = __builtin_amdgcn_mfma_f32_32x32x16_f16(pa1, ldF(ldsV, 0, 1), oacc0, 0, 0, 0);
        oacc0 = __builtin_amdgcn_mfma_f32_32x32x16_f16(pa2, ldF(ldsV, 0, 2), oacc0, 0, 0, 0);
        oacc0 = __builtin_amdgcn_mfma_f32_32x32x16_f16(pa3, ldF(ldsV, 0, 3), oacc0, 0, 0, 0);
        oacc1 = __builtin_amdgcn_mfma_f32_32x32x16_f16(pa0, ldF(ldsV, 1, 0), oacc1, 0, 0, 0);
        oacc1 = __builtin_amdgcn_mfma_f32_32x32x16_f16(pa1, ldF(ldsV, 1, 1), oacc1, 0, 0, 0);
        oacc1 = __builtin_amdgcn_mfma_f32_32x32x16_f16(pa2, ldF(ldsV, 1, 2), oacc1, 0, 0, 0);
        oacc1 = __builtin_amdgcn_mfma_f32_32x32x16_f16(pa3, ldF(ldsV, 1, 3), oacc1, 0, 0, 0);
        __builtin_amdgcn_s_setprio(0);

        __syncthreads();   // single per-round barrier: drains stage DMA + orders buf reuse
    }

    // ---- merge wave pairs (w <-> w+4) via LDS, exp2 domain ----
    // (loop ended with a barrier; no DMA outstanding, SB reusable)
    float* MRG = (float*)SB;               // 4 regions x 2176 f32 (34.8 KB)
    if (hf == 1) {
        float* B = MRG + wq * 2176;
        B[lane] = m_q;
        B[64 + lane] = l_q;
#pragma unroll
        for (int r = 0; r < 16; ++r) {
            B[128 + r * 64 + lane] = oacc0[r];
            B[1152 + r * 64 + lane] = oacc1[r];
        }
    }
    __syncthreads();
    if (hf == 0) {
        float* B = MRG + wq * 2176;
        float m1 = B[lane], l1 = B[64 + lane];
        float m = fmaxf(m_q, m1);
        float e0 = fexp2(m_q - m), e1 = fexp2(m1 - m);
        float linv = 1.f / (l_q * e0 + l1 * e1);
        int e0b = __builtin_bit_cast(int, e0);
        int e1b = __builtin_bit_cast(int, e1);
        int ivb = __builtin_bit_cast(int, linv);
#pragma unroll
        for (int r = 0; r < 16; ++r) {
            int qr = (r & 3) + 8 * (r >> 2) + 4 * hi;
            float s0f = __builtin_bit_cast(float, __builtin_amdgcn_ds_bpermute(4 * qr, e0b));
            float s1f = __builtin_bit_cast(float, __builtin_amdgcn_ds_bpermute(4 * qr, e1b));
            float iv = __builtin_bit_cast(float, __builtin_amdgcn_ds_bpermute(4 * qr, ivb));
            float o0 = (oacc0[r] * s0f + B[128 + r * 64 + lane] * s1f) * iv;
            float o1 = (oacc1[r] * s0f + B[1152 + r * 64 + lane] * s1f) * iv;
            int qglob = qt * 128 + wq * 32 + qr;
            size_t base = ((size_t)(n * S_LEN + qglob)) * DM + h * HD + l31;
            Oatt[base] = (_Float16)o0;
            Oatt[base + 32] = (_Float16)o1;
        }
    }
}

// ---------------------------------------------------------------------------
// Projection GEMM: 128x64 tile, BK=64, grid 512 (2 blocks/CU), LDS 48 KB
// double-buffered via gload16 (inverse-swizzled source, linear dest).
// 4 waves; wave w owns M rows [w*32, w*32+32) x all 64 N cols.
// XCD: ot = (id&7) + 8*((id>>3)&1) pins W strips per XCD.
// ---------------------------------------------------------------------------
__global__ __launch_bounds__(256) void k_proj(const _Float16* __restrict__ A,
                                              const _Float16* __restrict__ W,
                                              const float* __restrict__ bias,
                                              float* __restrict__ out) {
    __shared__ _Float16 As[2][128 * 64];   // 16 KB each
    __shared__ _Float16 Ws[2][64 * 64];    // 8 KB each

    const int id = blockIdx.x;
    const int ot = (id & 7) + 8 * ((id >> 3) & 1);   // 0..15, O strip of 64
    const int mt = id >> 4;                          // 0..31, M strip of 128
    const int tid = threadIdx.x;
    const int w = tid >> 6;
    const int lane = tid & 63;
    const int lr = lane & 15, lg = lane >> 4;
    const int wm = w * 32;

    const int rr = lane >> 3;
    const int cb = (lane & 7) * 16;
    const int gcb = cb ^ (rr << 4);

    const char* Abase = (const char*)(A + (size_t)(mt * 128) * DM);
    const char* Wbase = (const char*)(W + (size_t)(ot * 64) * DM);

    auto STAGE = [&](int kt, int b) {
#pragma unroll
        for (int r = 0; r < 4; ++r) {
            int row = r * 32 + w * 8 + rr;
            gload16(Abase + (size_t)row * 2048 + kt * 128 + gcb,
                    (char*)&As[b][0] + (r * 32 + w * 8) * 128);
        }
#pragma unroll
        for (int r = 0; r < 2; ++r) {
            int row = r * 32 + w * 8 + rr;
            gload16(Wbase + (size_t)row * 2048 + kt * 128 + gcb,
                    (char*)&Ws[b][0] + (r * 32 + w * 8) * 128);
        }
    };

    f32x4 zero = {0.f, 0.f, 0.f, 0.f};
    f32x4 acc[2][4];
#pragma unroll
    for (int mi = 0; mi < 2; ++mi)
#pragma unroll
        for (int ni = 0; ni < 4; ++ni) acc[mi][ni] = zero;

    auto COMPUTE = [&](int b) {
        const char* ldsA = (const char*)&As[b][0];
        const char* ldsW = (const char*)&Ws[b][0];
        half8 af[2][2], wf[4][2];
#pragma unroll
        for (int mi = 0; mi < 2; ++mi) {
            int row = wm + mi * 16 + lr;
            int sw = (row & 7) << 4;
            const char* p = ldsA + row * 128;
            af[mi][0] = *(const half8*)(p + ((lg * 16) ^ sw));
            af[mi][1] = *(const half8*)(p + ((64 + lg * 16) ^ sw));
        }
#pragma unroll
        for (int ni = 0; ni < 4; ++ni) {
            int row = ni * 16 + lr;
            int sw = (row & 7) << 4;
            const char* p = ldsW + row * 128;
            wf[ni][0] = *(const half8*)(p + ((lg * 16) ^ sw));
            wf[ni][1] = *(const half8*)(p + ((64 + lg * 16) ^ sw));
        }
#pragma unroll
        for (int mi = 0; mi < 2; ++mi)
#pragma unroll
            for (int ni = 0; ni < 4; ++ni) {
                acc[mi][ni] = __builtin_amdgcn_mfma_f32_16x16x32_f16(af[mi][0], wf[ni][0], acc[mi][ni], 0, 0, 0);
                acc[mi][ni] = __builtin_amdgcn_mfma_f32_16x16x32_f16(af[mi][1], wf[ni][1], acc[mi][ni], 0, 0, 0);
            }
    };

    STAGE(0, 0);
    __syncthreads();
    for (int kt = 0; kt < 15; ++kt) {
        STAGE(kt + 1, (kt & 1) ^ 1);
        COMPUTE(kt & 1);
        __syncthreads();
    }
    COMPUTE(1);   // kt=15, no stage -> no DMA outstanding at endpgm

    // epilogue: C row = m (A dim), col = o (W dim)
#pragma unroll
    for (int ni = 0; ni < 4; ++ni) {
        int o = ot * 64 + ni * 16 + lr;
        float b = bias[o];
#pragma unroll
        for (int mi = 0; mi < 2; ++mi)
#pragma unroll
            for (int i = 0; i < 4; ++i) {
                int m = mt * 128 + wm + mi * 16 + lg * 4 + i;
                out[(size_t)m * DM + o] = acc[mi][ni][i] + b;
            }
    }
}

// ---------------------------------------------------------------------------
extern "C" void kernel_launch(void* const* d_in, const int* in_sizes, int n_in,
                              void* d_out, int out_size, void* d_ws, size_t ws_size,
                              hipStream_t stream) {
    const float* Q = (const float*)d_in[0];
    const float* K = (const float*)d_in[1];
    const float* V = (const float*)d_in[2];
    const float* Wo = (const float*)d_in[3];
    const float* bo = (const float*)d_in[4];
    float* out = (float*)d_out;
    char* ws = (char*)d_ws;

    _Float16* Kh = (_Float16*)(ws);                     // 8 MB
    _Float16* Vt = (_Float16*)(ws + (8u << 20));        // 8 MB
    _Float16* Oatt = (_Float16*)(ws + (16u << 20));     // 8 MB
    _Float16* Wh = (_Float16*)(ws + (24u << 20));       // 2 MB

    k_prep<<<3584, 256, 0, stream>>>(K, V, Wo, Kh, Vt, Wh);
    k_attn<<<512, 512, 0, stream>>>(Q, Kh, Vt, Oatt);
    k_proj<<<512, 256, 0, stream>>>(Oatt, Wh, bo, out);
}

// Round 21
// 89.003 us; speedup vs baseline: 1.8430x; 1.0036x over previous
//
#include <hip/hip_runtime.h>

typedef _Float16 half8 __attribute__((ext_vector_type(8)));
typedef _Float16 half4 __attribute__((ext_vector_type(4)));
typedef float f32x4 __attribute__((ext_vector_type(4)));
typedef float f32x16 __attribute__((ext_vector_type(16)));
typedef unsigned u32x4 __attribute__((ext_vector_type(4)));

#define N_B 2
#define S_LEN 2048
#define NH 16
#define HD 64
#define DM 1024
#define LOG2E 1.44269504088896f

__device__ __forceinline__ void gload16(const void* g, void* l) {
    __builtin_amdgcn_global_load_lds(
        (const __attribute__((address_space(1))) unsigned int*)g,
        (__attribute__((address_space(3))) unsigned int*)l, 16, 0, 0);
}

__device__ __forceinline__ float fexp2(float x) {
    float r;
    asm("v_exp_f32 %0, %1" : "=v"(r) : "v"(x));
    return r;
}

// ---------------------------------------------------------------------------
// Fused prep (one launch, grid 3584): blocks [0,2048) convert K (2 float4
// per thread) -> f16 [n][h][s][d]; [2048,2560) cvt W (2 float4 per thread);
// [2560,3584) transpose V -> Vt f16 [n][h][d][s].
// ---------------------------------------------------------------------------
__global__ __launch_bounds__(256) void k_prep(const float* __restrict__ K,
                                              const float* __restrict__ V,
                                              const float* __restrict__ Wo,
                                              _Float16* __restrict__ Kh,
                                              _Float16* __restrict__ Vt,
                                              _Float16* __restrict__ Wh) {
    __shared__ _Float16 tile[64][65];
    const int id = blockIdx.x;
    if (id < 2048) {                       // ---- K regroup, 2 float4/thread
#pragma unroll
        for (int u = 0; u < 2; ++u) {
            int i = id * 512 + u * 256 + threadIdx.x;
            float4 v = ((const float4*)K)[i];
            int base = i * 4;
            int d = base & 63;
            int h = (base >> 6) & 15;
            int s = (base >> 10) & 2047;
            int n = base >> 21;
            size_t o = ((size_t)((n * NH + h) * S_LEN + s)) * HD + d;
            half4 hv = {(_Float16)v.x, (_Float16)v.y, (_Float16)v.z, (_Float16)v.w};
            *(half4*)(Kh + o) = hv;
        }
    } else if (id < 2560) {                // ---- W convert, 2 float4/thread
#pragma unroll
        for (int u = 0; u < 2; ++u) {
            int i = (id - 2048) * 512 + u * 256 + threadIdx.x;
            float4 v = ((const float4*)Wo)[i];
            half4 hv = {(_Float16)v.x, (_Float16)v.y, (_Float16)v.z, (_Float16)v.w};
            *(half4*)(Wh + (size_t)i * 4) = hv;
        }
    } else {                               // ---- V transpose (vectorized)
        int b = id - 2560;
        int st = b & 31, h = (b >> 5) & 15, n = b >> 9;
        int r0 = threadIdx.x >> 4;         // 0..15
        int c4 = (threadIdx.x & 15) * 4;   // 0,4,..,60
#pragma unroll
        for (int i = 0; i < 4; ++i) {
            int row = i * 16 + r0;
            float4 v = *(const float4*)(V + ((size_t)(n * S_LEN) + st * 64 + row) * DM + h * HD + c4);
            tile[row][c4 + 0] = (_Float16)v.x;
            tile[row][c4 + 1] = (_Float16)v.y;
            tile[row][c4 + 2] = (_Float16)v.z;
            tile[row][c4 + 3] = (_Float16)v.w;
        }
        __syncthreads();
#pragma unroll
        for (int i = 0; i < 4; ++i) {
            int d = i * 16 + r0;
            half4 hv = {tile[c4 + 0][d], tile[c4 + 1][d], tile[c4 + 2][d], tile[c4 + 3][d]};
            *(half4*)(Vt + ((size_t)((n * NH + h) * HD + d)) * S_LEN + st * 64 + c4) = hv;
        }
    }
}

// ---------------------------------------------------------------------------
// Flash attention, ONE barrier per round (R20-validated, 64.3us) + softmax
// chain cuts: (1) gate on lane-LOCAL max (cross-lane shfl only on trigger);
// (2) l_q is a per-(q,hi) PARTIAL, merged once before the epilogue (on a
// trigger, sc/m are cross-lane-uniform per q, so scaling partials is exact);
// (3) row-sum via 4 parallel accumulators (8-deep chains, not 32-deep).
// K AND V double-buffered (64 KB LDS); round t = { STAGE K/V(t+1)->buf^1;
// QK(t); softmax; PV(t); __syncthreads() }. 32x32 MFMA, in-register P
// (cvt_pkrtz + shfl mkpa), wave-level KV split, fragment-order LDS layout.
// Block = 8 waves (512 thr), QBLK=128; wave w: q-subtile (w&3), KV half
// (w>>2). defer-max THR=14. No DMA outstanding at endpgm.
// ---------------------------------------------------------------------------
__global__ __launch_bounds__(512, 4) void k_attn(const float* __restrict__ Q,
                                                 const _Float16* __restrict__ Kh,
                                                 const _Float16* __restrict__ Vth,
                                                 _Float16* __restrict__ Oatt) {
    __shared__ char SB[65536];
    // [0,32768): K dbuf (b,hf) 8KB each ; [32768,65536): V dbuf (b,hf) 8KB each

    // XCD swizzle (bijective on 512 = 8 * 64): 4 nh per XCD, 16 qt each
    const int id = blockIdx.x;
    const int xcd = id & 7;
    const int sl = id >> 3;              // 0..63
    const int nh = xcd + 8 * (sl >> 4);
    const int qt = sl & 15;              // q tile of 128

    const int tid = threadIdx.x;
    const int w = tid >> 6;              // 0..7
    const int wq = w & 3;                // q-subtile
    const int hf = w >> 2;               // KV half
    const int lane = tid & 63;
    const int l31 = lane & 31;
    const int hi = lane >> 5;
    const int n = nh >> 4, h = nh & 15;

    const size_t head = (size_t)nh * S_LEN * HD;
    const char* Khead = (const char*)(Kh + head);
    const char* Vhead = (const char*)(Vth + head);

    // ---- Q fragments (B-frag: col q=l31, k=8hi+j per 16-d chunk), LOG2E-scaled
    const int qg = qt * 128 + wq * 32 + l31;
    const float* qbase = Q + ((size_t)(n * S_LEN) + qg) * DM + h * HD;
    auto mkqf = [&](int c) -> half8 {
        float4 a = *(const float4*)(qbase + 16 * c + 8 * hi);
        float4 b = *(const float4*)(qbase + 16 * c + 8 * hi + 4);
        half8 r = {(_Float16)(a.x * LOG2E), (_Float16)(a.y * LOG2E),
                   (_Float16)(a.z * LOG2E), (_Float16)(a.w * LOG2E),
                   (_Float16)(b.x * LOG2E), (_Float16)(b.y * LOG2E),
                   (_Float16)(b.z * LOG2E), (_Float16)(b.w * LOG2E)};
        return r;
    };
    half8 qf0 = mkqf(0), qf1 = mkqf(1), qf2 = mkqf(2), qf3 = mkqf(3);

    f32x16 oacc0 = {}, oacc1 = {};
    float m_q = -1e30f, l_q = 0.f;       // m uniform per q; l per-(q,hi) PARTIAL

    auto kbuf = [&](int b, int half) -> char* { return SB + (b * 2 + half) * 8192; };
    auto vbuf = [&](int b, int half) -> char* { return SB + 32768 + (b * 2 + half) * 8192; };

    // staging: wave stages slices wq*2+j; per lane, decode the fragment-order
    // index and fetch the matching element from global.
    auto STAGE_K = [&](int t, int b) {
#pragma unroll
        for (int j = 0; j < 2; ++j) {
            int slice = wq * 2 + j;            // 0..7
            int idx = slice * 64 + lane;       // 0..511
            int bhi = idx & 1;
            int bl31 = (idx >> 1) & 31;
            int bc = (idx >> 6) & 3;
            int bblk = idx >> 8;
            int key = hf * 1024 + t * 64 + bblk * 32 + bl31;
            gload16(Khead + (size_t)key * 128 + bc * 32 + bhi * 16,
                    kbuf(b, hf) + slice * 1024);
        }
    };
    auto STAGE_V = [&](int t, int b) {
#pragma unroll
        for (int j = 0; j < 2; ++j) {
            int slice = wq * 2 + j;
            int idx = slice * 64 + lane;
            int bhi = idx & 1;
            int bl31 = (idx >> 1) & 31;
            int bc = (idx >> 6) & 3;
            int bblk = idx >> 8;
            int drow = bblk * 32 + bl31;
            gload16(Vhead + (size_t)drow * 4096 + hf * 2048 + t * 128 + bc * 32 + bhi * 16,
                    vbuf(b, hf) + slice * 1024);
        }
    };

    // fragment read: contiguous 1KB per (blk,c) -- conflict-free
    auto ldF = [&](const char* lds, int blk, int c) -> half8 {
        int off = (((blk * 4 + c) * 32 + l31) * 2 + hi) * 16;
        return *(const half8*)(lds + off);
    };

    auto pkrtz = [&](float a, float b) -> unsigned {
        return __builtin_bit_cast(unsigned, __builtin_amdgcn_cvt_pkrtz(a, b));
    };
    auto mkpa = [&](const f32x16& S, int rb) -> half8 {
        unsigned w0 = pkrtz(S[rb + 0], S[rb + 1]);
        unsigned w1 = pkrtz(S[rb + 2], S[rb + 3]);
        unsigned w2 = pkrtz(S[rb + 4], S[rb + 5]);
        unsigned w3 = pkrtz(S[rb + 6], S[rb + 7]);
        unsigned x0 = (unsigned)__shfl_xor((int)w0, 32);
        unsigned x1 = (unsigned)__shfl_xor((int)w1, 32);
        unsigned x2 = (unsigned)__shfl_xor((int)w2, 32);
        unsigned x3 = (unsigned)__shfl_xor((int)w3, 32);
        u32x4 t;
        t[0] = hi ? x2 : w0;
        t[1] = hi ? x3 : w1;
        t[2] = hi ? w2 : x0;
        t[3] = hi ? w3 : x1;
        return __builtin_bit_cast(half8, t);
    };

    STAGE_K(0, 0);
    STAGE_V(0, 0);
    __syncthreads();                       // K(0), V(0) resident

    for (int t = 0; t < 16; ++t) {
        const int buf = t & 1;
        if (t < 15) {                      // prefetch next round into buf^1
            STAGE_K(t + 1, buf ^ 1);
            STAGE_V(t + 1, buf ^ 1);
        }
        const char* ldsK = kbuf(buf, hf);
        const char* ldsV = vbuf(buf, hf);

        // ---- S^T = K Q^T : two 32-key blocks, d chained over 4 chunks
        f32x16 s0 = {}, s1 = {};
        __builtin_amdgcn_s_setprio(1);
        s0 = __builtin_amdgcn_mfma_f32_32x32x16_f16(ldF(ldsK, 0, 0), qf0, s0, 0, 0, 0);
        s0 = __builtin_amdgcn_mfma_f32_32x32x16_f16(ldF(ldsK, 0, 1), qf1, s0, 0, 0, 0);
        s0 = __builtin_amdgcn_mfma_f32_32x32x16_f16(ldF(ldsK, 0, 2), qf2, s0, 0, 0, 0);
        s0 = __builtin_amdgcn_mfma_f32_32x32x16_f16(ldF(ldsK, 0, 3), qf3, s0, 0, 0, 0);
        s1 = __builtin_amdgcn_mfma_f32_32x32x16_f16(ldF(ldsK, 1, 0), qf0, s1, 0, 0, 0);
        s1 = __builtin_amdgcn_mfma_f32_32x32x16_f16(ldF(ldsK, 1, 1), qf1, s1, 0, 0, 0);
        s1 = __builtin_amdgcn_mfma_f32_32x32x16_f16(ldF(ldsK, 1, 2), qf2, s1, 0, 0, 0);
        s1 = __builtin_amdgcn_mfma_f32_32x32x16_f16(ldF(ldsK, 1, 3), qf3, s1, 0, 0, 0);
        __builtin_amdgcn_s_setprio(0);

        // ---- lane-LOCAL max gate; cross-lane only on trigger (defer THR=14)
        float a0 = fmaxf(fmaxf(s0[0], s0[1]), fmaxf(s0[2], s0[3]));
        float a1 = fmaxf(fmaxf(s0[4], s0[5]), fmaxf(s0[6], s0[7]));
        float a2 = fmaxf(fmaxf(s0[8], s0[9]), fmaxf(s0[10], s0[11]));
        float a3 = fmaxf(fmaxf(s0[12], s0[13]), fmaxf(s0[14], s0[15]));
        float b0 = fmaxf(fmaxf(s1[0], s1[1]), fmaxf(s1[2], s1[3]));
        float b1 = fmaxf(fmaxf(s1[4], s1[5]), fmaxf(s1[6], s1[7]));
        float b2 = fmaxf(fmaxf(s1[8], s1[9]), fmaxf(s1[10], s1[11]));
        float b3 = fmaxf(fmaxf(s1[12], s1[13]), fmaxf(s1[14], s1[15]));
        float lmax = fmaxf(fmaxf(fmaxf(a0, a1), fmaxf(a2, a3)),
                           fmaxf(fmaxf(b0, b1), fmaxf(b2, b3)));
        if (!__all(lmax <= m_q + 14.f)) {
            float tm = fmaxf(lmax, __shfl_xor(lmax, 32));   // uniform per q
            float mn = fmaxf(m_q, tm);
            float sc = fexp2(m_q - mn);                     // uniform across hi
            m_q = mn;
            l_q *= sc;                                      // partial scales exactly
            int scb = __builtin_bit_cast(int, sc);
#pragma unroll
            for (int r = 0; r < 16; ++r) {
                int qr = (r & 3) + 8 * (r >> 2) + 4 * hi;
                float s = __builtin_bit_cast(float, __builtin_amdgcn_ds_bpermute(4 * qr, scb));
                oacc0[r] *= s;
                oacc1[r] *= s;
            }
        }
        // ---- exp + row-sum: 4 parallel accumulators, no cross-lane ----
        float r0 = 0.f, r1 = 0.f, r2 = 0.f, r3 = 0.f;
#pragma unroll
        for (int i = 0; i < 16; i += 4) {
            float p0 = fexp2(s0[i + 0] - m_q); s0[i + 0] = p0; r0 += p0;
            float p1 = fexp2(s0[i + 1] - m_q); s0[i + 1] = p1; r1 += p1;
            float p2 = fexp2(s0[i + 2] - m_q); s0[i + 2] = p2; r2 += p2;
            float p3 = fexp2(s0[i + 3] - m_q); s0[i + 3] = p3; r3 += p3;
        }
#pragma unroll
        for (int i = 0; i < 16; i += 4) {
            float p0 = fexp2(s1[i + 0] - m_q); s1[i + 0] = p0; r0 += p0;
            float p1 = fexp2(s1[i + 1] - m_q); s1[i + 1] = p1; r1 += p1;
            float p2 = fexp2(s1[i + 2] - m_q); s1[i + 2] = p2; r2 += p2;
            float p3 = fexp2(s1[i + 3] - m_q); s1[i + 3] = p3; r3 += p3;
        }
        l_q += (r0 + r1) + (r2 + r3);    // per-(q,hi) partial

        // ---- P -> A-fragments (in-register)
        half8 pa0 = mkpa(s0, 0), pa1 = mkpa(s0, 8);
        half8 pa2 = mkpa(s1, 0), pa3 = mkpa(s1, 8);

        // ---- O += P V  (V(t) resident since last round's barrier)
        __builtin_amdgcn_s_setprio(1);
        oacc0 = __builtin_amdgcn_mfma_f32_32x32x16_f16(pa0, ldF(ldsV, 0, 0), oacc0, 0, 0, 0);
        oacc0 = __builtin_amdgcn_mfma_f32_32x32x16_f16(pa1, ldF(ldsV, 0, 1), oacc0, 0, 0, 0);
        oacc0 = __builtin_amdgcn_mfma_f32_32x32x16_f16(pa2, ldF(ldsV, 0, 2), oacc0, 0, 0, 0);
        oacc0 = __builtin_amdgcn_mfma_f32_32x32x16_f16(pa3, ldF(ldsV, 0, 3), oacc0, 0, 0, 0);
        oacc1 = __builtin_amdgcn_mfma_f32_32x32x16_f16(pa0, ldF(ldsV, 1, 0), oacc1, 0, 0, 0);
        oacc1 = __builtin_amdgcn_mfma_f32_32x32x16_f16(pa1, ldF(ldsV, 1, 1), oacc1, 0, 0, 0);
        oacc1 = __builtin_amdgcn_mfma_f32_32x32x16_f16(pa2, ldF(ldsV, 1, 2), oacc1, 0, 0, 0);
        oacc1 = __builtin_amdgcn_mfma_f32_32x32x16_f16(pa3, ldF(ldsV, 1, 3), oacc1, 0, 0, 0);
        __builtin_amdgcn_s_setprio(0);

        __syncthreads();   // single per-round barrier: drains stage DMA + orders buf reuse
    }

    // ---- combine hi-half l partials (once) ----
    l_q += __shfl_xor(l_q, 32);

    // ---- merge wave pairs (w <-> w+4) via LDS, exp2 domain ----
    // (loop ended with a barrier; no DMA outstanding, SB reusable)
    float* MRG = (float*)SB;               // 4 regions x 2176 f32 (34.8 KB)
    if (hf == 1) {
        float* B = MRG + wq * 2176;
        B[lane] = m_q;
        B[64 + lane] = l_q;
#pragma unroll
        for (int r = 0; r < 16; ++r) {
            B[128 + r * 64 + lane] = oacc0[r];
            B[1152 + r * 64 + lane] = oacc1[r];
        }
    }
    __syncthreads();
    if (hf == 0) {
        float* B = MRG + wq * 2176;
        float m1 = B[lane], l1 = B[64 + lane];
        float m = fmaxf(m_q, m1);
        float e0 = fexp2(m_q - m), e1 = fexp2(m1 - m);
        float linv = 1.f / (l_q * e0 + l1 * e1);
        int e0b = __builtin_bit_cast(int, e0);
        int e1b = __builtin_bit_cast(int, e1);
        int ivb = __builtin_bit_cast(int, linv);
#pragma unroll
        for (int r = 0; r < 16; ++r) {
            int qr = (r & 3) + 8 * (r >> 2) + 4 * hi;
            float s0f = __builtin_bit_cast(float, __builtin_amdgcn_ds_bpermute(4 * qr, e0b));
            float s1f = __builtin_bit_cast(float, __builtin_amdgcn_ds_bpermute(4 * qr, e1b));
            float iv = __builtin_bit_cast(float, __builtin_amdgcn_ds_bpermute(4 * qr, ivb));
            float o0 = (oacc0[r] * s0f + B[128 + r * 64 + lane] * s1f) * iv;
            float o1 = (oacc1[r] * s0f + B[1152 + r * 64 + lane] * s1f) * iv;
            int qglob = qt * 128 + wq * 32 + qr;
            size_t base = ((size_t)(n * S_LEN + qglob)) * DM + h * HD + l31;
            Oatt[base] = (_Float16)o0;
            Oatt[base + 32] = (_Float16)o1;
        }
    }
}

// ---------------------------------------------------------------------------
// Projection GEMM: 128x64 tile, BK=64, grid 512 (2 blocks/CU), LDS 48 KB
// double-buffered via gload16 (inverse-swizzled source, linear dest).
// 4 waves; wave w owns M rows [w*32, w*32+32) x all 64 N cols.
// XCD: ot = (id&7) + 8*((id>>3)&1) pins W strips per XCD.
// ---------------------------------------------------------------------------
__global__ __launch_bounds__(256) void k_proj(const _Float16* __restrict__ A,
                                              const _Float16* __restrict__ W,
                                              const float* __restrict__ bias,
                                              float* __restrict__ out) {
    __shared__ _Float16 As[2][128 * 64];   // 16 KB each
    __shared__ _Float16 Ws[2][64 * 64];    // 8 KB each

    const int id = blockIdx.x;
    const int ot = (id & 7) + 8 * ((id >> 3) & 1);   // 0..15, O strip of 64
    const int mt = id >> 4;                          // 0..31, M strip of 128
    const int tid = threadIdx.x;
    const int w = tid >> 6;
    const int lane = tid & 63;
    const int lr = lane & 15, lg = lane >> 4;
    const int wm = w * 32;

    const int rr = lane >> 3;
    const int cb = (lane & 7) * 16;
    const int gcb = cb ^ (rr << 4);

    const char* Abase = (const char*)(A + (size_t)(mt * 128) * DM);
    const char* Wbase = (const char*)(W + (size_t)(ot * 64) * DM);

    auto STAGE = [&](int kt, int b) {
#pragma unroll
        for (int r = 0; r < 4; ++r) {
            int row = r * 32 + w * 8 + rr;
            gload16(Abase + (size_t)row * 2048 + kt * 128 + gcb,
                    (char*)&As[b][0] + (r * 32 + w * 8) * 128);
        }
#pragma unroll
        for (int r = 0; r < 2; ++r) {
            int row = r * 32 + w * 8 + rr;
            gload16(Wbase + (size_t)row * 2048 + kt * 128 + gcb,
                    (char*)&Ws[b][0] + (r * 32 + w * 8) * 128);
        }
    };

    f32x4 zero = {0.f, 0.f, 0.f, 0.f};
    f32x4 acc[2][4];
#pragma unroll
    for (int mi = 0; mi < 2; ++mi)
#pragma unroll
        for (int ni = 0; ni < 4; ++ni) acc[mi][ni] = zero;

    auto COMPUTE = [&](int b) {
        const char* ldsA = (const char*)&As[b][0];
        const char* ldsW = (const char*)&Ws[b][0];
        half8 af[2][2], wf[4][2];
#pragma unroll
        for (int mi = 0; mi < 2; ++mi) {
            int row = wm + mi * 16 + lr;
            int sw = (row & 7) << 4;
            const char* p = ldsA + row * 128;
            af[mi][0] = *(const half8*)(p + ((lg * 16) ^ sw));
            af[mi][1] = *(const half8*)(p + ((64 + lg * 16) ^ sw));
        }
#pragma unroll
        for (int ni = 0; ni < 4; ++ni) {
            int row = ni * 16 + lr;
            int sw = (row & 7) << 4;
            const char* p = ldsW + row * 128;
            wf[ni][0] = *(const half8*)(p + ((lg * 16) ^ sw));
            wf[ni][1] = *(const half8*)(p + ((64 + lg * 16) ^ sw));
        }
#pragma unroll
        for (int mi = 0; mi < 2; ++mi)
#pragma unroll
            for (int ni = 0; ni < 4; ++ni) {
                acc[mi][ni] = __builtin_amdgcn_mfma_f32_16x16x32_f16(af[mi][0], wf[ni][0], acc[mi][ni], 0, 0, 0);
                acc[mi][ni] = __builtin_amdgcn_mfma_f32_16x16x32_f16(af[mi][1], wf[ni][1], acc[mi][ni], 0, 0, 0);
            }
    };

    STAGE(0, 0);
    __syncthreads();
    for (int kt = 0; kt < 15; ++kt) {
        STAGE(kt + 1, (kt & 1) ^ 1);
        COMPUTE(kt & 1);
        __syncthreads();
    }
    COMPUTE(1);   // kt=15, no stage -> no DMA outstanding at endpgm

    // epilogue: C row = m (A dim), col = o (W dim)
#pragma unroll
    for (int ni = 0; ni < 4; ++ni) {
        int o = ot * 64 + ni * 16 + lr;
        float b = bias[o];
#pragma unroll
        for (int mi = 0; mi < 2; ++mi)
#pragma unroll
            for (int i = 0; i < 4; ++i) {
                int m = mt * 128 + wm + mi * 16 + lg * 4 + i;
                out[(size_t)m * DM + o] = acc[mi][ni][i] + b;
            }
    }
}

// ---------------------------------------------------------------------------
extern "C" void kernel_launch(void* const* d_in, const int* in_sizes, int n_in,
                              void* d_out, int out_size, void* d_ws, size_t ws_size,
                              hipStream_t stream) {
    const float* Q = (const float*)d_in[0];
    const float* K = (const float*)d_in[1];
    const float* V = (const float*)d_in[2];
    const float* Wo = (const float*)d_in[3];
    const float* bo = (const float*)d_in[4];
    float* out = (float*)d_out;
    char* ws = (char*)d_ws;

    _Float16* Kh = (_Float16*)(ws);                     // 8 MB
    _Float16* Vt = (_Float16*)(ws + (8u << 20));        // 8 MB
    _Float16* Oatt = (_Float16*)(ws + (16u << 20));     // 8 MB
    _Float16* Wh = (_Float16*)(ws + (24u << 20));       // 2 MB

    k_prep<<<3584, 256, 0, stream>>>(K, V, Wo, Kh, Vt, Wh);
    k_attn<<<512, 512, 0, stream>>>(Q, Kh, Vt, Oatt);
    k_proj<<<512, 256, 0, stream>>>(Oatt, Wh, bo, out);
}

// Round 22
// 84.757 us; speedup vs baseline: 1.9353x; 1.0501x over previous
//
#include <hip/hip_runtime.h>

typedef _Float16 half8 __attribute__((ext_vector_type(8)));
typedef _Float16 half4 __attribute__((ext_vector_type(4)));
typedef float f32x4 __attribute__((ext_vector_type(4)));
typedef float f32x16 __attribute__((ext_vector_type(16)));
typedef unsigned u32x4 __attribute__((ext_vector_type(4)));

#define N_B 2
#define S_LEN 2048
#define NH 16
#define HD 64
#define DM 1024
#define LOG2E 1.44269504088896f

__device__ __forceinline__ void gload16(const void* g, void* l) {
    __builtin_amdgcn_global_load_lds(
        (const __attribute__((address_space(1))) unsigned int*)g,
        (__attribute__((address_space(3))) unsigned int*)l, 16, 0, 0);
}

__device__ __forceinline__ float fexp2(float x) {
    float r;
    asm("v_exp_f32 %0, %1" : "=v"(r) : "v"(x));
    return r;
}

// ---------------------------------------------------------------------------
// Fused prep (one launch, grid 3584): blocks [0,2048) convert K (2 float4
// per thread) -> f16 [n][h][s][d]; [2048,2560) cvt W (2 float4 per thread);
// [2560,3584) transpose V -> Vt f16 [n][h][d][s'], with the key index
// PERMUTED within each 16-key block (quadruples {4-7} <-> {8-11} swapped).
// With that order, each 16B staging granule in k_attn delivers the
// P-natural key set for its hi, so the P->A-frag pack needs NO cross-lane
// exchange (PV's key-sum is permutation invariant).
// ---------------------------------------------------------------------------
__global__ __launch_bounds__(256) void k_prep(const float* __restrict__ K,
                                              const float* __restrict__ V,
                                              const float* __restrict__ Wo,
                                              _Float16* __restrict__ Kh,
                                              _Float16* __restrict__ Vt,
                                              _Float16* __restrict__ Wh) {
    __shared__ _Float16 tile[64][65];
    const int id = blockIdx.x;
    if (id < 2048) {                       // ---- K regroup, 2 float4/thread
#pragma unroll
        for (int u = 0; u < 2; ++u) {
            int i = id * 512 + u * 256 + threadIdx.x;
            float4 v = ((const float4*)K)[i];
            int base = i * 4;
            int d = base & 63;
            int h = (base >> 6) & 15;
            int s = (base >> 10) & 2047;
            int n = base >> 21;
            size_t o = ((size_t)((n * NH + h) * S_LEN + s)) * HD + d;
            half4 hv = {(_Float16)v.x, (_Float16)v.y, (_Float16)v.z, (_Float16)v.w};
            *(half4*)(Kh + o) = hv;
        }
    } else if (id < 2560) {                // ---- W convert, 2 float4/thread
#pragma unroll
        for (int u = 0; u < 2; ++u) {
            int i = (id - 2048) * 512 + u * 256 + threadIdx.x;
            float4 v = ((const float4*)Wo)[i];
            half4 hv = {(_Float16)v.x, (_Float16)v.y, (_Float16)v.z, (_Float16)v.w};
            *(half4*)(Wh + (size_t)i * 4) = hv;
        }
    } else {                               // ---- V transpose (vectorized)
        int b = id - 2560;
        int st = b & 31, h = (b >> 5) & 15, n = b >> 9;
        int r0 = threadIdx.x >> 4;         // 0..15
        int c4 = (threadIdx.x & 15) * 4;   // 0,4,..,60 (source key base)
        // permuted destination: swap quadruples {4-7}<->{8-11} in each 16
        int pc4 = (c4 & ~12) | ((c4 & 4) << 1) | ((c4 & 8) >> 1);
#pragma unroll
        for (int i = 0; i < 4; ++i) {
            int row = i * 16 + r0;
            float4 v = *(const float4*)(V + ((size_t)(n * S_LEN) + st * 64 + row) * DM + h * HD + c4);
            tile[row][c4 + 0] = (_Float16)v.x;
            tile[row][c4 + 1] = (_Float16)v.y;
            tile[row][c4 + 2] = (_Float16)v.z;
            tile[row][c4 + 3] = (_Float16)v.w;
        }
        __syncthreads();
#pragma unroll
        for (int i = 0; i < 4; ++i) {
            int d = i * 16 + r0;
            half4 hv = {tile[c4 + 0][d], tile[c4 + 1][d], tile[c4 + 2][d], tile[c4 + 3][d]};
            *(half4*)(Vt + ((size_t)((n * NH + h) * HD + d)) * S_LEN + st * 64 + pc4) = hv;
        }
    }
}

// ---------------------------------------------------------------------------
// Flash attention, ONE barrier per round (R20-validated) + shfl-free P pack:
// Vt's prep-side key permutation makes slot (hi,j)'s key equal register j of
// s0/s1, so mkpa is 4x cvt_pkrtz (no ds_swizzle, no cndmask). K AND V
// double-buffered (64 KB LDS); round t = { STAGE K/V(t+1)->buf^1; QK(t);
// softmax; PV(t); __syncthreads() }. 32x32 MFMA, wave-level KV split,
// fragment-order LDS layout (conflict-free b128 reads). Block = 8 waves
// (512 thr), QBLK=128; wave w: q-subtile (w&3), KV half (w>>2). defer-max
// THR=14, lane-local gate, partial l. No DMA outstanding at endpgm.
// ---------------------------------------------------------------------------
__global__ __launch_bounds__(512, 4) void k_attn(const float* __restrict__ Q,
                                                 const _Float16* __restrict__ Kh,
                                                 const _Float16* __restrict__ Vth,
                                                 _Float16* __restrict__ Oatt) {
    __shared__ char SB[65536];
    // [0,32768): K dbuf (b,hf) 8KB each ; [32768,65536): V dbuf (b,hf) 8KB each

    // XCD swizzle (bijective on 512 = 8 * 64): 4 nh per XCD, 16 qt each
    const int id = blockIdx.x;
    const int xcd = id & 7;
    const int sl = id >> 3;              // 0..63
    const int nh = xcd + 8 * (sl >> 4);
    const int qt = sl & 15;              // q tile of 128

    const int tid = threadIdx.x;
    const int w = tid >> 6;              // 0..7
    const int wq = w & 3;                // q-subtile
    const int hf = w >> 2;               // KV half
    const int lane = tid & 63;
    const int l31 = lane & 31;
    const int hi = lane >> 5;
    const int n = nh >> 4, h = nh & 15;

    const size_t head = (size_t)nh * S_LEN * HD;
    const char* Khead = (const char*)(Kh + head);
    const char* Vhead = (const char*)(Vth + head);

    // ---- Q fragments (B-frag: col q=l31, k=8hi+j per 16-d chunk), LOG2E-scaled
    const int qg = qt * 128 + wq * 32 + l31;
    const float* qbase = Q + ((size_t)(n * S_LEN) + qg) * DM + h * HD;
    auto mkqf = [&](int c) -> half8 {
        float4 a = *(const float4*)(qbase + 16 * c + 8 * hi);
        float4 b = *(const float4*)(qbase + 16 * c + 8 * hi + 4);
        half8 r = {(_Float16)(a.x * LOG2E), (_Float16)(a.y * LOG2E),
                   (_Float16)(a.z * LOG2E), (_Float16)(a.w * LOG2E),
                   (_Float16)(b.x * LOG2E), (_Float16)(b.y * LOG2E),
                   (_Float16)(b.z * LOG2E), (_Float16)(b.w * LOG2E)};
        return r;
    };
    half8 qf0 = mkqf(0), qf1 = mkqf(1), qf2 = mkqf(2), qf3 = mkqf(3);

    f32x16 oacc0 = {}, oacc1 = {};
    float m_q = -1e30f, l_q = 0.f;       // m uniform per q; l per-(q,hi) PARTIAL

    auto kbuf = [&](int b, int half) -> char* { return SB + (b * 2 + half) * 8192; };
    auto vbuf = [&](int b, int half) -> char* { return SB + 32768 + (b * 2 + half) * 8192; };

    // staging: wave stages slices wq*2+j; per lane, decode the fragment-order
    // index and fetch the matching element from global.
    auto STAGE_K = [&](int t, int b) {
#pragma unroll
        for (int j = 0; j < 2; ++j) {
            int slice = wq * 2 + j;            // 0..7
            int idx = slice * 64 + lane;       // 0..511
            int bhi = idx & 1;
            int bl31 = (idx >> 1) & 31;
            int bc = (idx >> 6) & 3;
            int bblk = idx >> 8;
            int key = hf * 1024 + t * 64 + bblk * 32 + bl31;
            gload16(Khead + (size_t)key * 128 + bc * 32 + bhi * 16,
                    kbuf(b, hf) + slice * 1024);
        }
    };
    auto STAGE_V = [&](int t, int b) {
#pragma unroll
        for (int j = 0; j < 2; ++j) {
            int slice = wq * 2 + j;
            int idx = slice * 64 + lane;
            int bhi = idx & 1;
            int bl31 = (idx >> 1) & 31;
            int bc = (idx >> 6) & 3;
            int bblk = idx >> 8;
            int drow = bblk * 32 + bl31;
            gload16(Vhead + (size_t)drow * 4096 + hf * 2048 + t * 128 + bc * 32 + bhi * 16,
                    vbuf(b, hf) + slice * 1024);
        }
    };

    // fragment read: contiguous 1KB per (blk,c) -- conflict-free
    auto ldF = [&](const char* lds, int blk, int c) -> half8 {
        int off = (((blk * 4 + c) * 32 + l31) * 2 + hi) * 16;
        return *(const half8*)(lds + off);
    };

    auto pkrtz = [&](float a, float b) -> unsigned {
        return __builtin_bit_cast(unsigned, __builtin_amdgcn_cvt_pkrtz(a, b));
    };
    // P -> A-frag: with the prep-side Vt key permutation, slot (hi,j)'s key
    // equals C-layout register j -- straight packed converts, no cross-lane.
    auto mkpa = [&](const f32x16& S, int rb) -> half8 {
        u32x4 t;
        t[0] = pkrtz(S[rb + 0], S[rb + 1]);
        t[1] = pkrtz(S[rb + 2], S[rb + 3]);
        t[2] = pkrtz(S[rb + 4], S[rb + 5]);
        t[3] = pkrtz(S[rb + 6], S[rb + 7]);
        return __builtin_bit_cast(half8, t);
    };

    STAGE_K(0, 0);
    STAGE_V(0, 0);
    __syncthreads();                       // K(0), V(0) resident

    for (int t = 0; t < 16; ++t) {
        const int buf = t & 1;
        if (t < 15) {                      // prefetch next round into buf^1
            STAGE_K(t + 1, buf ^ 1);
            STAGE_V(t + 1, buf ^ 1);
        }
        const char* ldsK = kbuf(buf, hf);
        const char* ldsV = vbuf(buf, hf);

        // ---- S^T = K Q^T : two 32-key blocks, d chained over 4 chunks
        f32x16 s0 = {}, s1 = {};
        __builtin_amdgcn_s_setprio(1);
        s0 = __builtin_amdgcn_mfma_f32_32x32x16_f16(ldF(ldsK, 0, 0), qf0, s0, 0, 0, 0);
        s0 = __builtin_amdgcn_mfma_f32_32x32x16_f16(ldF(ldsK, 0, 1), qf1, s0, 0, 0, 0);
        s0 = __builtin_amdgcn_mfma_f32_32x32x16_f16(ldF(ldsK, 0, 2), qf2, s0, 0, 0, 0);
        s0 = __builtin_amdgcn_mfma_f32_32x32x16_f16(ldF(ldsK, 0, 3), qf3, s0, 0, 0, 0);
        s1 = __builtin_amdgcn_mfma_f32_32x32x16_f16(ldF(ldsK, 1, 0), qf0, s1, 0, 0, 0);
        s1 = __builtin_amdgcn_mfma_f32_32x32x16_f16(ldF(ldsK, 1, 1), qf1, s1, 0, 0, 0);
        s1 = __builtin_amdgcn_mfma_f32_32x32x16_f16(ldF(ldsK, 1, 2), qf2, s1, 0, 0, 0);
        s1 = __builtin_amdgcn_mfma_f32_32x32x16_f16(ldF(ldsK, 1, 3), qf3, s1, 0, 0, 0);
        __builtin_amdgcn_s_setprio(0);

        // ---- lane-LOCAL max gate; cross-lane only on trigger (defer THR=14)
        float a0 = fmaxf(fmaxf(s0[0], s0[1]), fmaxf(s0[2], s0[3]));
        float a1 = fmaxf(fmaxf(s0[4], s0[5]), fmaxf(s0[6], s0[7]));
        float a2 = fmaxf(fmaxf(s0[8], s0[9]), fmaxf(s0[10], s0[11]));
        float a3 = fmaxf(fmaxf(s0[12], s0[13]), fmaxf(s0[14], s0[15]));
        float b0 = fmaxf(fmaxf(s1[0], s1[1]), fmaxf(s1[2], s1[3]));
        float b1 = fmaxf(fmaxf(s1[4], s1[5]), fmaxf(s1[6], s1[7]));
        float b2 = fmaxf(fmaxf(s1[8], s1[9]), fmaxf(s1[10], s1[11]));
        float b3 = fmaxf(fmaxf(s1[12], s1[13]), fmaxf(s1[14], s1[15]));
        float lmax = fmaxf(fmaxf(fmaxf(a0, a1), fmaxf(a2, a3)),
                           fmaxf(fmaxf(b0, b1), fmaxf(b2, b3)));
        if (!__all(lmax <= m_q + 14.f)) {
            float tm = fmaxf(lmax, __shfl_xor(lmax, 32));   // uniform per q
            float mn = fmaxf(m_q, tm);
            float sc = fexp2(m_q - mn);                     // uniform across hi
            m_q = mn;
            l_q *= sc;                                      // partial scales exactly
            int scb = __builtin_bit_cast(int, sc);
#pragma unroll
            for (int r = 0; r < 16; ++r) {
                int qr = (r & 3) + 8 * (r >> 2) + 4 * hi;
                float s = __builtin_bit_cast(float, __builtin_amdgcn_ds_bpermute(4 * qr, scb));
                oacc0[r] *= s;
                oacc1[r] *= s;
            }
        }
        // ---- exp + row-sum: 4 parallel accumulators, no cross-lane ----
        float r0 = 0.f, r1 = 0.f, r2 = 0.f, r3 = 0.f;
#pragma unroll
        for (int i = 0; i < 16; i += 4) {
            float p0 = fexp2(s0[i + 0] - m_q); s0[i + 0] = p0; r0 += p0;
            float p1 = fexp2(s0[i + 1] - m_q); s0[i + 1] = p1; r1 += p1;
            float p2 = fexp2(s0[i + 2] - m_q); s0[i + 2] = p2; r2 += p2;
            float p3 = fexp2(s0[i + 3] - m_q); s0[i + 3] = p3; r3 += p3;
        }
#pragma unroll
        for (int i = 0; i < 16; i += 4) {
            float p0 = fexp2(s1[i + 0] - m_q); s1[i + 0] = p0; r0 += p0;
            float p1 = fexp2(s1[i + 1] - m_q); s1[i + 1] = p1; r1 += p1;
            float p2 = fexp2(s1[i + 2] - m_q); s1[i + 2] = p2; r2 += p2;
            float p3 = fexp2(s1[i + 3] - m_q); s1[i + 3] = p3; r3 += p3;
        }
        l_q += (r0 + r1) + (r2 + r3);    // per-(q,hi) partial

        // ---- P -> A-fragments (pure pkrtz, no shfl)
        half8 pa0 = mkpa(s0, 0), pa1 = mkpa(s0, 8);
        half8 pa2 = mkpa(s1, 0), pa3 = mkpa(s1, 8);

        // ---- O += P V  (V(t) resident since last round's barrier)
        __builtin_amdgcn_s_setprio(1);
        oacc0 = __builtin_amdgcn_mfma_f32_32x32x16_f16(pa0, ldF(ldsV, 0, 0), oacc0, 0, 0, 0);
        oacc0 = __builtin_amdgcn_mfma_f32_32x32x16_f16(pa1, ldF(ldsV, 0, 1), oacc0, 0, 0, 0);
        oacc0 = __builtin_amdgcn_mfma_f32_32x32x16_f16(pa2, ldF(ldsV, 0, 2), oacc0, 0, 0, 0);
        oacc0 = __builtin_amdgcn_mfma_f32_32x32x16_f16(pa3, ldF(ldsV, 0, 3), oacc0, 0, 0, 0);
        oacc1 = __builtin_amdgcn_mfma_f32_32x32x16_f16(pa0, ldF(ldsV, 1, 0), oacc1, 0, 0, 0);
        oacc1 = __builtin_amdgcn_mfma_f32_32x32x16_f16(pa1, ldF(ldsV, 1, 1), oacc1, 0, 0, 0);
        oacc1 = __builtin_amdgcn_mfma_f32_32x32x16_f16(pa2, ldF(ldsV, 1, 2), oacc1, 0, 0, 0);
        oacc1 = __builtin_amdgcn_mfma_f32_32x32x16_f16(pa3, ldF(ldsV, 1, 3), oacc1, 0, 0, 0);
        __builtin_amdgcn_s_setprio(0);

        __syncthreads();   // single per-round barrier: drains stage DMA + orders buf reuse
    }

    // ---- combine hi-half l partials (once) ----
    l_q += __shfl_xor(l_q, 32);

    // ---- merge wave pairs (w <-> w+4) via LDS, exp2 domain ----
    // (loop ended with a barrier; no DMA outstanding, SB reusable)
    float* MRG = (float*)SB;               // 4 regions x 2176 f32 (34.8 KB)
    if (hf == 1) {
        float* B = MRG + wq * 2176;
        B[lane] = m_q;
        B[64 + lane] = l_q;
#pragma unroll
        for (int r = 0; r < 16; ++r) {
            B[128 + r * 64 + lane] = oacc0[r];
            B[1152 + r * 64 + lane] = oacc1[r];
        }
    }
    __syncthreads();
    if (hf == 0) {
        float* B = MRG + wq * 2176;
        float m1 = B[lane], l1 = B[64 + lane];
        float m = fmaxf(m_q, m1);
        float e0 = fexp2(m_q - m), e1 = fexp2(m1 - m);
        float linv = 1.f / (l_q * e0 + l1 * e1);
        int e0b = __builtin_bit_cast(int, e0);
        int e1b = __builtin_bit_cast(int, e1);
        int ivb = __builtin_bit_cast(int, linv);
#pragma unroll
        for (int r = 0; r < 16; ++r) {
            int qr = (r & 3) + 8 * (r >> 2) + 4 * hi;
            float s0f = __builtin_bit_cast(float, __builtin_amdgcn_ds_bpermute(4 * qr, e0b));
            float s1f = __builtin_bit_cast(float, __builtin_amdgcn_ds_bpermute(4 * qr, e1b));
            float iv = __builtin_bit_cast(float, __builtin_amdgcn_ds_bpermute(4 * qr, ivb));
            float o0 = (oacc0[r] * s0f + B[128 + r * 64 + lane] * s1f) * iv;
            float o1 = (oacc1[r] * s0f + B[1152 + r * 64 + lane] * s1f) * iv;
            int qglob = qt * 128 + wq * 32 + qr;
            size_t base = ((size_t)(n * S_LEN + qglob)) * DM + h * HD + l31;
            Oatt[base] = (_Float16)o0;
            Oatt[base + 32] = (_Float16)o1;
        }
    }
}

// ---------------------------------------------------------------------------
// Projection GEMM: 128x64 tile, BK=64, grid 512 (2 blocks/CU), LDS 48 KB
// double-buffered via gload16 (inverse-swizzled source, linear dest).
// 4 waves; wave w owns M rows [w*32, w*32+32) x all 64 N cols.
// XCD: ot = (id&7) + 8*((id>>3)&1) pins W strips per XCD.
// ---------------------------------------------------------------------------
__global__ __launch_bounds__(256) void k_proj(const _Float16* __restrict__ A,
                                              const _Float16* __restrict__ W,
                                              const float* __restrict__ bias,
                                              float* __restrict__ out) {
    __shared__ _Float16 As[2][128 * 64];   // 16 KB each
    __shared__ _Float16 Ws[2][64 * 64];    // 8 KB each

    const int id = blockIdx.x;
    const int ot = (id & 7) + 8 * ((id >> 3) & 1);   // 0..15, O strip of 64
    const int mt = id >> 4;                          // 0..31, M strip of 128
    const int tid = threadIdx.x;
    const int w = tid >> 6;
    const int lane = tid & 63;
    const int lr = lane & 15, lg = lane >> 4;
    const int wm = w * 32;

    const int rr = lane >> 3;
    const int cb = (lane & 7) * 16;
    const int gcb = cb ^ (rr << 4);

    const char* Abase = (const char*)(A + (size_t)(mt * 128) * DM);
    const char* Wbase = (const char*)(W + (size_t)(ot * 64) * DM);

    auto STAGE = [&](int kt, int b) {
#pragma unroll
        for (int r = 0; r < 4; ++r) {
            int row = r * 32 + w * 8 + rr;
            gload16(Abase + (size_t)row * 2048 + kt * 128 + gcb,
                    (char*)&As[b][0] + (r * 32 + w * 8) * 128);
        }
#pragma unroll
        for (int r = 0; r < 2; ++r) {
            int row = r * 32 + w * 8 + rr;
            gload16(Wbase + (size_t)row * 2048 + kt * 128 + gcb,
                    (char*)&Ws[b][0] + (r * 32 + w * 8) * 128);
        }
    };

    f32x4 zero = {0.f, 0.f, 0.f, 0.f};
    f32x4 acc[2][4];
#pragma unroll
    for (int mi = 0; mi < 2; ++mi)
#pragma unroll
        for (int ni = 0; ni < 4; ++ni) acc[mi][ni] = zero;

    auto COMPUTE = [&](int b) {
        const char* ldsA = (const char*)&As[b][0];
        const char* ldsW = (const char*)&Ws[b][0];
        half8 af[2][2], wf[4][2];
#pragma unroll
        for (int mi = 0; mi < 2; ++mi) {
            int row = wm + mi * 16 + lr;
            int sw = (row & 7) << 4;
            const char* p = ldsA + row * 128;
            af[mi][0] = *(const half8*)(p + ((lg * 16) ^ sw));
            af[mi][1] = *(const half8*)(p + ((64 + lg * 16) ^ sw));
        }
#pragma unroll
        for (int ni = 0; ni < 4; ++ni) {
            int row = ni * 16 + lr;
            int sw = (row & 7) << 4;
            const char* p = ldsW + row * 128;
            wf[ni][0] = *(const half8*)(p + ((lg * 16) ^ sw));
            wf[ni][1] = *(const half8*)(p + ((64 + lg * 16) ^ sw));
        }
#pragma unroll
        for (int mi = 0; mi < 2; ++mi)
#pragma unroll
            for (int ni = 0; ni < 4; ++ni) {
                acc[mi][ni] = __builtin_amdgcn_mfma_f32_16x16x32_f16(af[mi][0], wf[ni][0], acc[mi][ni], 0, 0, 0);
                acc[mi][ni] = __builtin_amdgcn_mfma_f32_16x16x32_f16(af[mi][1], wf[ni][1], acc[mi][ni], 0, 0, 0);
            }
    };

    STAGE(0, 0);
    __syncthreads();
    for (int kt = 0; kt < 15; ++kt) {
        STAGE(kt + 1, (kt & 1) ^ 1);
        COMPUTE(kt & 1);
        __syncthreads();
    }
    COMPUTE(1);   // kt=15, no stage -> no DMA outstanding at endpgm

    // epilogue: C row = m (A dim), col = o (W dim)
#pragma unroll
    for (int ni = 0; ni < 4; ++ni) {
        int o = ot * 64 + ni * 16 + lr;
        float b = bias[o];
#pragma unroll
        for (int mi = 0; mi < 2; ++mi)
#pragma unroll
            for (int i = 0; i < 4; ++i) {
                int m = mt * 128 + wm + mi * 16 + lg * 4 + i;
                out[(size_t)m * DM + o] = acc[mi][ni][i] + b;
            }
    }
}

// ---------------------------------------------------------------------------
extern "C" void kernel_launch(void* const* d_in, const int* in_sizes, int n_in,
                              void* d_out, int out_size, void* d_ws, size_t ws_size,
                              hipStream_t stream) {
    const float* Q = (const float*)d_in[0];
    const float* K = (const float*)d_in[1];
    const float* V = (const float*)d_in[2];
    const float* Wo = (const float*)d_in[3];
    const float* bo = (const float*)d_in[4];
    float* out = (float*)d_out;
    char* ws = (char*)d_ws;

    _Float16* Kh = (_Float16*)(ws);                     // 8 MB
    _Float16* Vt = (_Float16*)(ws + (8u << 20));        // 8 MB
    _Float16* Oatt = (_Float16*)(ws + (16u << 20));     // 8 MB
    _Float16* Wh = (_Float16*)(ws + (24u << 20));       // 2 MB

    k_prep<<<3584, 256, 0, stream>>>(K, V, Wo, Kh, Vt, Wh);
    k_attn<<<512, 512, 0, stream>>>(Q, Kh, Vt, Oatt);
    k_proj<<<512, 256, 0, stream>>>(Oatt, Wh, bo, out);
}

// Round 23
// 83.376 us; speedup vs baseline: 1.9674x; 1.0166x over previous
//
#include <hip/hip_runtime.h>

typedef _Float16 half8 __attribute__((ext_vector_type(8)));
typedef _Float16 half4 __attribute__((ext_vector_type(4)));
typedef float f32x4 __attribute__((ext_vector_type(4)));
typedef float f32x16 __attribute__((ext_vector_type(16)));
typedef unsigned u32x4 __attribute__((ext_vector_type(4)));

#define N_B 2
#define S_LEN 2048
#define NH 16
#define HD 64
#define DM 1024
#define LOG2E 1.44269504088896f

__device__ __forceinline__ void gload16(const void* g, void* l) {
    __builtin_amdgcn_global_load_lds(
        (const __attribute__((address_space(1))) unsigned int*)g,
        (__attribute__((address_space(3))) unsigned int*)l, 16, 0, 0);
}

__device__ __forceinline__ float fexp2(float x) {
    float r;
    asm("v_exp_f32 %0, %1" : "=v"(r) : "v"(x));
    return r;
}

// ---------------------------------------------------------------------------
// Prep (grid 3072): blocks [0,2048) convert K (2 float4/thread) ->
// f16 [n][h][s][d]; [2048,3072) transpose V -> Vt f16 [n][h][d][s'] with
// keys PERMUTED within each 16 (quads {4-7}<->{8-11}) so k_attn's P pack
// needs no cross-lane exchange. (W-convert moved into k_attn tail blocks.)
// ---------------------------------------------------------------------------
__global__ __launch_bounds__(256) void k_prep(const float* __restrict__ K,
                                              const float* __restrict__ V,
                                              _Float16* __restrict__ Kh,
                                              _Float16* __restrict__ Vt) {
    __shared__ _Float16 tile[64][65];
    const int id = blockIdx.x;
    if (id < 2048) {                       // ---- K regroup, 2 float4/thread
#pragma unroll
        for (int u = 0; u < 2; ++u) {
            int i = id * 512 + u * 256 + threadIdx.x;
            float4 v = ((const float4*)K)[i];
            int base = i * 4;
            int d = base & 63;
            int h = (base >> 6) & 15;
            int s = (base >> 10) & 2047;
            int n = base >> 21;
            size_t o = ((size_t)((n * NH + h) * S_LEN + s)) * HD + d;
            half4 hv = {(_Float16)v.x, (_Float16)v.y, (_Float16)v.z, (_Float16)v.w};
            *(half4*)(Kh + o) = hv;
        }
    } else {                               // ---- V transpose (vectorized)
        int b = id - 2048;
        int st = b & 31, h = (b >> 5) & 15, n = b >> 9;
        int r0 = threadIdx.x >> 4;         // 0..15
        int c4 = (threadIdx.x & 15) * 4;   // 0,4,..,60 (source key base)
        // permuted destination: swap quadruples {4-7}<->{8-11} in each 16
        int pc4 = (c4 & ~12) | ((c4 & 4) << 1) | ((c4 & 8) >> 1);
#pragma unroll
        for (int i = 0; i < 4; ++i) {
            int row = i * 16 + r0;
            float4 v = *(const float4*)(V + ((size_t)(n * S_LEN) + st * 64 + row) * DM + h * HD + c4);
            tile[row][c4 + 0] = (_Float16)v.x;
            tile[row][c4 + 1] = (_Float16)v.y;
            tile[row][c4 + 2] = (_Float16)v.z;
            tile[row][c4 + 3] = (_Float16)v.w;
        }
        __syncthreads();
#pragma unroll
        for (int i = 0; i < 4; ++i) {
            int d = i * 16 + r0;
            half4 hv = {tile[c4 + 0][d], tile[c4 + 1][d], tile[c4 + 2][d], tile[c4 + 3][d]};
            *(half4*)(Vt + ((size_t)((n * NH + h) * HD + d)) * S_LEN + st * 64 + pc4) = hv;
        }
    }
}

// ---------------------------------------------------------------------------
// Flash attention (R22-validated, 59us) + W-convert tail blocks (id>=512):
// those 128 blocks convert W_out f32->f16 (needed only by k_proj, which
// runs after) and exit -- they fill the CU tail as attn blocks drain.
// Attn: ONE barrier/round, K AND V double-buffered (64 KB LDS), 32x32
// MFMA, wave-level KV split, fragment-order LDS layout (conflict-free
// b128 reads), shfl-free P pack (prep-side Vt key permutation), exp2
// softmax, defer-max THR=14, lane-local gate, partial l. Block = 8 waves
// (512 thr), QBLK=128. No DMA outstanding at endpgm.
// ---------------------------------------------------------------------------
__global__ __launch_bounds__(512, 4) void k_attn(const float* __restrict__ Q,
                                                 const _Float16* __restrict__ Kh,
                                                 const _Float16* __restrict__ Vth,
                                                 _Float16* __restrict__ Oatt,
                                                 const float* __restrict__ Wo,
                                                 _Float16* __restrict__ Wh) {
    __shared__ char SB[65536];
    // [0,32768): K dbuf (b,hf) 8KB each ; [32768,65536): V dbuf (b,hf) 8KB each

    const int id = blockIdx.x;
    if (id >= 512) {                       // ---- W convert tail blocks
        int b = id - 512;                  // 0..127
#pragma unroll
        for (int u = 0; u < 4; ++u) {
            int i = b * 2048 + u * 512 + threadIdx.x;
            float4 v = ((const float4*)Wo)[i];
            half4 hv = {(_Float16)v.x, (_Float16)v.y, (_Float16)v.z, (_Float16)v.w};
            *(half4*)(Wh + (size_t)i * 4) = hv;
        }
        return;
    }

    // XCD swizzle (bijective on 512 = 8 * 64): 4 nh per XCD, 16 qt each
    const int xcd = id & 7;
    const int sl = id >> 3;              // 0..63
    const int nh = xcd + 8 * (sl >> 4);
    const int qt = sl & 15;              // q tile of 128

    const int tid = threadIdx.x;
    const int w = tid >> 6;              // 0..7
    const int wq = w & 3;                // q-subtile
    const int hf = w >> 2;               // KV half
    const int lane = tid & 63;
    const int l31 = lane & 31;
    const int hi = lane >> 5;
    const int n = nh >> 4, h = nh & 15;

    const size_t head = (size_t)nh * S_LEN * HD;
    const char* Khead = (const char*)(Kh + head);
    const char* Vhead = (const char*)(Vth + head);

    // ---- Q fragments (B-frag: col q=l31, k=8hi+j per 16-d chunk), LOG2E-scaled
    const int qg = qt * 128 + wq * 32 + l31;
    const float* qbase = Q + ((size_t)(n * S_LEN) + qg) * DM + h * HD;
    auto mkqf = [&](int c) -> half8 {
        float4 a = *(const float4*)(qbase + 16 * c + 8 * hi);
        float4 b = *(const float4*)(qbase + 16 * c + 8 * hi + 4);
        half8 r = {(_Float16)(a.x * LOG2E), (_Float16)(a.y * LOG2E),
                   (_Float16)(a.z * LOG2E), (_Float16)(a.w * LOG2E),
                   (_Float16)(b.x * LOG2E), (_Float16)(b.y * LOG2E),
                   (_Float16)(b.z * LOG2E), (_Float16)(b.w * LOG2E)};
        return r;
    };
    half8 qf0 = mkqf(0), qf1 = mkqf(1), qf2 = mkqf(2), qf3 = mkqf(3);

    f32x16 oacc0 = {}, oacc1 = {};
    float m_q = -1e30f, l_q = 0.f;       // m uniform per q; l per-(q,hi) PARTIAL

    auto kbuf = [&](int b, int half) -> char* { return SB + (b * 2 + half) * 8192; };
    auto vbuf = [&](int b, int half) -> char* { return SB + 32768 + (b * 2 + half) * 8192; };

    auto STAGE_K = [&](int t, int b) {
#pragma unroll
        for (int j = 0; j < 2; ++j) {
            int slice = wq * 2 + j;            // 0..7
            int idx = slice * 64 + lane;       // 0..511
            int bhi = idx & 1;
            int bl31 = (idx >> 1) & 31;
            int bc = (idx >> 6) & 3;
            int bblk = idx >> 8;
            int key = hf * 1024 + t * 64 + bblk * 32 + bl31;
            gload16(Khead + (size_t)key * 128 + bc * 32 + bhi * 16,
                    kbuf(b, hf) + slice * 1024);
        }
    };
    auto STAGE_V = [&](int t, int b) {
#pragma unroll
        for (int j = 0; j < 2; ++j) {
            int slice = wq * 2 + j;
            int idx = slice * 64 + lane;
            int bhi = idx & 1;
            int bl31 = (idx >> 1) & 31;
            int bc = (idx >> 6) & 3;
            int bblk = idx >> 8;
            int drow = bblk * 32 + bl31;
            gload16(Vhead + (size_t)drow * 4096 + hf * 2048 + t * 128 + bc * 32 + bhi * 16,
                    vbuf(b, hf) + slice * 1024);
        }
    };

    // fragment read: contiguous 1KB per (blk,c) -- conflict-free
    auto ldF = [&](const char* lds, int blk, int c) -> half8 {
        int off = (((blk * 4 + c) * 32 + l31) * 2 + hi) * 16;
        return *(const half8*)(lds + off);
    };

    auto pkrtz = [&](float a, float b) -> unsigned {
        return __builtin_bit_cast(unsigned, __builtin_amdgcn_cvt_pkrtz(a, b));
    };
    // P -> A-frag: with the prep-side Vt key permutation, slot (hi,j)'s key
    // equals C-layout register j -- straight packed converts, no cross-lane.
    auto mkpa = [&](const f32x16& S, int rb) -> half8 {
        u32x4 t;
        t[0] = pkrtz(S[rb + 0], S[rb + 1]);
        t[1] = pkrtz(S[rb + 2], S[rb + 3]);
        t[2] = pkrtz(S[rb + 4], S[rb + 5]);
        t[3] = pkrtz(S[rb + 6], S[rb + 7]);
        return __builtin_bit_cast(half8, t);
    };

    STAGE_K(0, 0);
    STAGE_V(0, 0);
    __syncthreads();                       // K(0), V(0) resident

    for (int t = 0; t < 16; ++t) {
        const int buf = t & 1;
        if (t < 15) {                      // prefetch next round into buf^1
            STAGE_K(t + 1, buf ^ 1);
            STAGE_V(t + 1, buf ^ 1);
        }
        const char* ldsK = kbuf(buf, hf);
        const char* ldsV = vbuf(buf, hf);

        // ---- S^T = K Q^T : two 32-key blocks, d chained over 4 chunks
        f32x16 s0 = {}, s1 = {};
        __builtin_amdgcn_s_setprio(1);
        s0 = __builtin_amdgcn_mfma_f32_32x32x16_f16(ldF(ldsK, 0, 0), qf0, s0, 0, 0, 0);
        s0 = __builtin_amdgcn_mfma_f32_32x32x16_f16(ldF(ldsK, 0, 1), qf1, s0, 0, 0, 0);
        s0 = __builtin_amdgcn_mfma_f32_32x32x16_f16(ldF(ldsK, 0, 2), qf2, s0, 0, 0, 0);
        s0 = __builtin_amdgcn_mfma_f32_32x32x16_f16(ldF(ldsK, 0, 3), qf3, s0, 0, 0, 0);
        s1 = __builtin_amdgcn_mfma_f32_32x32x16_f16(ldF(ldsK, 1, 0), qf0, s1, 0, 0, 0);
        s1 = __builtin_amdgcn_mfma_f32_32x32x16_f16(ldF(ldsK, 1, 1), qf1, s1, 0, 0, 0);
        s1 = __builtin_amdgcn_mfma_f32_32x32x16_f16(ldF(ldsK, 1, 2), qf2, s1, 0, 0, 0);
        s1 = __builtin_amdgcn_mfma_f32_32x32x16_f16(ldF(ldsK, 1, 3), qf3, s1, 0, 0, 0);
        __builtin_amdgcn_s_setprio(0);

        // ---- lane-LOCAL max gate; cross-lane only on trigger (defer THR=14)
        float a0 = fmaxf(fmaxf(s0[0], s0[1]), fmaxf(s0[2], s0[3]));
        float a1 = fmaxf(fmaxf(s0[4], s0[5]), fmaxf(s0[6], s0[7]));
        float a2 = fmaxf(fmaxf(s0[8], s0[9]), fmaxf(s0[10], s0[11]));
        float a3 = fmaxf(fmaxf(s0[12], s0[13]), fmaxf(s0[14], s0[15]));
        float b0 = fmaxf(fmaxf(s1[0], s1[1]), fmaxf(s1[2], s1[3]));
        float b1 = fmaxf(fmaxf(s1[4], s1[5]), fmaxf(s1[6], s1[7]));
        float b2 = fmaxf(fmaxf(s1[8], s1[9]), fmaxf(s1[10], s1[11]));
        float b3 = fmaxf(fmaxf(s1[12], s1[13]), fmaxf(s1[14], s1[15]));
        float lmax = fmaxf(fmaxf(fmaxf(a0, a1), fmaxf(a2, a3)),
                           fmaxf(fmaxf(b0, b1), fmaxf(b2, b3)));
        if (!__all(lmax <= m_q + 14.f)) {
            float tm = fmaxf(lmax, __shfl_xor(lmax, 32));   // uniform per q
            float mn = fmaxf(m_q, tm);
            float sc = fexp2(m_q - mn);                     // uniform across hi
            m_q = mn;
            l_q *= sc;                                      // partial scales exactly
            int scb = __builtin_bit_cast(int, sc);
#pragma unroll
            for (int r = 0; r < 16; ++r) {
                int qr = (r & 3) + 8 * (r >> 2) + 4 * hi;
                float s = __builtin_bit_cast(float, __builtin_amdgcn_ds_bpermute(4 * qr, scb));
                oacc0[r] *= s;
                oacc1[r] *= s;
            }
        }
        // ---- exp + row-sum: 4 parallel accumulators, no cross-lane ----
        float r0 = 0.f, r1 = 0.f, r2 = 0.f, r3 = 0.f;
#pragma unroll
        for (int i = 0; i < 16; i += 4) {
            float p0 = fexp2(s0[i + 0] - m_q); s0[i + 0] = p0; r0 += p0;
            float p1 = fexp2(s0[i + 1] - m_q); s0[i + 1] = p1; r1 += p1;
            float p2 = fexp2(s0[i + 2] - m_q); s0[i + 2] = p2; r2 += p2;
            float p3 = fexp2(s0[i + 3] - m_q); s0[i + 3] = p3; r3 += p3;
        }
#pragma unroll
        for (int i = 0; i < 16; i += 4) {
            float p0 = fexp2(s1[i + 0] - m_q); s1[i + 0] = p0; r0 += p0;
            float p1 = fexp2(s1[i + 1] - m_q); s1[i + 1] = p1; r1 += p1;
            float p2 = fexp2(s1[i + 2] - m_q); s1[i + 2] = p2; r2 += p2;
            float p3 = fexp2(s1[i + 3] - m_q); s1[i + 3] = p3; r3 += p3;
        }
        l_q += (r0 + r1) + (r2 + r3);    // per-(q,hi) partial

        // ---- P -> A-fragments (pure pkrtz, no shfl)
        half8 pa0 = mkpa(s0, 0), pa1 = mkpa(s0, 8);
        half8 pa2 = mkpa(s1, 0), pa3 = mkpa(s1, 8);

        // ---- O += P V  (V(t) resident since last round's barrier)
        __builtin_amdgcn_s_setprio(1);
        oacc0 = __builtin_amdgcn_mfma_f32_32x32x16_f16(pa0, ldF(ldsV, 0, 0), oacc0, 0, 0, 0);
        oacc0 = __builtin_amdgcn_mfma_f32_32x32x16_f16(pa1, ldF(ldsV, 0, 1), oacc0, 0, 0, 0);
        oacc0 = __builtin_amdgcn_mfma_f32_32x32x16_f16(pa2, ldF(ldsV, 0, 2), oacc0, 0, 0, 0);
        oacc0 = __builtin_amdgcn_mfma_f32_32x32x16_f16(pa3, ldF(ldsV, 0, 3), oacc0, 0, 0, 0);
        oacc1 = __builtin_amdgcn_mfma_f32_32x32x16_f16(pa0, ldF(ldsV, 1, 0), oacc1, 0, 0, 0);
        oacc1 = __builtin_amdgcn_mfma_f32_32x32x16_f16(pa1, ldF(ldsV, 1, 1), oacc1, 0, 0, 0);
        oacc1 = __builtin_amdgcn_mfma_f32_32x32x16_f16(pa2, ldF(ldsV, 1, 2), oacc1, 0, 0, 0);
        oacc1 = __builtin_amdgcn_mfma_f32_32x32x16_f16(pa3, ldF(ldsV, 1, 3), oacc1, 0, 0, 0);
        __builtin_amdgcn_s_setprio(0);

        __syncthreads();   // single per-round barrier: drains stage DMA + orders buf reuse
    }

    // ---- combine hi-half l partials (once) ----
    l_q += __shfl_xor(l_q, 32);

    // ---- merge wave pairs (w <-> w+4) via LDS, exp2 domain ----
    float* MRG = (float*)SB;               // 4 regions x 2176 f32 (34.8 KB)
    if (hf == 1) {
        float* B = MRG + wq * 2176;
        B[lane] = m_q;
        B[64 + lane] = l_q;
#pragma unroll
        for (int r = 0; r < 16; ++r) {
            B[128 + r * 64 + lane] = oacc0[r];
            B[1152 + r * 64 + lane] = oacc1[r];
        }
    }
    __syncthreads();
    if (hf == 0) {
        float* B = MRG + wq * 2176;
        float m1 = B[lane], l1 = B[64 + lane];
        float m = fmaxf(m_q, m1);
        float e0 = fexp2(m_q - m), e1 = fexp2(m1 - m);
        float linv = 1.f / (l_q * e0 + l1 * e1);
        int e0b = __builtin_bit_cast(int, e0);
        int e1b = __builtin_bit_cast(int, e1);
        int ivb = __builtin_bit_cast(int, linv);
#pragma unroll
        for (int r = 0; r < 16; ++r) {
            int qr = (r & 3) + 8 * (r >> 2) + 4 * hi;
            float s0f = __builtin_bit_cast(float, __builtin_amdgcn_ds_bpermute(4 * qr, e0b));
            float s1f = __builtin_bit_cast(float, __builtin_amdgcn_ds_bpermute(4 * qr, e1b));
            float iv = __builtin_bit_cast(float, __builtin_amdgcn_ds_bpermute(4 * qr, ivb));
            float o0 = (oacc0[r] * s0f + B[128 + r * 64 + lane] * s1f) * iv;
            float o1 = (oacc1[r] * s0f + B[1152 + r * 64 + lane] * s1f) * iv;
            int qglob = qt * 128 + wq * 32 + qr;
            size_t base = ((size_t)(n * S_LEN + qglob)) * DM + h * HD + l31;
            Oatt[base] = (_Float16)o0;
            Oatt[base + 32] = (_Float16)o1;
        }
    }
}

// ---------------------------------------------------------------------------
// Projection GEMM: 128x64 tile, BK=64, grid 512 (2 blocks/CU), LDS 48 KB
// double-buffered via gload16 (inverse-swizzled source, linear dest).
// 4 waves; wave w owns M rows [w*32, w*32+32) x all 64 N cols.
// XCD: ot = (id&7) + 8*((id>>3)&1) pins W strips per XCD.
// ---------------------------------------------------------------------------
__global__ __launch_bounds__(256) void k_proj(const _Float16* __restrict__ A,
                                              const _Float16* __restrict__ W,
                                              const float* __restrict__ bias,
                                              float* __restrict__ out) {
    __shared__ _Float16 As[2][128 * 64];   // 16 KB each
    __shared__ _Float16 Ws[2][64 * 64];    // 8 KB each

    const int id = blockIdx.x;
    const int ot = (id & 7) + 8 * ((id >> 3) & 1);   // 0..15, O strip of 64
    const int mt = id >> 4;                          // 0..31, M strip of 128
    const int tid = threadIdx.x;
    const int w = tid >> 6;
    const int lane = tid & 63;
    const int lr = lane & 15, lg = lane >> 4;
    const int wm = w * 32;

    const int rr = lane >> 3;
    const int cb = (lane & 7) * 16;
    const int gcb = cb ^ (rr << 4);

    const char* Abase = (const char*)(A + (size_t)(mt * 128) * DM);
    const char* Wbase = (const char*)(W + (size_t)(ot * 64) * DM);

    auto STAGE = [&](int kt, int b) {
#pragma unroll
        for (int r = 0; r < 4; ++r) {
            int row = r * 32 + w * 8 + rr;
            gload16(Abase + (size_t)row * 2048 + kt * 128 + gcb,
                    (char*)&As[b][0] + (r * 32 + w * 8) * 128);
        }
#pragma unroll
        for (int r = 0; r < 2; ++r) {
            int row = r * 32 + w * 8 + rr;
            gload16(Wbase + (size_t)row * 2048 + kt * 128 + gcb,
                    (char*)&Ws[b][0] + (r * 32 + w * 8) * 128);
        }
    };

    f32x4 zero = {0.f, 0.f, 0.f, 0.f};
    f32x4 acc[2][4];
#pragma unroll
    for (int mi = 0; mi < 2; ++mi)
#pragma unroll
        for (int ni = 0; ni < 4; ++ni) acc[mi][ni] = zero;

    auto COMPUTE = [&](int b) {
        const char* ldsA = (const char*)&As[b][0];
        const char* ldsW = (const char*)&Ws[b][0];
        half8 af[2][2], wf[4][2];
#pragma unroll
        for (int mi = 0; mi < 2; ++mi) {
            int row = wm + mi * 16 + lr;
            int sw = (row & 7) << 4;
            const char* p = ldsA + row * 128;
            af[mi][0] = *(const half8*)(p + ((lg * 16) ^ sw));
            af[mi][1] = *(const half8*)(p + ((64 + lg * 16) ^ sw));
        }
#pragma unroll
        for (int ni = 0; ni < 4; ++ni) {
            int row = ni * 16 + lr;
            int sw = (row & 7) << 4;
            const char* p = ldsW + row * 128;
            wf[ni][0] = *(const half8*)(p + ((lg * 16) ^ sw));
            wf[ni][1] = *(const half8*)(p + ((64 + lg * 16) ^ sw));
        }
#pragma unroll
        for (int mi = 0; mi < 2; ++mi)
#pragma unroll
            for (int ni = 0; ni < 4; ++ni) {
                acc[mi][ni] = __builtin_amdgcn_mfma_f32_16x16x32_f16(af[mi][0], wf[ni][0], acc[mi][ni], 0, 0, 0);
                acc[mi][ni] = __builtin_amdgcn_mfma_f32_16x16x32_f16(af[mi][1], wf[ni][1], acc[mi][ni], 0, 0, 0);
            }
    };

    STAGE(0, 0);
    __syncthreads();
    for (int kt = 0; kt < 15; ++kt) {
        STAGE(kt + 1, (kt & 1) ^ 1);
        COMPUTE(kt & 1);
        __syncthreads();
    }
    COMPUTE(1);   // kt=15, no stage -> no DMA outstanding at endpgm

    // epilogue: C row = m (A dim), col = o (W dim)
#pragma unroll
    for (int ni = 0; ni < 4; ++ni) {
        int o = ot * 64 + ni * 16 + lr;
        float b = bias[o];
#pragma unroll
        for (int mi = 0; mi < 2; ++mi)
#pragma unroll
            for (int i = 0; i < 4; ++i) {
                int m = mt * 128 + wm + mi * 16 + lg * 4 + i;
                out[(size_t)m * DM + o] = acc[mi][ni][i] + b;
            }
    }
}

// ---------------------------------------------------------------------------
extern "C" void kernel_launch(void* const* d_in, const int* in_sizes, int n_in,
                              void* d_out, int out_size, void* d_ws, size_t ws_size,
                              hipStream_t stream) {
    const float* Q = (const float*)d_in[0];
    const float* K = (const float*)d_in[1];
    const float* V = (const float*)d_in[2];
    const float* Wo = (const float*)d_in[3];
    const float* bo = (const float*)d_in[4];
    float* out = (float*)d_out;
    char* ws = (char*)d_ws;

    _Float16* Kh = (_Float16*)(ws);                     // 8 MB
    _Float16* Vt = (_Float16*)(ws + (8u << 20));        // 8 MB
    _Float16* Oatt = (_Float16*)(ws + (16u << 20));     // 8 MB
    _Float16* Wh = (_Float16*)(ws + (24u << 20));       // 2 MB

    k_prep<<<3072, 256, 0, stream>>>(K, V, Kh, Vt);
    k_attn<<<640, 512, 0, stream>>>(Q, Kh, Vt, Oatt, Wo, Wh);
    k_proj<<<512, 256, 0, stream>>>(Oatt, Wh, bo, out);
}